// Round 3
// baseline (1779.836 us; speedup 1.0000x reference)
//
#include <hip/hip_runtime.h>

typedef unsigned short u16;
typedef unsigned int   u32;
typedef __bf16 bf16x8 __attribute__((ext_vector_type(8)));
typedef float  f32x4  __attribute__((ext_vector_type(4)));

#define DEV __device__ __forceinline__

DEV u16 f2bf(float f) {
    u32 u = __builtin_bit_cast(u32, f);
    u32 r = u + 0x7FFFu + ((u >> 16) & 1u);
    return (u16)(r >> 16);
}

DEV void gload16(const void* g, void* l) {
    __builtin_amdgcn_global_load_lds((const __attribute__((address_space(1))) void*)g,
                                     (__attribute__((address_space(3))) void*)l, 16, 0, 0);
}

// bijective XCD-aware swizzle (m204)
DEV int xcd_swz(int bid, int nwg) {
    int q = nwg >> 3, r = nwg & 7;
    int xcd = bid & 7, idx = bid >> 3;
    return (xcd < r ? xcd * (q + 1) : r * (q + 1) + (xcd - r) * q) + idx;
}

// ---------------- convert f32 -> bf16 ----------------
__global__ void cvt_k(const float* __restrict__ src, u16* __restrict__ dst, int n4) {
    int i = blockIdx.x * blockDim.x + threadIdx.x;
    int stride = gridDim.x * blockDim.x;
    for (; i < n4; i += stride) {
        float4 v = ((const float4*)src)[i];
        ushort4 u;
        u.x = f2bf(v.x); u.y = f2bf(v.y); u.z = f2bf(v.z); u.w = f2bf(v.w);
        ((ushort4*)dst)[i] = u;
    }
}

// ---------------- embedding ----------------
__global__ void embed_k(const int* __restrict__ x, const float* __restrict__ te,
                        const float* __restrict__ pe, float* __restrict__ h) {
    int row = blockIdx.x;
    int t = threadIdx.x;
    int tok = x[row];
    int s = row & 1023;
    float4 a = ((const float4*)(te + (size_t)tok * 1024))[t];
    float4 p = ((const float4*)(pe + (size_t)s * 1024))[t];
    a.x += p.x; a.y += p.y; a.z += p.z; a.w += p.w;
    ((float4*)(h + (size_t)row * 1024))[t] = a;
}

// ---------------- LayerNorm: f32 in -> bf16 out ----------------
__global__ void ln_k(const float* __restrict__ in, const float* __restrict__ g,
                     const float* __restrict__ b, u16* __restrict__ out) {
    int row = blockIdx.x;
    int t = threadIdx.x;
    float4 v = ((const float4*)(in + (size_t)row * 1024))[t];
    float s = v.x + v.y + v.z + v.w;
    float s2 = v.x * v.x + v.y * v.y + v.z * v.z + v.w * v.w;
    #pragma unroll
    for (int msk = 1; msk < 64; msk <<= 1) {
        s  += __shfl_xor(s, msk);
        s2 += __shfl_xor(s2, msk);
    }
    __shared__ float ps[4], ps2[4];
    if ((t & 63) == 0) { ps[t >> 6] = s; ps2[t >> 6] = s2; }
    __syncthreads();
    s = ps[0] + ps[1] + ps[2] + ps[3];
    s2 = ps2[0] + ps2[1] + ps2[2] + ps2[3];
    float mu = s * (1.0f / 1024.0f);
    float var = s2 * (1.0f / 1024.0f) - mu * mu;
    float rstd = rsqrtf(var + 1e-5f);
    float4 gg = ((const float4*)g)[t];
    float4 bb = ((const float4*)b)[t];
    ushort4 o;
    o.x = f2bf((v.x - mu) * rstd * gg.x + bb.x);
    o.y = f2bf((v.y - mu) * rstd * gg.y + bb.y);
    o.z = f2bf((v.z - mu) * rstd * gg.z + bb.z);
    o.w = f2bf((v.w - mu) * rstd * gg.w + bb.w);
    ((ushort4*)out)[(size_t)row * 256 + t] = o;
}

// ============ 256x256 8-wave phase-interleaved GEMM (counted vmcnt, 4-deep ring) ============
// C[m,n] = sum_k A[m,k]*Bw[n,k], bf16 in, BK=32, LDS ring of 4 K-tiles (A 16KB + B 16KB each).
// Wave (8): wr2=w>>2 owns rows wr2*128.., wc2=w&3 owns cols wc2*64.. -> 128x64 per wave.
// Swizzle: logical byte L (row*64+cb) <-> physical L ^ ((row&3)<<4), both on stage-src and ds_read.
template<int BIAS, int GELU_, int OUTBF>
__global__ __launch_bounds__(512, 2)
void gemm256(const u16* __restrict__ A, const u16* __restrict__ Bw,
             const float* __restrict__ bias,
             float* __restrict__ outf, u16* __restrict__ outb,
             int M, int N, int K) {
    __shared__ u16 lds[4 * 16384];     // 128 KiB: 4 bufs x (A 8192 u16 | B 8192 u16)
    const int t = threadIdx.x;
    const int w = t >> 6, l = t & 63;
    const int fr = l & 15, fq = l >> 4;
    const int wr2 = w >> 2, wc2 = w & 3;

    int bid = blockIdx.y * gridDim.x + blockIdx.x;
    int swz = xcd_swz(bid, gridDim.x * gridDim.y);
    const int m0 = (swz % gridDim.x) * 256;
    const int n0 = (swz / gridDim.x) * 256;
    const int nt = K >> 5;

    // staging source mapping (pre-swizzled global source, linear LDS dest)
    int sr0, sc0_, sr1, sc1_;
    {
        int o = (w * 2) * 1024 + l * 16;
        int L = o ^ (((o >> 6) & 3) << 4);
        sr0 = L >> 6; sc0_ = (L & 63) >> 1;
    }
    {
        int o = (w * 2 + 1) * 1024 + l * 16;
        int L = o ^ (((o >> 6) & 3) << 4);
        sr1 = L >> 6; sc1_ = (L & 63) >> 1;
    }
    const u16* srcA0 = A  + (size_t)(m0 + sr0) * K + sc0_;
    const u16* srcA1 = A  + (size_t)(m0 + sr1) * K + sc1_;
    const u16* srcB0 = Bw + (size_t)(n0 + sr0) * K + sc0_;
    const u16* srcB1 = Bw + (size_t)(n0 + sr1) * K + sc1_;
    u16* dA0 = lds + (w * 2) * 512;            // + buf*16384
    u16* dA1 = lds + (w * 2 + 1) * 512;
    u16* dB0 = dA0 + 8192;
    u16* dB1 = dA1 + 8192;

    f32x4 acc[8][4] = {};

    // prologue: stage tiles 0,1,2 (12 loads/thread-pairs: 4 per tile)
    #pragma unroll
    for (int tt = 0; tt < 3; ++tt) {
        int kk = tt * 32, bo = tt * 16384;
        gload16(srcA0 + kk, dA0 + bo);
        gload16(srcA1 + kk, dA1 + bo);
        gload16(srcB0 + kk, dB0 + bo);
        gload16(srcB1 + kk, dB1 + bo);
    }
    asm volatile("s_waitcnt vmcnt(8)" ::: "memory");   // tile 0 landed; tiles 1,2 in flight
    __builtin_amdgcn_s_barrier();
    __builtin_amdgcn_sched_barrier(0);

    for (int tk = 0; tk < nt; ++tk) {
        const char* Ab = (const char*)(lds + (tk & 3) * 16384);
        const char* Bb = Ab + 16384;
        const bool pf = (tk + 3 < nt);
        const int kk = (tk + 3) * 32, bo = ((tk + 3) & 3) * 16384;

        // ---- phase A: B frags + A frags mi 0..3, stage A(t+3) ----
        bf16x8 bfr[4], afr[4];
        #pragma unroll
        for (int nj = 0; nj < 4; ++nj) {
            int row = wc2 * 64 + nj * 16 + fr;
            int phys = (row * 64 + fq * 16) ^ ((row & 3) << 4);
            bfr[nj] = *(const bf16x8*)(Bb + phys);
        }
        #pragma unroll
        for (int mi = 0; mi < 4; ++mi) {
            int row = wr2 * 128 + mi * 16 + fr;
            int phys = (row * 64 + fq * 16) ^ ((row & 3) << 4);
            afr[mi] = *(const bf16x8*)(Ab + phys);
        }
        if (pf) {
            gload16(srcA0 + kk, dA0 + bo);
            gload16(srcA1 + kk, dA1 + bo);
        }
        __builtin_amdgcn_s_barrier();
        __builtin_amdgcn_s_setprio(1);
        #pragma unroll
        for (int mi = 0; mi < 4; ++mi)
            #pragma unroll
            for (int nj = 0; nj < 4; ++nj)
                acc[mi][nj] = __builtin_amdgcn_mfma_f32_16x16x32_bf16(afr[mi], bfr[nj], acc[mi][nj], 0, 0, 0);
        __builtin_amdgcn_s_setprio(0);
        __builtin_amdgcn_s_barrier();

        // ---- phase B: A frags mi 4..7, stage B(t+3) ----
        bf16x8 afr2[4];
        #pragma unroll
        for (int mi = 0; mi < 4; ++mi) {
            int row = wr2 * 128 + 64 + mi * 16 + fr;
            int phys = (row * 64 + fq * 16) ^ ((row & 3) << 4);
            afr2[mi] = *(const bf16x8*)(Ab + phys);
        }
        if (pf) {
            gload16(srcB0 + kk, dB0 + bo);
            gload16(srcB1 + kk, dB1 + bo);
        }
        __builtin_amdgcn_s_barrier();
        __builtin_amdgcn_s_setprio(1);
        #pragma unroll
        for (int mi = 0; mi < 4; ++mi)
            #pragma unroll
            for (int nj = 0; nj < 4; ++nj)
                acc[mi + 4][nj] = __builtin_amdgcn_mfma_f32_16x16x32_bf16(afr2[mi], bfr[nj], acc[mi + 4][nj], 0, 0, 0);
        __builtin_amdgcn_s_setprio(0);

        // ---- tile boundary: counted vmcnt (tile tk+1 must be landed), never 0 in steady state ----
        if (tk < nt - 3)       asm volatile("s_waitcnt vmcnt(8)" ::: "memory");
        else if (tk == nt - 3) asm volatile("s_waitcnt vmcnt(4)" ::: "memory");
        else if (tk == nt - 2) asm volatile("s_waitcnt vmcnt(0)" ::: "memory");
        __builtin_amdgcn_s_barrier();
        __builtin_amdgcn_sched_barrier(0);
    }

    // ---- epilogue ----
    #pragma unroll
    for (int mi = 0; mi < 8; ++mi) {
        #pragma unroll
        for (int nj = 0; nj < 4; ++nj) {
            #pragma unroll
            for (int r = 0; r < 4; ++r) {
                int row = m0 + wr2 * 128 + mi * 16 + fq * 4 + r;
                int col = n0 + wc2 * 64 + nj * 16 + fr;
                float v = acc[mi][nj][r];
                if (BIAS) v += bias[col];
                if (GELU_) v = 0.5f * v * (1.0f + erff(v * 0.70710678118f));
                if (OUTBF) outb[(size_t)row * N + col] = f2bf(v);
                else       outf[(size_t)row * N + col] = v;
            }
        }
    }
}

// ---------------- 128-tile GEMM (kept for proj/fc2: small N, residual epilogue) ----------------
template<int BM, int BN, int BIAS, int GELU_, int RES, int OUTBF>
__global__ void gemm_bt(const u16* __restrict__ A, const u16* __restrict__ Bw,
                        const float* __restrict__ bias, const float* __restrict__ res,
                        float* __restrict__ outf, u16* __restrict__ outb,
                        int M, int N, int K) {
    constexpr int MR = BM / 32;
    constexpr int NR = BN / 32;
    constexpr int AL = BM / 64;
    constexpr int BL = BN / 64;
    __shared__ u16 lA[BM * 32];
    __shared__ u16 lB[BN * 32];
    const int t = threadIdx.x;
    const int w = t >> 6, l = t & 63;

    int bid = blockIdx.y * gridDim.x + blockIdx.x;
    int swz = xcd_swz(bid, gridDim.x * gridDim.y);
    const int m0 = (swz % gridDim.x) * BM;
    const int n0 = (swz / gridDim.x) * BN;

    const int wr = (w >> 1) * (BM / 2), wc = (w & 1) * (BN / 2);
    const int fr = l & 15, fq = l >> 4;

    f32x4 acc[MR][NR] = {};
    const int g0 = w * 64 + l;

    for (int k0 = 0; k0 < K; k0 += 32) {
        #pragma unroll
        for (int i = 0; i < AL; ++i) {
            int g = g0 + i * 256;
            int row = g >> 2, c = (g & 3) * 8;
            gload16(A + (size_t)(m0 + row) * K + k0 + c, lA + w * 512 + i * 2048);
        }
        #pragma unroll
        for (int i = 0; i < BL; ++i) {
            int g = g0 + i * 256;
            int row = g >> 2, c = (g & 3) * 8;
            gload16(Bw + (size_t)(n0 + row) * K + k0 + c, lB + w * 512 + i * 2048);
        }
        __syncthreads();
        bf16x8 af[MR], bfv[NR];
        #pragma unroll
        for (int mi = 0; mi < MR; ++mi)
            af[mi] = *(const bf16x8*)(lA + (wr + mi * 16 + fr) * 32 + fq * 8);
        #pragma unroll
        for (int ni = 0; ni < NR; ++ni)
            bfv[ni] = *(const bf16x8*)(lB + (wc + ni * 16 + fr) * 32 + fq * 8);
        #pragma unroll
        for (int mi = 0; mi < MR; ++mi)
            #pragma unroll
            for (int ni = 0; ni < NR; ++ni)
                acc[mi][ni] = __builtin_amdgcn_mfma_f32_16x16x32_bf16(af[mi], bfv[ni], acc[mi][ni], 0, 0, 0);
        __syncthreads();
    }

    #pragma unroll
    for (int mi = 0; mi < MR; ++mi) {
        #pragma unroll
        for (int ni = 0; ni < NR; ++ni) {
            #pragma unroll
            for (int r = 0; r < 4; ++r) {
                int row = m0 + wr + mi * 16 + fq * 4 + r;
                int col = n0 + wc + ni * 16 + fr;
                float v = acc[mi][ni][r];
                if (BIAS) v += bias[col];
                if (GELU_) v = 0.5f * v * (1.0f + erff(v * 0.70710678118f));
                if (RES) v += res[(size_t)row * N + col];
                if (OUTBF) outb[(size_t)row * N + col] = f2bf(v);
                else       outf[(size_t)row * N + col] = v;
            }
        }
    }
}

// ---------------- Flash attention ----------------
__global__ void attn_k(const u16* __restrict__ qkv, u16* __restrict__ o) {
    __shared__ u16 lK[64 * 64];
    __shared__ u16 lV[64 * 64];
    __shared__ u16 lP[4 * 16 * 64];
    const int t = threadIdx.x;
    const int w = t >> 6, l = t & 63;
    const int fr = l & 15, fq = l >> 4;
    const int b = blockIdx.z, hh = blockIdx.y;
    const int qb = gridDim.x - 1 - blockIdx.x;
    const int q0 = qb * 64;

    bf16x8 qf[2];
    {
        size_t base = ((size_t)(b * 1024) + q0 + w * 16 + fr) * 3072 + hh * 64;
        qf[0] = *(const bf16x8*)(qkv + base + fq * 8);
        qf[1] = *(const bf16x8*)(qkv + base + 32 + fq * 8);
    }

    float m_run[4], l_run[4];
    f32x4 acc_o[4] = {};
    #pragma unroll
    for (int r = 0; r < 4; ++r) { m_run[r] = -__builtin_inff(); l_run[r] = 0.0f; }

    for (int kv0 = 0; kv0 <= q0; kv0 += 64) {
        #pragma unroll
        for (int i = 0; i < 2; ++i) {
            int g = w * 64 + l + i * 256;
            int row = g >> 3, c = (g & 7) * 8;
            gload16(qkv + ((size_t)(b * 1024) + kv0 + row) * 3072 + 1024 + hh * 64 + c,
                    lK + w * 512 + i * 2048);
        }
        #pragma unroll
        for (int i = 0; i < 2; ++i) {
            int g = t + i * 256;
            int kv = g >> 3, d0 = (g & 7) * 8;
            const u32* gv = (const u32*)(qkv + ((size_t)(b * 1024) + kv0 + kv) * 3072 + 2048 + hh * 64 + d0);
            u32 v0 = gv[0], v1 = gv[1], v2 = gv[2], v3 = gv[3];
            u16 e[8] = { (u16)v0, (u16)(v0 >> 16), (u16)v1, (u16)(v1 >> 16),
                         (u16)v2, (u16)(v2 >> 16), (u16)v3, (u16)(v3 >> 16) };
            #pragma unroll
            for (int j = 0; j < 8; ++j) lV[(d0 + j) * 64 + kv] = e[j];
        }
        __syncthreads();

        f32x4 accs[4] = {};
        #pragma unroll
        for (int nt = 0; nt < 4; ++nt) {
            #pragma unroll
            for (int ks = 0; ks < 2; ++ks) {
                bf16x8 kf = *(const bf16x8*)(lK + (nt * 16 + fr) * 64 + ks * 32 + fq * 8);
                accs[nt] = __builtin_amdgcn_mfma_f32_16x16x32_bf16(qf[ks], kf, accs[nt], 0, 0, 0);
            }
        }

        float p[4][4], mx[4], rs[4];
        #pragma unroll
        for (int r = 0; r < 4; ++r) {
            int qg = q0 + w * 16 + fq * 4 + r;
            float m = -__builtin_inff();
            #pragma unroll
            for (int nt = 0; nt < 4; ++nt) {
                int kvg = kv0 + nt * 16 + fr;
                float s = (kvg <= qg) ? accs[nt][r] * 0.125f : -__builtin_inff();
                p[nt][r] = s;
                m = fmaxf(m, s);
            }
            mx[r] = m;
        }
        #pragma unroll
        for (int msk = 1; msk < 16; msk <<= 1) {
            #pragma unroll
            for (int r = 0; r < 4; ++r) mx[r] = fmaxf(mx[r], __shfl_xor(mx[r], msk));
        }
        float mnew[4], alpha[4];
        #pragma unroll
        for (int r = 0; r < 4; ++r) {
            mnew[r] = fmaxf(m_run[r], mx[r]);
            alpha[r] = __expf(m_run[r] - mnew[r]);
            float s = 0.0f;
            #pragma unroll
            for (int nt = 0; nt < 4; ++nt) {
                float pv = __expf(p[nt][r] - mnew[r]);
                p[nt][r] = pv;
                s += pv;
            }
            rs[r] = s;
        }
        #pragma unroll
        for (int msk = 1; msk < 16; msk <<= 1) {
            #pragma unroll
            for (int r = 0; r < 4; ++r) rs[r] += __shfl_xor(rs[r], msk);
        }
        #pragma unroll
        for (int r = 0; r < 4; ++r) {
            l_run[r] = l_run[r] * alpha[r] + rs[r];
            m_run[r] = mnew[r];
        }
        #pragma unroll
        for (int nt = 0; nt < 4; ++nt)
            #pragma unroll
            for (int r = 0; r < 4; ++r) acc_o[nt][r] *= alpha[r];

        #pragma unroll
        for (int nt = 0; nt < 4; ++nt)
            #pragma unroll
            for (int r = 0; r < 4; ++r)
                lP[w * 1024 + (fq * 4 + r) * 64 + nt * 16 + fr] = f2bf(p[nt][r]);
        __syncthreads();

        bf16x8 pa[2];
        pa[0] = *(const bf16x8*)(lP + w * 1024 + fr * 64 + fq * 8);
        pa[1] = *(const bf16x8*)(lP + w * 1024 + fr * 64 + 32 + fq * 8);
        #pragma unroll
        for (int nt = 0; nt < 4; ++nt) {
            #pragma unroll
            for (int ks = 0; ks < 2; ++ks) {
                bf16x8 vf = *(const bf16x8*)(lV + (nt * 16 + fr) * 64 + ks * 32 + fq * 8);
                acc_o[nt] = __builtin_amdgcn_mfma_f32_16x16x32_bf16(pa[ks], vf, acc_o[nt], 0, 0, 0);
            }
        }
        __syncthreads();
    }

    #pragma unroll
    for (int nt = 0; nt < 4; ++nt) {
        #pragma unroll
        for (int r = 0; r < 4; ++r) {
            int qg = q0 + w * 16 + fq * 4 + r;
            int d = nt * 16 + fr;
            float ov = acc_o[nt][r] / l_run[r];
            o[((size_t)(b * 1024) + qg) * 1024 + hh * 64 + d] = f2bf(ov);
        }
    }
}

// ---------------- launch ----------------
extern "C" void kernel_launch(void* const* d_in, const int* in_sizes, int n_in,
                              void* d_out, int out_size, void* d_ws, size_t ws_size,
                              hipStream_t stream) {
    const int*   x       = (const int*)  d_in[0];
    const float* tok_emb = (const float*)d_in[1];
    const float* pos_emb = (const float*)d_in[2];
    const float* ln1_g   = (const float*)d_in[3];
    const float* ln1_b   = (const float*)d_in[4];
    const float* qkv_w   = (const float*)d_in[5];
    const float* qkv_b   = (const float*)d_in[6];
    const float* proj_w  = (const float*)d_in[7];
    const float* proj_b  = (const float*)d_in[8];
    const float* ln2_g   = (const float*)d_in[9];
    const float* ln2_b   = (const float*)d_in[10];
    const float* fc1_w   = (const float*)d_in[11];
    const float* fc1_b   = (const float*)d_in[12];
    const float* fc2_w   = (const float*)d_in[13];
    const float* fc2_b   = (const float*)d_in[14];
    const float* lnf_g   = (const float*)d_in[15];
    const float* lnf_b   = (const float*)d_in[16];
    const float* head_w  = (const float*)d_in[17];
    float* out = (float*)d_out;

    char* ws = (char*)d_ws;
    float* h   = (float*)(ws + 0);            //  8 MB f32 (2048x1024)
    u16*   xn  = (u16*)(ws + 8388608);        //  4 MB bf16
    u16*   qkv = (u16*)(ws + 12582912);       // 12.6 MB bf16 (2048x3072)
    u16*   ob  = (u16*)(ws + 25165824);       //  4 MB bf16
    u16*   ff  = (u16*)(ws + 29360128);       // 16.8 MB bf16 (2048x4096)
    u16*   wq  = (u16*)(ws + 46137344);       // 65.5 MB bf16 weight slab

    const int M = 2048;

    embed_k<<<dim3(2048), 256, 0, stream>>>(x, tok_emb, pos_emb, h);

    for (int lyr = 0; lyr < 6; ++lyr) {
        cvt_k<<<dim3(1024), 256, 0, stream>>>(qkv_w + (size_t)lyr * 3072 * 1024, wq, 3072 * 1024 / 4);
        ln_k<<<dim3(2048), 256, 0, stream>>>(h, ln1_g + lyr * 1024, ln1_b + lyr * 1024, xn);
        gemm256<1, 0, 1><<<dim3(8, 12), 512, 0, stream>>>(
            xn, wq, qkv_b + lyr * 3072, nullptr, qkv, M, 3072, 1024);
        attn_k<<<dim3(16, 16, 2), 256, 0, stream>>>(qkv, ob);
        cvt_k<<<dim3(1024), 256, 0, stream>>>(proj_w + (size_t)lyr * 1024 * 1024, wq, 1024 * 1024 / 4);
        gemm_bt<128, 64, 1, 0, 1, 0><<<dim3(16, 16), 256, 0, stream>>>(
            ob, wq, proj_b + lyr * 1024, h, h, nullptr, M, 1024, 1024);
        ln_k<<<dim3(2048), 256, 0, stream>>>(h, ln2_g + lyr * 1024, ln2_b + lyr * 1024, xn);
        cvt_k<<<dim3(1024), 256, 0, stream>>>(fc1_w + (size_t)lyr * 4096 * 1024, wq, 4096 * 1024 / 4);
        gemm256<1, 1, 1><<<dim3(8, 16), 512, 0, stream>>>(
            xn, wq, fc1_b + lyr * 4096, nullptr, ff, M, 4096, 1024);
        cvt_k<<<dim3(1024), 256, 0, stream>>>(fc2_w + (size_t)lyr * 1024 * 4096, wq, 1024 * 4096 / 4);
        gemm_bt<128, 64, 1, 0, 1, 0><<<dim3(16, 16), 256, 0, stream>>>(
            ff, wq, fc2_b + lyr * 1024, h, h, nullptr, M, 1024, 4096);
    }

    ln_k<<<dim3(2048), 256, 0, stream>>>(h, lnf_g, lnf_b, xn);
    cvt_k<<<dim3(2048), 256, 0, stream>>>(head_w, wq, 32000 * 1024 / 4);
    gemm256<0, 0, 0><<<dim3(8, 125), 512, 0, stream>>>(
        xn, wq, nullptr, out, nullptr, M, 32000, 1024);
}

// Round 4
// 1590.699 us; speedup vs baseline: 1.1189x; 1.1189x over previous
//
#include <hip/hip_runtime.h>

typedef unsigned short u16;
typedef unsigned int   u32;
typedef __bf16 bf16x8 __attribute__((ext_vector_type(8)));
typedef float  f32x4  __attribute__((ext_vector_type(4)));

#define DEV __device__ __forceinline__

DEV u16 f2bf(float f) {
    u32 u = __builtin_bit_cast(u32, f);
    u32 r = u + 0x7FFFu + ((u >> 16) & 1u);
    return (u16)(r >> 16);
}

DEV void gload16(const void* g, void* l) {
    __builtin_amdgcn_global_load_lds((const __attribute__((address_space(1))) void*)g,
                                     (__attribute__((address_space(3))) void*)l, 16, 0, 0);
}

// bijective XCD-aware swizzle (m204)
DEV int xcd_swz(int bid, int nwg) {
    int q = nwg >> 3, r = nwg & 7;
    int xcd = bid & 7, idx = bid >> 3;
    return (xcd < r ? xcd * (q + 1) : r * (q + 1) + (xcd - r) * q) + idx;
}

// involutive LDS byte swizzle for 128B rows (BK=64 bf16): XOR bits[6:4] with row bits[0,2,1]
DEV int swz(int p) {
    int m = (((p >> 7) & 1) << 6) | (((p >> 9) & 1) << 5) | (((p >> 8) & 1) << 4);
    return p ^ m;
}

// ---------------- convert f32 -> bf16 ----------------
__global__ void cvt_k(const float* __restrict__ src, u16* __restrict__ dst, int n4) {
    int i = blockIdx.x * blockDim.x + threadIdx.x;
    int stride = gridDim.x * blockDim.x;
    for (; i < n4; i += stride) {
        float4 v = ((const float4*)src)[i];
        ushort4 u;
        u.x = f2bf(v.x); u.y = f2bf(v.y); u.z = f2bf(v.z); u.w = f2bf(v.w);
        ((ushort4*)dst)[i] = u;
    }
}

// ---------------- embedding ----------------
__global__ void embed_k(const int* __restrict__ x, const float* __restrict__ te,
                        const float* __restrict__ pe, float* __restrict__ h) {
    int row = blockIdx.x;
    int t = threadIdx.x;
    int tok = x[row];
    int s = row & 1023;
    float4 a = ((const float4*)(te + (size_t)tok * 1024))[t];
    float4 p = ((const float4*)(pe + (size_t)s * 1024))[t];
    a.x += p.x; a.y += p.y; a.z += p.z; a.w += p.w;
    ((float4*)(h + (size_t)row * 1024))[t] = a;
}

// ---------------- LayerNorm: f32 in -> bf16 out ----------------
__global__ void ln_k(const float* __restrict__ in, const float* __restrict__ g,
                     const float* __restrict__ b, u16* __restrict__ out) {
    int row = blockIdx.x;
    int t = threadIdx.x;
    float4 v = ((const float4*)(in + (size_t)row * 1024))[t];
    float s = v.x + v.y + v.z + v.w;
    float s2 = v.x * v.x + v.y * v.y + v.z * v.z + v.w * v.w;
    #pragma unroll
    for (int msk = 1; msk < 64; msk <<= 1) {
        s  += __shfl_xor(s, msk);
        s2 += __shfl_xor(s2, msk);
    }
    __shared__ float ps[4], ps2[4];
    if ((t & 63) == 0) { ps[t >> 6] = s; ps2[t >> 6] = s2; }
    __syncthreads();
    s = ps[0] + ps[1] + ps[2] + ps[3];
    s2 = ps2[0] + ps2[1] + ps2[2] + ps2[3];
    float mu = s * (1.0f / 1024.0f);
    float var = s2 * (1.0f / 1024.0f) - mu * mu;
    float rstd = rsqrtf(var + 1e-5f);
    float4 gg = ((const float4*)g)[t];
    float4 bb = ((const float4*)b)[t];
    ushort4 o;
    o.x = f2bf((v.x - mu) * rstd * gg.x + bb.x);
    o.y = f2bf((v.y - mu) * rstd * gg.y + bb.y);
    o.z = f2bf((v.z - mu) * rstd * gg.z + bb.z);
    o.w = f2bf((v.w - mu) * rstd * gg.w + bb.w);
    ((ushort4*)out)[(size_t)row * 256 + t] = o;
}

// ============ 256x256 8-wave 4-phase-per-K-tile GEMM (m201-style, BK=64) ============
// LDS 128KB: A dbuf (2x32KB) + B dbuf (2x32KB). Per K-tile T (4 phases):
//   ph0: read B frags (8xb128) + A mi0,1 (4xb128); stage A(T+1).lo; bar; lgkm0; 16 MFMA; bar
//   ph1: A mi2,3; stage A(T+1).hi; ...   ph2: A mi4,5; stage B(T+2).lo; ...
//   ph3: A mi6,7; stage B(T+2).hi; ...; vmcnt(4); bar   [B(T+2) is the only thing in flight]
template<int PH>
DEV void phase_mma(const bf16x8 (&af)[2][2], const bf16x8 (&bfr)[4][2], f32x4 (&acc)[8][4]) {
    __builtin_amdgcn_s_barrier();
    asm volatile("s_waitcnt lgkmcnt(0)" ::: "memory");
    __builtin_amdgcn_sched_barrier(0);
    __builtin_amdgcn_s_setprio(1);
    #pragma unroll
    for (int ms = 0; ms < 2; ++ms)
        #pragma unroll
        for (int nj = 0; nj < 4; ++nj)
            #pragma unroll
            for (int kk = 0; kk < 2; ++kk)
                acc[PH * 2 + ms][nj] = __builtin_amdgcn_mfma_f32_16x16x32_bf16(
                    af[ms][kk], bfr[nj][kk], acc[PH * 2 + ms][nj], 0, 0, 0);
    __builtin_amdgcn_s_setprio(0);
}

template<int PH>
DEV void read_afrags(const char* Ab, int arow, int fr, int fq, bf16x8 (&af)[2][2]) {
    #pragma unroll
    for (int ms = 0; ms < 2; ++ms)
        #pragma unroll
        for (int kk = 0; kk < 2; ++kk) {
            int lin = (arow + (PH * 2 + ms) * 16 + fr) * 128 + kk * 64 + fq * 16;
            af[ms][kk] = *(const bf16x8*)(Ab + swz(lin));
        }
}

template<int BIAS, int OUTBF>
__global__ __launch_bounds__(512, 2)
void gemm8p(const u16* __restrict__ A, const u16* __restrict__ Bw,
            const float* __restrict__ bias,
            float* __restrict__ outf, u16* __restrict__ outb,
            int M, int N, int K) {
    __shared__ char lds[131072];
    char* ldsA = lds;              // A0 @0, A1 @32768
    char* ldsB = lds + 65536;      // B0 @65536, B1 @98304
    const int t = threadIdx.x;
    const int w = t >> 6, l = t & 63;
    const int fr = l & 15, fq = l >> 4;
    const int wm = w >> 2, wn = w & 3;

    int bid = blockIdx.y * gridDim.x + blockIdx.x;
    int swzb = xcd_swz(bid, gridDim.x * gridDim.y);
    const int m0 = (swzb % gridDim.x) * 256;
    const int n0 = (swzb / gridDim.x) * 256;
    const int nt = K >> 6;
    const int arow = wm * 128;

    const u16* Asrc = A + (size_t)m0 * K;
    const u16* Bsrc = Bw + (size_t)n0 * K;

    // per-thread staging offsets (u16 units), h=half, j=load index; LDS phys p -> logical via swz
    size_t o00, o01, o10, o11;
    {
        int p;
        p = 0 * 16384 + 0 * 8192 + t * 16; o00 = (size_t)(p >> 7) * K + ((swz(p) & 127) >> 1);
        p = 0 * 16384 + 1 * 8192 + t * 16; o01 = (size_t)(p >> 7) * K + ((swz(p) & 127) >> 1);
        p = 1 * 16384 + 0 * 8192 + t * 16; o10 = (size_t)(p >> 7) * K + ((swz(p) & 127) >> 1);
        p = 1 * 16384 + 1 * 8192 + t * 16; o11 = (size_t)(p >> 7) * K + ((swz(p) & 127) >> 1);
    }
    const int wb = w * 1024;

    // prologue: A(0)->A0, B(0)->B0, B(1)->B1; wait for A0+B0 (B1 stays in flight)
    gload16(Asrc + o00, ldsA + wb);
    gload16(Asrc + o01, ldsA + 8192 + wb);
    gload16(Asrc + o10, ldsA + 16384 + wb);
    gload16(Asrc + o11, ldsA + 16384 + 8192 + wb);
    gload16(Bsrc + o00, ldsB + wb);
    gload16(Bsrc + o01, ldsB + 8192 + wb);
    gload16(Bsrc + o10, ldsB + 16384 + wb);
    gload16(Bsrc + o11, ldsB + 16384 + 8192 + wb);
    gload16(Bsrc + o00 + 64, ldsB + 32768 + wb);
    gload16(Bsrc + o01 + 64, ldsB + 32768 + 8192 + wb);
    gload16(Bsrc + o10 + 64, ldsB + 32768 + 16384 + wb);
    gload16(Bsrc + o11 + 64, ldsB + 32768 + 16384 + 8192 + wb);
    asm volatile("s_waitcnt vmcnt(4)" ::: "memory");
    __builtin_amdgcn_s_barrier();
    __builtin_amdgcn_sched_barrier(0);

    f32x4 acc[8][4] = {};

    for (int T = 0; T < nt; ++T) {
        const char* Ab = ldsA + (T & 1) * 32768;
        const char* Bb = ldsB + (T & 1) * 32768;
        char* Anx = ldsA + ((T + 1) & 1) * 32768;
        char* Bnx = ldsB + (T & 1) * 32768;            // B(T+2) parity == T parity
        const bool stA = (T + 1 < nt), stB = (T + 2 < nt);
        const size_t kA = (size_t)(T + 1) * 64, kB = (size_t)(T + 2) * 64;

        bf16x8 bfr[4][2], af[2][2];

        // ---- phase 0: B frags + A mi0,1; stage A(T+1).lo ----
        #pragma unroll
        for (int nj = 0; nj < 4; ++nj)
            #pragma unroll
            for (int kk = 0; kk < 2; ++kk) {
                int lin = (wn * 64 + nj * 16 + fr) * 128 + kk * 64 + fq * 16;
                bfr[nj][kk] = *(const bf16x8*)(Bb + swz(lin));
            }
        read_afrags<0>(Ab, arow, fr, fq, af);
        if (stA) {
            gload16(Asrc + o00 + kA, Anx + wb);
            gload16(Asrc + o01 + kA, Anx + 8192 + wb);
        }
        phase_mma<0>(af, bfr, acc);
        __builtin_amdgcn_s_barrier();

        // ---- phase 1: A mi2,3; stage A(T+1).hi ----
        read_afrags<1>(Ab, arow, fr, fq, af);
        if (stA) {
            gload16(Asrc + o10 + kA, Anx + 16384 + wb);
            gload16(Asrc + o11 + kA, Anx + 16384 + 8192 + wb);
        }
        phase_mma<1>(af, bfr, acc);
        __builtin_amdgcn_s_barrier();

        // ---- phase 2: A mi4,5; stage B(T+2).lo ----
        read_afrags<2>(Ab, arow, fr, fq, af);
        if (stB) {
            gload16(Bsrc + o00 + kB, Bnx + wb);
            gload16(Bsrc + o01 + kB, Bnx + 8192 + wb);
        }
        phase_mma<2>(af, bfr, acc);
        __builtin_amdgcn_s_barrier();

        // ---- phase 3: A mi6,7; stage B(T+2).hi; counted vmcnt at K-tile boundary ----
        read_afrags<3>(Ab, arow, fr, fq, af);
        if (stB) {
            gload16(Bsrc + o10 + kB, Bnx + 16384 + wb);
            gload16(Bsrc + o11 + kB, Bnx + 16384 + 8192 + wb);
        }
        phase_mma<3>(af, bfr, acc);
        if (stB)      asm volatile("s_waitcnt vmcnt(4)" ::: "memory");
        else if (stA) asm volatile("s_waitcnt vmcnt(0)" ::: "memory");
        __builtin_amdgcn_s_barrier();
        __builtin_amdgcn_sched_barrier(0);
    }

    // epilogue
    #pragma unroll
    for (int mi = 0; mi < 8; ++mi) {
        #pragma unroll
        for (int nj = 0; nj < 4; ++nj) {
            #pragma unroll
            for (int r = 0; r < 4; ++r) {
                int row = m0 + wm * 128 + mi * 16 + fq * 4 + r;
                int col = n0 + wn * 64 + nj * 16 + fr;
                float v = acc[mi][nj][r];
                if (BIAS) v += bias[col];
                if (OUTBF) outb[(size_t)row * N + col] = f2bf(v);
                else       outf[(size_t)row * N + col] = v;
            }
        }
    }
}

// ---------------- 128-tile GEMM (2-barrier structure, measured-good for mid sizes) ----------------
template<int BM, int BN, int BIAS, int GELU_, int RES, int OUTBF>
__global__ void gemm_bt(const u16* __restrict__ A, const u16* __restrict__ Bw,
                        const float* __restrict__ bias, const float* __restrict__ res,
                        float* __restrict__ outf, u16* __restrict__ outb,
                        int M, int N, int K) {
    constexpr int MR = BM / 32;
    constexpr int NR = BN / 32;
    constexpr int AL = BM / 64;
    constexpr int BL = BN / 64;
    __shared__ u16 lA[BM * 32];
    __shared__ u16 lB[BN * 32];
    const int t = threadIdx.x;
    const int w = t >> 6, l = t & 63;

    int bid = blockIdx.y * gridDim.x + blockIdx.x;
    int swzb = xcd_swz(bid, gridDim.x * gridDim.y);
    const int m0 = (swzb % gridDim.x) * BM;
    const int n0 = (swzb / gridDim.x) * BN;

    const int wr = (w >> 1) * (BM / 2), wc = (w & 1) * (BN / 2);
    const int fr = l & 15, fq = l >> 4;

    f32x4 acc[MR][NR] = {};
    const int g0 = w * 64 + l;

    for (int k0 = 0; k0 < K; k0 += 32) {
        #pragma unroll
        for (int i = 0; i < AL; ++i) {
            int g = g0 + i * 256;
            int row = g >> 2, c = (g & 3) * 8;
            gload16(A + (size_t)(m0 + row) * K + k0 + c, lA + w * 512 + i * 2048);
        }
        #pragma unroll
        for (int i = 0; i < BL; ++i) {
            int g = g0 + i * 256;
            int row = g >> 2, c = (g & 3) * 8;
            gload16(Bw + (size_t)(n0 + row) * K + k0 + c, lB + w * 512 + i * 2048);
        }
        __syncthreads();
        bf16x8 af[MR], bfv[NR];
        #pragma unroll
        for (int mi = 0; mi < MR; ++mi)
            af[mi] = *(const bf16x8*)(lA + (wr + mi * 16 + fr) * 32 + fq * 8);
        #pragma unroll
        for (int ni = 0; ni < NR; ++ni)
            bfv[ni] = *(const bf16x8*)(lB + (wc + ni * 16 + fr) * 32 + fq * 8);
        #pragma unroll
        for (int mi = 0; mi < MR; ++mi)
            #pragma unroll
            for (int ni = 0; ni < NR; ++ni)
                acc[mi][ni] = __builtin_amdgcn_mfma_f32_16x16x32_bf16(af[mi], bfv[ni], acc[mi][ni], 0, 0, 0);
        __syncthreads();
    }

    #pragma unroll
    for (int mi = 0; mi < MR; ++mi) {
        #pragma unroll
        for (int ni = 0; ni < NR; ++ni) {
            #pragma unroll
            for (int r = 0; r < 4; ++r) {
                int row = m0 + wr + mi * 16 + fq * 4 + r;
                int col = n0 + wc + ni * 16 + fr;
                float v = acc[mi][ni][r];
                if (BIAS) v += bias[col];
                if (GELU_) v = 0.5f * v * (1.0f + erff(v * 0.70710678118f));
                if (RES) v += res[(size_t)row * N + col];
                if (OUTBF) outb[(size_t)row * N + col] = f2bf(v);
                else       outf[(size_t)row * N + col] = v;
            }
        }
    }
}

// ---------------- Flash attention ----------------
__global__ void attn_k(const u16* __restrict__ qkv, u16* __restrict__ o) {
    __shared__ u16 lK[64 * 64];
    __shared__ u16 lV[64 * 64];
    __shared__ u16 lP[4 * 16 * 64];
    const int t = threadIdx.x;
    const int w = t >> 6, l = t & 63;
    const int fr = l & 15, fq = l >> 4;
    const int b = blockIdx.z, hh = blockIdx.y;
    const int qb = gridDim.x - 1 - blockIdx.x;
    const int q0 = qb * 64;

    bf16x8 qf[2];
    {
        size_t base = ((size_t)(b * 1024) + q0 + w * 16 + fr) * 3072 + hh * 64;
        qf[0] = *(const bf16x8*)(qkv + base + fq * 8);
        qf[1] = *(const bf16x8*)(qkv + base + 32 + fq * 8);
    }

    float m_run[4], l_run[4];
    f32x4 acc_o[4] = {};
    #pragma unroll
    for (int r = 0; r < 4; ++r) { m_run[r] = -__builtin_inff(); l_run[r] = 0.0f; }

    for (int kv0 = 0; kv0 <= q0; kv0 += 64) {
        #pragma unroll
        for (int i = 0; i < 2; ++i) {
            int g = w * 64 + l + i * 256;
            int row = g >> 3, c = (g & 7) * 8;
            gload16(qkv + ((size_t)(b * 1024) + kv0 + row) * 3072 + 1024 + hh * 64 + c,
                    lK + w * 512 + i * 2048);
        }
        #pragma unroll
        for (int i = 0; i < 2; ++i) {
            int g = t + i * 256;
            int kv = g >> 3, d0 = (g & 7) * 8;
            const u32* gv = (const u32*)(qkv + ((size_t)(b * 1024) + kv0 + kv) * 3072 + 2048 + hh * 64 + d0);
            u32 v0 = gv[0], v1 = gv[1], v2 = gv[2], v3 = gv[3];
            u16 e[8] = { (u16)v0, (u16)(v0 >> 16), (u16)v1, (u16)(v1 >> 16),
                         (u16)v2, (u16)(v2 >> 16), (u16)v3, (u16)(v3 >> 16) };
            #pragma unroll
            for (int j = 0; j < 8; ++j) lV[(d0 + j) * 64 + kv] = e[j];
        }
        __syncthreads();

        f32x4 accs[4] = {};
        #pragma unroll
        for (int nt = 0; nt < 4; ++nt) {
            #pragma unroll
            for (int ks = 0; ks < 2; ++ks) {
                bf16x8 kf = *(const bf16x8*)(lK + (nt * 16 + fr) * 64 + ks * 32 + fq * 8);
                accs[nt] = __builtin_amdgcn_mfma_f32_16x16x32_bf16(qf[ks], kf, accs[nt], 0, 0, 0);
            }
        }

        float p[4][4], mx[4], rs[4];
        #pragma unroll
        for (int r = 0; r < 4; ++r) {
            int qg = q0 + w * 16 + fq * 4 + r;
            float m = -__builtin_inff();
            #pragma unroll
            for (int nt = 0; nt < 4; ++nt) {
                int kvg = kv0 + nt * 16 + fr;
                float s = (kvg <= qg) ? accs[nt][r] * 0.125f : -__builtin_inff();
                p[nt][r] = s;
                m = fmaxf(m, s);
            }
            mx[r] = m;
        }
        #pragma unroll
        for (int msk = 1; msk < 16; msk <<= 1) {
            #pragma unroll
            for (int r = 0; r < 4; ++r) mx[r] = fmaxf(mx[r], __shfl_xor(mx[r], msk));
        }
        float mnew[4], alpha[4];
        #pragma unroll
        for (int r = 0; r < 4; ++r) {
            mnew[r] = fmaxf(m_run[r], mx[r]);
            alpha[r] = __expf(m_run[r] - mnew[r]);
            float s = 0.0f;
            #pragma unroll
            for (int nt = 0; nt < 4; ++nt) {
                float pv = __expf(p[nt][r] - mnew[r]);
                p[nt][r] = pv;
                s += pv;
            }
            rs[r] = s;
        }
        #pragma unroll
        for (int msk = 1; msk < 16; msk <<= 1) {
            #pragma unroll
            for (int r = 0; r < 4; ++r) rs[r] += __shfl_xor(rs[r], msk);
        }
        #pragma unroll
        for (int r = 0; r < 4; ++r) {
            l_run[r] = l_run[r] * alpha[r] + rs[r];
            m_run[r] = mnew[r];
        }
        #pragma unroll
        for (int nt = 0; nt < 4; ++nt)
            #pragma unroll
            for (int r = 0; r < 4; ++r) acc_o[nt][r] *= alpha[r];

        #pragma unroll
        for (int nt = 0; nt < 4; ++nt)
            #pragma unroll
            for (int r = 0; r < 4; ++r)
                lP[w * 1024 + (fq * 4 + r) * 64 + nt * 16 + fr] = f2bf(p[nt][r]);
        __syncthreads();

        bf16x8 pa[2];
        pa[0] = *(const bf16x8*)(lP + w * 1024 + fr * 64 + fq * 8);
        pa[1] = *(const bf16x8*)(lP + w * 1024 + fr * 64 + 32 + fq * 8);
        #pragma unroll
        for (int nt = 0; nt < 4; ++nt) {
            #pragma unroll
            for (int ks = 0; ks < 2; ++ks) {
                bf16x8 vf = *(const bf16x8*)(lV + (nt * 16 + fr) * 64 + ks * 32 + fq * 8);
                acc_o[nt] = __builtin_amdgcn_mfma_f32_16x16x32_bf16(pa[ks], vf, acc_o[nt], 0, 0, 0);
            }
        }
        __syncthreads();
    }

    #pragma unroll
    for (int nt = 0; nt < 4; ++nt) {
        #pragma unroll
        for (int r = 0; r < 4; ++r) {
            int qg = q0 + w * 16 + fq * 4 + r;
            int d = nt * 16 + fr;
            float ov = acc_o[nt][r] / l_run[r];
            o[((size_t)(b * 1024) + qg) * 1024 + hh * 64 + d] = f2bf(ov);
        }
    }
}

// ---------------- launch ----------------
extern "C" void kernel_launch(void* const* d_in, const int* in_sizes, int n_in,
                              void* d_out, int out_size, void* d_ws, size_t ws_size,
                              hipStream_t stream) {
    const int*   x       = (const int*)  d_in[0];
    const float* tok_emb = (const float*)d_in[1];
    const float* pos_emb = (const float*)d_in[2];
    const float* ln1_g   = (const float*)d_in[3];
    const float* ln1_b   = (const float*)d_in[4];
    const float* qkv_w   = (const float*)d_in[5];
    const float* qkv_b   = (const float*)d_in[6];
    const float* proj_w  = (const float*)d_in[7];
    const float* proj_b  = (const float*)d_in[8];
    const float* ln2_g   = (const float*)d_in[9];
    const float* ln2_b   = (const float*)d_in[10];
    const float* fc1_w   = (const float*)d_in[11];
    const float* fc1_b   = (const float*)d_in[12];
    const float* fc2_w   = (const float*)d_in[13];
    const float* fc2_b   = (const float*)d_in[14];
    const float* lnf_g   = (const float*)d_in[15];
    const float* lnf_b   = (const float*)d_in[16];
    const float* head_w  = (const float*)d_in[17];
    float* out = (float*)d_out;

    char* ws = (char*)d_ws;
    float* h   = (float*)(ws + 0);            //  8 MB f32 (2048x1024)
    u16*   xn  = (u16*)(ws + 8388608);        //  4 MB bf16
    u16*   qkv = (u16*)(ws + 12582912);       // 12.6 MB bf16 (2048x3072)
    u16*   ob  = (u16*)(ws + 25165824);       //  4 MB bf16
    u16*   ff  = (u16*)(ws + 29360128);       // 16.8 MB bf16 (2048x4096)
    u16*   wq  = (u16*)(ws + 46137344);       // 65.5 MB bf16 weight slab

    const int M = 2048;

    embed_k<<<dim3(2048), 256, 0, stream>>>(x, tok_emb, pos_emb, h);

    for (int lyr = 0; lyr < 6; ++lyr) {
        cvt_k<<<dim3(1024), 256, 0, stream>>>(qkv_w + (size_t)lyr * 3072 * 1024, wq, 3072 * 1024 / 4);
        ln_k<<<dim3(2048), 256, 0, stream>>>(h, ln1_g + lyr * 1024, ln1_b + lyr * 1024, xn);
        gemm_bt<128, 128, 1, 0, 0, 1><<<dim3(16, 24), 256, 0, stream>>>(
            xn, wq, qkv_b + lyr * 3072, nullptr, nullptr, qkv, M, 3072, 1024);
        attn_k<<<dim3(16, 16, 2), 256, 0, stream>>>(qkv, ob);
        cvt_k<<<dim3(1024), 256, 0, stream>>>(proj_w + (size_t)lyr * 1024 * 1024, wq, 1024 * 1024 / 4);
        gemm_bt<128, 64, 1, 0, 1, 0><<<dim3(16, 16), 256, 0, stream>>>(
            ob, wq, proj_b + lyr * 1024, h, h, nullptr, M, 1024, 1024);
        ln_k<<<dim3(2048), 256, 0, stream>>>(h, ln2_g + lyr * 1024, ln2_b + lyr * 1024, xn);
        cvt_k<<<dim3(1024), 256, 0, stream>>>(fc1_w + (size_t)lyr * 4096 * 1024, wq, 4096 * 1024 / 4);
        gemm_bt<128, 128, 1, 1, 0, 1><<<dim3(16, 32), 256, 0, stream>>>(
            xn, wq, fc1_b + lyr * 4096, nullptr, nullptr, ff, M, 4096, 1024);
        cvt_k<<<dim3(1024), 256, 0, stream>>>(fc2_w + (size_t)lyr * 1024 * 4096, wq, 1024 * 4096 / 4);
        gemm_bt<128, 64, 1, 0, 1, 0><<<dim3(16, 16), 256, 0, stream>>>(
            ff, wq, fc2_b + lyr * 1024, h, h, nullptr, M, 1024, 4096);
    }

    ln_k<<<dim3(2048), 256, 0, stream>>>(h, lnf_g, lnf_b, xn);
    cvt_k<<<dim3(2048), 256, 0, stream>>>(head_w, wq, 32000 * 1024 / 4);
    gemm8p<0, 0><<<dim3(8, 125), 512, 0, stream>>>(
        xn, wq, nullptr, out, nullptr, M, 32000, 1024);
}

// Round 5
// 1502.855 us; speedup vs baseline: 1.1843x; 1.0585x over previous
//
#include <hip/hip_runtime.h>

typedef unsigned short u16;
typedef unsigned int   u32;
typedef __bf16 bf16x8 __attribute__((ext_vector_type(8)));
typedef float  f32x4  __attribute__((ext_vector_type(4)));

#define DEV __device__ __forceinline__

DEV u16 f2bf(float f) {
    u32 u = __builtin_bit_cast(u32, f);
    u32 r = u + 0x7FFFu + ((u >> 16) & 1u);
    return (u16)(r >> 16);
}

DEV void gload16(const void* g, void* l) {
    __builtin_amdgcn_global_load_lds((const __attribute__((address_space(1))) void*)g,
                                     (__attribute__((address_space(3))) void*)l, 16, 0, 0);
}

// bijective XCD-aware swizzle (m204)
DEV int xcd_swz(int bid, int nwg) {
    int q = nwg >> 3, r = nwg & 7;
    int xcd = bid & 7, idx = bid >> 3;
    return (xcd < r ? xcd * (q + 1) : r * (q + 1) + (xcd - r) * q) + idx;
}

// involutive LDS byte swizzle for 128B rows: XOR byte bits[6:4] with row bits [0,2,1]
DEV int swz(int p) {
    int m = (((p >> 7) & 1) << 6) | (((p >> 9) & 1) << 5) | (((p >> 8) & 1) << 4);
    return p ^ m;
}

// ---------------- convert f32 -> bf16 (single tensor) ----------------
__global__ void cvt_k(const float* __restrict__ src, u16* __restrict__ dst, int n4) {
    int i = blockIdx.x * blockDim.x + threadIdx.x;
    int stride = gridDim.x * blockDim.x;
    for (; i < n4; i += stride) {
        float4 v = ((const float4*)src)[i];
        ushort4 u;
        u.x = f2bf(v.x); u.y = f2bf(v.y); u.z = f2bf(v.z); u.w = f2bf(v.w);
        ((ushort4*)dst)[i] = u;
    }
}

// ---------------- convert 4 tensors in one launch (per-layer weights) ----------------
__global__ void cvt4_k(const float* __restrict__ s0, const float* __restrict__ s1,
                       const float* __restrict__ s2, const float* __restrict__ s3,
                       u16* __restrict__ dst, int n0, int n1, int n2, int n3) {
    int i = blockIdx.x * blockDim.x + threadIdx.x;
    int stride = gridDim.x * blockDim.x;
    int t0 = n0, t1 = t0 + n1, t2 = t1 + n2, t3 = t2 + n3;
    for (; i < t3; i += stride) {
        const float* s; int j;
        if (i < t0)      { s = s0; j = i; }
        else if (i < t1) { s = s1; j = i - t0; }
        else if (i < t2) { s = s2; j = i - t1; }
        else             { s = s3; j = i - t2; }
        float4 v = ((const float4*)s)[j];
        ushort4 u;
        u.x = f2bf(v.x); u.y = f2bf(v.y); u.z = f2bf(v.z); u.w = f2bf(v.w);
        ((ushort4*)dst)[i] = u;
    }
}

// ---------------- embedding ----------------
__global__ void embed_k(const int* __restrict__ x, const float* __restrict__ te,
                        const float* __restrict__ pe, float* __restrict__ h) {
    int row = blockIdx.x;
    int t = threadIdx.x;
    int tok = x[row];
    int s = row & 1023;
    float4 a = ((const float4*)(te + (size_t)tok * 1024))[t];
    float4 p = ((const float4*)(pe + (size_t)s * 1024))[t];
    a.x += p.x; a.y += p.y; a.z += p.z; a.w += p.w;
    ((float4*)(h + (size_t)row * 1024))[t] = a;
}

// ---------------- LayerNorm: f32 in -> bf16 out ----------------
__global__ void ln_k(const float* __restrict__ in, const float* __restrict__ g,
                     const float* __restrict__ b, u16* __restrict__ out) {
    int row = blockIdx.x;
    int t = threadIdx.x;
    float4 v = ((const float4*)(in + (size_t)row * 1024))[t];
    float s = v.x + v.y + v.z + v.w;
    float s2 = v.x * v.x + v.y * v.y + v.z * v.z + v.w * v.w;
    #pragma unroll
    for (int msk = 1; msk < 64; msk <<= 1) {
        s  += __shfl_xor(s, msk);
        s2 += __shfl_xor(s2, msk);
    }
    __shared__ float ps[4], ps2[4];
    if ((t & 63) == 0) { ps[t >> 6] = s; ps2[t >> 6] = s2; }
    __syncthreads();
    s = ps[0] + ps[1] + ps[2] + ps[3];
    s2 = ps2[0] + ps2[1] + ps2[2] + ps2[3];
    float mu = s * (1.0f / 1024.0f);
    float var = s2 * (1.0f / 1024.0f) - mu * mu;
    float rstd = rsqrtf(var + 1e-5f);
    float4 gg = ((const float4*)g)[t];
    float4 bb = ((const float4*)b)[t];
    ushort4 o;
    o.x = f2bf((v.x - mu) * rstd * gg.x + bb.x);
    o.y = f2bf((v.y - mu) * rstd * gg.y + bb.y);
    o.z = f2bf((v.z - mu) * rstd * gg.z + bb.z);
    o.w = f2bf((v.w - mu) * rstd * gg.w + bb.w);
    ((ushort4*)out)[(size_t)row * 256 + t] = o;
}

// ============ 256x256 8-wave 4-phase-per-K-tile GEMM (BK=64, counted vmcnt) ============
template<int PH>
DEV void phase_mma(const bf16x8 (&af)[2][2], const bf16x8 (&bfr)[4][2], f32x4 (&acc)[8][4]) {
    __builtin_amdgcn_s_barrier();
    asm volatile("s_waitcnt lgkmcnt(0)" ::: "memory");
    __builtin_amdgcn_sched_barrier(0);
    __builtin_amdgcn_s_setprio(1);
    #pragma unroll
    for (int ms = 0; ms < 2; ++ms)
        #pragma unroll
        for (int nj = 0; nj < 4; ++nj)
            #pragma unroll
            for (int kk = 0; kk < 2; ++kk)
                acc[PH * 2 + ms][nj] = __builtin_amdgcn_mfma_f32_16x16x32_bf16(
                    af[ms][kk], bfr[nj][kk], acc[PH * 2 + ms][nj], 0, 0, 0);
    __builtin_amdgcn_s_setprio(0);
}

template<int PH>
DEV void read_afrags(const char* Ab, int arow, int fr, int fq, bf16x8 (&af)[2][2]) {
    #pragma unroll
    for (int ms = 0; ms < 2; ++ms)
        #pragma unroll
        for (int kk = 0; kk < 2; ++kk) {
            int lin = (arow + (PH * 2 + ms) * 16 + fr) * 128 + kk * 64 + fq * 16;
            af[ms][kk] = *(const bf16x8*)(Ab + swz(lin));
        }
}

template<int BIAS, int OUTBF>
__global__ __launch_bounds__(512, 2)
void gemm8p(const u16* __restrict__ A, const u16* __restrict__ Bw,
            const float* __restrict__ bias,
            float* __restrict__ outf, u16* __restrict__ outb,
            int M, int N, int K) {
    __shared__ char lds[131072];
    char* ldsA = lds;
    char* ldsB = lds + 65536;
    const int t = threadIdx.x;
    const int w = t >> 6, l = t & 63;
    const int fr = l & 15, fq = l >> 4;
    const int wm = w >> 2, wn = w & 3;

    int bid = blockIdx.y * gridDim.x + blockIdx.x;
    int swzb = xcd_swz(bid, gridDim.x * gridDim.y);
    const int m0 = (swzb % gridDim.x) * 256;
    const int n0 = (swzb / gridDim.x) * 256;
    const int nt = K >> 6;
    const int arow = wm * 128;

    const u16* Asrc = A + (size_t)m0 * K;
    const u16* Bsrc = Bw + (size_t)n0 * K;

    size_t o00, o01, o10, o11;
    {
        int p;
        p = 0 * 16384 + 0 * 8192 + t * 16; o00 = (size_t)(p >> 7) * K + ((swz(p) & 127) >> 1);
        p = 0 * 16384 + 1 * 8192 + t * 16; o01 = (size_t)(p >> 7) * K + ((swz(p) & 127) >> 1);
        p = 1 * 16384 + 0 * 8192 + t * 16; o10 = (size_t)(p >> 7) * K + ((swz(p) & 127) >> 1);
        p = 1 * 16384 + 1 * 8192 + t * 16; o11 = (size_t)(p >> 7) * K + ((swz(p) & 127) >> 1);
    }
    const int wb = w * 1024;

    gload16(Asrc + o00, ldsA + wb);
    gload16(Asrc + o01, ldsA + 8192 + wb);
    gload16(Asrc + o10, ldsA + 16384 + wb);
    gload16(Asrc + o11, ldsA + 16384 + 8192 + wb);
    gload16(Bsrc + o00, ldsB + wb);
    gload16(Bsrc + o01, ldsB + 8192 + wb);
    gload16(Bsrc + o10, ldsB + 16384 + wb);
    gload16(Bsrc + o11, ldsB + 16384 + 8192 + wb);
    gload16(Bsrc + o00 + 64, ldsB + 32768 + wb);
    gload16(Bsrc + o01 + 64, ldsB + 32768 + 8192 + wb);
    gload16(Bsrc + o10 + 64, ldsB + 32768 + 16384 + wb);
    gload16(Bsrc + o11 + 64, ldsB + 32768 + 16384 + 8192 + wb);
    asm volatile("s_waitcnt vmcnt(4)" ::: "memory");
    __builtin_amdgcn_s_barrier();
    __builtin_amdgcn_sched_barrier(0);

    f32x4 acc[8][4] = {};

    for (int T = 0; T < nt; ++T) {
        const char* Ab = ldsA + (T & 1) * 32768;
        const char* Bb = ldsB + (T & 1) * 32768;
        char* Anx = ldsA + ((T + 1) & 1) * 32768;
        char* Bnx = ldsB + (T & 1) * 32768;
        const bool stA = (T + 1 < nt), stB = (T + 2 < nt);
        const size_t kA = (size_t)(T + 1) * 64, kB = (size_t)(T + 2) * 64;

        bf16x8 bfr[4][2], af[2][2];

        #pragma unroll
        for (int nj = 0; nj < 4; ++nj)
            #pragma unroll
            for (int kk = 0; kk < 2; ++kk) {
                int lin = (wn * 64 + nj * 16 + fr) * 128 + kk * 64 + fq * 16;
                bfr[nj][kk] = *(const bf16x8*)(Bb + swz(lin));
            }
        read_afrags<0>(Ab, arow, fr, fq, af);
        if (stA) {
            gload16(Asrc + o00 + kA, Anx + wb);
            gload16(Asrc + o01 + kA, Anx + 8192 + wb);
        }
        phase_mma<0>(af, bfr, acc);
        __builtin_amdgcn_s_barrier();

        read_afrags<1>(Ab, arow, fr, fq, af);
        if (stA) {
            gload16(Asrc + o10 + kA, Anx + 16384 + wb);
            gload16(Asrc + o11 + kA, Anx + 16384 + 8192 + wb);
        }
        phase_mma<1>(af, bfr, acc);
        __builtin_amdgcn_s_barrier();

        read_afrags<2>(Ab, arow, fr, fq, af);
        if (stB) {
            gload16(Bsrc + o00 + kB, Bnx + wb);
            gload16(Bsrc + o01 + kB, Bnx + 8192 + wb);
        }
        phase_mma<2>(af, bfr, acc);
        __builtin_amdgcn_s_barrier();

        read_afrags<3>(Ab, arow, fr, fq, af);
        if (stB) {
            gload16(Bsrc + o10 + kB, Bnx + 16384 + wb);
            gload16(Bsrc + o11 + kB, Bnx + 16384 + 8192 + wb);
        }
        phase_mma<3>(af, bfr, acc);
        if (stB)      asm volatile("s_waitcnt vmcnt(4)" ::: "memory");
        else if (stA) asm volatile("s_waitcnt vmcnt(0)" ::: "memory");
        __builtin_amdgcn_s_barrier();
        __builtin_amdgcn_sched_barrier(0);
    }

    #pragma unroll
    for (int mi = 0; mi < 8; ++mi) {
        #pragma unroll
        for (int nj = 0; nj < 4; ++nj) {
            #pragma unroll
            for (int r = 0; r < 4; ++r) {
                int row = m0 + wm * 128 + mi * 16 + fq * 4 + r;
                int col = n0 + wn * 64 + nj * 16 + fr;
                float v = acc[mi][nj][r];
                if (BIAS) v += bias[col];
                if (OUTBF) outb[(size_t)row * N + col] = f2bf(v);
                else       outf[(size_t)row * N + col] = v;
            }
        }
    }
}

// ---------------- 128-tile GEMM (2-barrier structure) ----------------
template<int BM, int BN, int BIAS, int GELU_, int RES, int OUTBF>
__global__ void gemm_bt(const u16* __restrict__ A, const u16* __restrict__ Bw,
                        const float* __restrict__ bias, const float* __restrict__ res,
                        float* __restrict__ outf, u16* __restrict__ outb,
                        int M, int N, int K) {
    constexpr int MR = BM / 32;
    constexpr int NR = BN / 32;
    constexpr int AL = BM / 64;
    constexpr int BL = BN / 64;
    __shared__ u16 lA[BM * 32];
    __shared__ u16 lB[BN * 32];
    const int t = threadIdx.x;
    const int w = t >> 6, l = t & 63;

    int bid = blockIdx.y * gridDim.x + blockIdx.x;
    int swzb = xcd_swz(bid, gridDim.x * gridDim.y);
    const int m0 = (swzb % gridDim.x) * BM;
    const int n0 = (swzb / gridDim.x) * BN;

    const int wr = (w >> 1) * (BM / 2), wc = (w & 1) * (BN / 2);
    const int fr = l & 15, fq = l >> 4;

    f32x4 acc[MR][NR] = {};
    const int g0 = w * 64 + l;

    for (int k0 = 0; k0 < K; k0 += 32) {
        #pragma unroll
        for (int i = 0; i < AL; ++i) {
            int g = g0 + i * 256;
            int row = g >> 2, c = (g & 3) * 8;
            gload16(A + (size_t)(m0 + row) * K + k0 + c, lA + w * 512 + i * 2048);
        }
        #pragma unroll
        for (int i = 0; i < BL; ++i) {
            int g = g0 + i * 256;
            int row = g >> 2, c = (g & 3) * 8;
            gload16(Bw + (size_t)(n0 + row) * K + k0 + c, lB + w * 512 + i * 2048);
        }
        __syncthreads();
        bf16x8 af[MR], bfv[NR];
        #pragma unroll
        for (int mi = 0; mi < MR; ++mi)
            af[mi] = *(const bf16x8*)(lA + (wr + mi * 16 + fr) * 32 + fq * 8);
        #pragma unroll
        for (int ni = 0; ni < NR; ++ni)
            bfv[ni] = *(const bf16x8*)(lB + (wc + ni * 16 + fr) * 32 + fq * 8);
        #pragma unroll
        for (int mi = 0; mi < MR; ++mi)
            #pragma unroll
            for (int ni = 0; ni < NR; ++ni)
                acc[mi][ni] = __builtin_amdgcn_mfma_f32_16x16x32_bf16(af[mi], bfv[ni], acc[mi][ni], 0, 0, 0);
        __syncthreads();
    }

    #pragma unroll
    for (int mi = 0; mi < MR; ++mi) {
        #pragma unroll
        for (int ni = 0; ni < NR; ++ni) {
            #pragma unroll
            for (int r = 0; r < 4; ++r) {
                int row = m0 + wr + mi * 16 + fq * 4 + r;
                int col = n0 + wc + ni * 16 + fr;
                float v = acc[mi][ni][r];
                if (BIAS) v += bias[col];
                if (GELU_) v = 0.5f * v * (1.0f + erff(v * 0.70710678118f));
                if (RES) v += res[(size_t)row * N + col];
                if (OUTBF) outb[(size_t)row * N + col] = f2bf(v);
                else       outf[(size_t)row * N + col] = v;
            }
        }
    }
}

// ---------------- Flash attention (swizzled LDS, XCD-chunked grid) ----------------
__global__ void attn_k(const u16* __restrict__ qkv, u16* __restrict__ o) {
    __shared__ u16 lK[64 * 64];
    __shared__ u16 lV[64 * 64];       // transposed: [d][kv], swizzled
    __shared__ u16 lP[4 * 16 * 64];   // swizzled
    const int t = threadIdx.x;
    const int w = t >> 6, l = t & 63;
    const int fr = l & 15, fq = l >> 4;

    // flattened grid (512): XCD-chunked so same-(head,batch) groups share an L2;
    // within each chunk qb descends -> long blocks dispatch first
    int swzb = xcd_swz(blockIdx.x, gridDim.x);
    const int qb = 15 - (swzb & 15);
    const int hh = (swzb >> 4) & 15;
    const int b  = swzb >> 8;
    const int q0 = qb * 64;

    // K staging: pre-swizzled per-lane global source, linear LDS dest
    const u16* srcK[2];
    #pragma unroll
    for (int i = 0; i < 2; ++i) {
        int p = (t + i * 256) * 16;
        int L = swz(p);
        srcK[i] = qkv + ((size_t)(b * 1024) + (L >> 7)) * 3072 + 1024 + hh * 64 + ((L & 127) >> 1);
    }

    bf16x8 qf[2];
    {
        size_t base = ((size_t)(b * 1024) + q0 + w * 16 + fr) * 3072 + hh * 64;
        qf[0] = *(const bf16x8*)(qkv + base + fq * 8);
        qf[1] = *(const bf16x8*)(qkv + base + 32 + fq * 8);
    }

    float m_run[4], l_run[4];
    f32x4 acc_o[4] = {};
    #pragma unroll
    for (int r = 0; r < 4; ++r) { m_run[r] = -__builtin_inff(); l_run[r] = 0.0f; }

    for (int kv0 = 0; kv0 <= q0; kv0 += 64) {
        #pragma unroll
        for (int i = 0; i < 2; ++i)
            gload16(srcK[i] + (size_t)kv0 * 3072, (char*)lK + w * 1024 + i * 4096);
        #pragma unroll
        for (int i = 0; i < 2; ++i) {
            int g = t + i * 256;
            int kv = g >> 3, d0 = (g & 7) * 8;
            const u32* gv = (const u32*)(qkv + ((size_t)(b * 1024) + kv0 + kv) * 3072 + 2048 + hh * 64 + d0);
            u32 v0 = gv[0], v1 = gv[1], v2 = gv[2], v3 = gv[3];
            u16 e[8] = { (u16)v0, (u16)(v0 >> 16), (u16)v1, (u16)(v1 >> 16),
                         (u16)v2, (u16)(v2 >> 16), (u16)v3, (u16)(v3 >> 16) };
            #pragma unroll
            for (int j = 0; j < 8; ++j) {
                int pv = ((d0 + j) * 64 + kv) * 2;
                *(u16*)((char*)lV + swz(pv)) = e[j];
            }
        }
        __syncthreads();

        f32x4 accs[4] = {};
        #pragma unroll
        for (int nt = 0; nt < 4; ++nt) {
            #pragma unroll
            for (int ks = 0; ks < 2; ++ks) {
                int pk = ((nt * 16 + fr) * 64 + ks * 32 + fq * 8) * 2;
                bf16x8 kf = *(const bf16x8*)((const char*)lK + swz(pk));
                accs[nt] = __builtin_amdgcn_mfma_f32_16x16x32_bf16(qf[ks], kf, accs[nt], 0, 0, 0);
            }
        }

        float p[4][4], mx[4], rs[4];
        #pragma unroll
        for (int r = 0; r < 4; ++r) {
            int qg = q0 + w * 16 + fq * 4 + r;
            float m = -__builtin_inff();
            #pragma unroll
            for (int nt = 0; nt < 4; ++nt) {
                int kvg = kv0 + nt * 16 + fr;
                float s = (kvg <= qg) ? accs[nt][r] * 0.125f : -__builtin_inff();
                p[nt][r] = s;
                m = fmaxf(m, s);
            }
            mx[r] = m;
        }
        #pragma unroll
        for (int msk = 1; msk < 16; msk <<= 1) {
            #pragma unroll
            for (int r = 0; r < 4; ++r) mx[r] = fmaxf(mx[r], __shfl_xor(mx[r], msk));
        }
        float mnew[4], alpha[4];
        #pragma unroll
        for (int r = 0; r < 4; ++r) {
            mnew[r] = fmaxf(m_run[r], mx[r]);
            alpha[r] = __expf(m_run[r] - mnew[r]);
            float s = 0.0f;
            #pragma unroll
            for (int nt = 0; nt < 4; ++nt) {
                float pv = __expf(p[nt][r] - mnew[r]);
                p[nt][r] = pv;
                s += pv;
            }
            rs[r] = s;
        }
        #pragma unroll
        for (int msk = 1; msk < 16; msk <<= 1) {
            #pragma unroll
            for (int r = 0; r < 4; ++r) rs[r] += __shfl_xor(rs[r], msk);
        }
        #pragma unroll
        for (int r = 0; r < 4; ++r) {
            l_run[r] = l_run[r] * alpha[r] + rs[r];
            m_run[r] = mnew[r];
        }
        #pragma unroll
        for (int nt = 0; nt < 4; ++nt)
            #pragma unroll
            for (int r = 0; r < 4; ++r) acc_o[nt][r] *= alpha[r];

        #pragma unroll
        for (int nt = 0; nt < 4; ++nt)
            #pragma unroll
            for (int r = 0; r < 4; ++r) {
                int pp = (w * 1024 + (fq * 4 + r) * 64 + nt * 16 + fr) * 2;
                *(u16*)((char*)lP + swz(pp)) = f2bf(p[nt][r]);
            }
        __syncthreads();

        bf16x8 pa[2];
        #pragma unroll
        for (int ks = 0; ks < 2; ++ks) {
            int ppr = (w * 1024 + fr * 64 + ks * 32 + fq * 8) * 2;
            pa[ks] = *(const bf16x8*)((const char*)lP + swz(ppr));
        }
        #pragma unroll
        for (int nt = 0; nt < 4; ++nt) {
            #pragma unroll
            for (int ks = 0; ks < 2; ++ks) {
                int pvr = ((nt * 16 + fr) * 64 + ks * 32 + fq * 8) * 2;
                bf16x8 vf = *(const bf16x8*)((const char*)lV + swz(pvr));
                acc_o[nt] = __builtin_amdgcn_mfma_f32_16x16x32_bf16(pa[ks], vf, acc_o[nt], 0, 0, 0);
            }
        }
        __syncthreads();
    }

    #pragma unroll
    for (int nt = 0; nt < 4; ++nt) {
        #pragma unroll
        for (int r = 0; r < 4; ++r) {
            int qg = q0 + w * 16 + fq * 4 + r;
            int d = nt * 16 + fr;
            float ov = acc_o[nt][r] / l_run[r];
            o[((size_t)(b * 1024) + qg) * 1024 + hh * 64 + d] = f2bf(ov);
        }
    }
}

// ---------------- launch ----------------
extern "C" void kernel_launch(void* const* d_in, const int* in_sizes, int n_in,
                              void* d_out, int out_size, void* d_ws, size_t ws_size,
                              hipStream_t stream) {
    const int*   x       = (const int*)  d_in[0];
    const float* tok_emb = (const float*)d_in[1];
    const float* pos_emb = (const float*)d_in[2];
    const float* ln1_g   = (const float*)d_in[3];
    const float* ln1_b   = (const float*)d_in[4];
    const float* qkv_w   = (const float*)d_in[5];
    const float* qkv_b   = (const float*)d_in[6];
    const float* proj_w  = (const float*)d_in[7];
    const float* proj_b  = (const float*)d_in[8];
    const float* ln2_g   = (const float*)d_in[9];
    const float* ln2_b   = (const float*)d_in[10];
    const float* fc1_w   = (const float*)d_in[11];
    const float* fc1_b   = (const float*)d_in[12];
    const float* fc2_w   = (const float*)d_in[13];
    const float* fc2_b   = (const float*)d_in[14];
    const float* lnf_g   = (const float*)d_in[15];
    const float* lnf_b   = (const float*)d_in[16];
    const float* head_w  = (const float*)d_in[17];
    float* out = (float*)d_out;

    char* ws = (char*)d_ws;
    float* h   = (float*)(ws + 0);            //  8 MB f32 (2048x1024)
    u16*   xn  = (u16*)(ws + 8388608);        //  4 MB bf16
    u16*   qkv = (u16*)(ws + 12582912);       // 12.6 MB bf16 (2048x3072)
    u16*   ob  = (u16*)(ws + 25165824);       //  4 MB bf16
    u16*   ff  = (u16*)(ws + 29360128);       // 16.8 MB bf16 (2048x4096)
    u16*   wq  = (u16*)(ws + 46137344);       // 65.5 MB bf16 weight slab

    // per-layer weight slab layout (u16 elements)
    u16* wqkv = wq;
    u16* wproj = wqkv + 3072 * 1024;
    u16* wfc1  = wproj + 1024 * 1024;
    u16* wfc2  = wfc1 + 4096 * 1024;

    const int M = 2048;

    embed_k<<<dim3(2048), 256, 0, stream>>>(x, tok_emb, pos_emb, h);

    for (int lyr = 0; lyr < 6; ++lyr) {
        cvt4_k<<<dim3(2048), 256, 0, stream>>>(
            qkv_w + (size_t)lyr * 3072 * 1024, proj_w + (size_t)lyr * 1024 * 1024,
            fc1_w + (size_t)lyr * 4096 * 1024, fc2_w + (size_t)lyr * 1024 * 4096,
            wq, 3072 * 256, 1024 * 256, 4096 * 256, 4096 * 256);
        ln_k<<<dim3(2048), 256, 0, stream>>>(h, ln1_g + lyr * 1024, ln1_b + lyr * 1024, xn);
        gemm_bt<128, 128, 1, 0, 0, 1><<<dim3(16, 24), 256, 0, stream>>>(
            xn, wqkv, qkv_b + lyr * 3072, nullptr, nullptr, qkv, M, 3072, 1024);
        attn_k<<<dim3(512), 256, 0, stream>>>(qkv, ob);
        gemm_bt<128, 64, 1, 0, 1, 0><<<dim3(16, 16), 256, 0, stream>>>(
            ob, wproj, proj_b + lyr * 1024, h, h, nullptr, M, 1024, 1024);
        ln_k<<<dim3(2048), 256, 0, stream>>>(h, ln2_g + lyr * 1024, ln2_b + lyr * 1024, xn);
        gemm_bt<128, 128, 1, 1, 0, 1><<<dim3(16, 32), 256, 0, stream>>>(
            xn, wfc1, fc1_b + lyr * 4096, nullptr, nullptr, ff, M, 4096, 1024);
        gemm_bt<128, 64, 1, 0, 1, 0><<<dim3(16, 16), 256, 0, stream>>>(
            ff, wfc2, fc2_b + lyr * 1024, h, h, nullptr, M, 1024, 4096);
    }

    ln_k<<<dim3(2048), 256, 0, stream>>>(h, lnf_g, lnf_b, xn);
    cvt_k<<<dim3(2048), 256, 0, stream>>>(head_w, wq, 32000 * 1024 / 4);
    gemm8p<0, 0><<<dim3(8, 125), 512, 0, stream>>>(
        xn, wq, nullptr, out, nullptr, M, 32000, 1024);
}

// Round 6
// 1350.434 us; speedup vs baseline: 1.3180x; 1.1129x over previous
//
#include <hip/hip_runtime.h>

typedef unsigned short u16;
typedef unsigned int   u32;
typedef __bf16 bf16x8 __attribute__((ext_vector_type(8)));
typedef float  f32x4  __attribute__((ext_vector_type(4)));

#define DEV __device__ __forceinline__

DEV u16 f2bf(float f) {
    u32 u = __builtin_bit_cast(u32, f);
    u32 r = u + 0x7FFFu + ((u >> 16) & 1u);
    return (u16)(r >> 16);
}

DEV void gload16(const void* g, void* l) {
    __builtin_amdgcn_global_load_lds((const __attribute__((address_space(1))) void*)g,
                                     (__attribute__((address_space(3))) void*)l, 16, 0, 0);
}

// bijective XCD-aware swizzle (m204)
DEV int xcd_swz(int bid, int nwg) {
    int q = nwg >> 3, r = nwg & 7;
    int xcd = bid & 7, idx = bid >> 3;
    return (xcd < r ? xcd * (q + 1) : r * (q + 1) + (xcd - r) * q) + idx;
}

// involutive LDS byte swizzle for 128B rows: XOR byte bits[6:4] with row bits [0,2,1]
DEV int swz(int p) {
    int m = (((p >> 7) & 1) << 6) | (((p >> 9) & 1) << 5) | (((p >> 8) & 1) << 4);
    return p ^ m;
}

// ---------------- convert f32 -> bf16 (single tensor) ----------------
__global__ void cvt_k(const float* __restrict__ src, u16* __restrict__ dst, int n4) {
    int i = blockIdx.x * blockDim.x + threadIdx.x;
    int stride = gridDim.x * blockDim.x;
    for (; i < n4; i += stride) {
        float4 v = ((const float4*)src)[i];
        ushort4 u;
        u.x = f2bf(v.x); u.y = f2bf(v.y); u.z = f2bf(v.z); u.w = f2bf(v.w);
        ((ushort4*)dst)[i] = u;
    }
}

// ---------------- convert 4 tensors in one launch (per-layer weights) ----------------
__global__ void cvt4_k(const float* __restrict__ s0, const float* __restrict__ s1,
                       const float* __restrict__ s2, const float* __restrict__ s3,
                       u16* __restrict__ dst, int n0, int n1, int n2, int n3) {
    int i = blockIdx.x * blockDim.x + threadIdx.x;
    int stride = gridDim.x * blockDim.x;
    int t0 = n0, t1 = t0 + n1, t2 = t1 + n2, t3 = t2 + n3;
    for (; i < t3; i += stride) {
        const float* s; int j;
        if (i < t0)      { s = s0; j = i; }
        else if (i < t1) { s = s1; j = i - t0; }
        else if (i < t2) { s = s2; j = i - t1; }
        else             { s = s3; j = i - t2; }
        float4 v = ((const float4*)s)[j];
        ushort4 u;
        u.x = f2bf(v.x); u.y = f2bf(v.y); u.z = f2bf(v.z); u.w = f2bf(v.w);
        ((ushort4*)dst)[i] = u;
    }
}

// ---------------- embedding ----------------
__global__ void embed_k(const int* __restrict__ x, const float* __restrict__ te,
                        const float* __restrict__ pe, float* __restrict__ h) {
    int row = blockIdx.x;
    int t = threadIdx.x;
    int tok = x[row];
    int s = row & 1023;
    float4 a = ((const float4*)(te + (size_t)tok * 1024))[t];
    float4 p = ((const float4*)(pe + (size_t)s * 1024))[t];
    a.x += p.x; a.y += p.y; a.z += p.z; a.w += p.w;
    ((float4*)(h + (size_t)row * 1024))[t] = a;
}

// ---------------- LayerNorm: f32 in -> bf16 out ----------------
__global__ void ln_k(const float* __restrict__ in, const float* __restrict__ g,
                     const float* __restrict__ b, u16* __restrict__ out) {
    int row = blockIdx.x;
    int t = threadIdx.x;
    float4 v = ((const float4*)(in + (size_t)row * 1024))[t];
    float s = v.x + v.y + v.z + v.w;
    float s2 = v.x * v.x + v.y * v.y + v.z * v.z + v.w * v.w;
    #pragma unroll
    for (int msk = 1; msk < 64; msk <<= 1) {
        s  += __shfl_xor(s, msk);
        s2 += __shfl_xor(s2, msk);
    }
    __shared__ float ps[4], ps2[4];
    if ((t & 63) == 0) { ps[t >> 6] = s; ps2[t >> 6] = s2; }
    __syncthreads();
    s = ps[0] + ps[1] + ps[2] + ps[3];
    s2 = ps2[0] + ps2[1] + ps2[2] + ps2[3];
    float mu = s * (1.0f / 1024.0f);
    float var = s2 * (1.0f / 1024.0f) - mu * mu;
    float rstd = rsqrtf(var + 1e-5f);
    float4 gg = ((const float4*)g)[t];
    float4 bb = ((const float4*)b)[t];
    ushort4 o;
    o.x = f2bf((v.x - mu) * rstd * gg.x + bb.x);
    o.y = f2bf((v.y - mu) * rstd * gg.y + bb.y);
    o.z = f2bf((v.z - mu) * rstd * gg.z + bb.z);
    o.w = f2bf((v.w - mu) * rstd * gg.w + bb.w);
    ((ushort4*)out)[(size_t)row * 256 + t] = o;
}

// ---------------- fc2 fuse: h += p0 + p1 + bias ----------------
__global__ void fuse2_k(const float* __restrict__ p0, const float* __restrict__ p1,
                        const float* __restrict__ bias, float* __restrict__ h) {
    int row = blockIdx.x;
    int t = threadIdx.x;
    size_t idx = (size_t)row * 256 + t;
    float4 a = ((const float4*)p0)[idx];
    float4 b = ((const float4*)p1)[idx];
    float4 c = ((const float4*)bias)[t];
    float4 v = ((const float4*)h)[idx];
    v.x += a.x + b.x + c.x;
    v.y += a.y + b.y + c.y;
    v.z += a.z + b.z + c.z;
    v.w += a.w + b.w + c.w;
    ((float4*)h)[idx] = v;
}

// ============ 256x256 8-wave 4-phase-per-K-tile GEMM (BK=64, counted vmcnt) ============
template<int PH>
DEV void phase_mma(const bf16x8 (&af)[2][2], const bf16x8 (&bfr)[4][2], f32x4 (&acc)[8][4]) {
    __builtin_amdgcn_s_barrier();
    asm volatile("s_waitcnt lgkmcnt(0)" ::: "memory");
    __builtin_amdgcn_sched_barrier(0);
    __builtin_amdgcn_s_setprio(1);
    #pragma unroll
    for (int ms = 0; ms < 2; ++ms)
        #pragma unroll
        for (int nj = 0; nj < 4; ++nj)
            #pragma unroll
            for (int kk = 0; kk < 2; ++kk)
                acc[PH * 2 + ms][nj] = __builtin_amdgcn_mfma_f32_16x16x32_bf16(
                    af[ms][kk], bfr[nj][kk], acc[PH * 2 + ms][nj], 0, 0, 0);
    __builtin_amdgcn_s_setprio(0);
}

template<int PH>
DEV void read_afrags(const char* Ab, int arow, int fr, int fq, bf16x8 (&af)[2][2]) {
    #pragma unroll
    for (int ms = 0; ms < 2; ++ms)
        #pragma unroll
        for (int kk = 0; kk < 2; ++kk) {
            int lin = (arow + (PH * 2 + ms) * 16 + fr) * 128 + kk * 64 + fq * 16;
            af[ms][kk] = *(const bf16x8*)(Ab + swz(lin));
        }
}

template<int BIAS, int OUTBF>
__global__ __launch_bounds__(512, 2)
void gemm8p(const u16* __restrict__ A, const u16* __restrict__ Bw,
            const float* __restrict__ bias,
            float* __restrict__ outf, u16* __restrict__ outb,
            int M, int N, int K) {
    __shared__ char lds[131072];
    char* ldsA = lds;
    char* ldsB = lds + 65536;
    const int t = threadIdx.x;
    const int w = t >> 6, l = t & 63;
    const int fr = l & 15, fq = l >> 4;
    const int wm = w >> 2, wn = w & 3;

    int bid = blockIdx.y * gridDim.x + blockIdx.x;
    int swzb = xcd_swz(bid, gridDim.x * gridDim.y);
    const int m0 = (swzb % gridDim.x) * 256;
    const int n0 = (swzb / gridDim.x) * 256;
    const int nt = K >> 6;
    const int arow = wm * 128;

    const u16* Asrc = A + (size_t)m0 * K;
    const u16* Bsrc = Bw + (size_t)n0 * K;

    size_t o00, o01, o10, o11;
    {
        int p;
        p = 0 * 16384 + 0 * 8192 + t * 16; o00 = (size_t)(p >> 7) * K + ((swz(p) & 127) >> 1);
        p = 0 * 16384 + 1 * 8192 + t * 16; o01 = (size_t)(p >> 7) * K + ((swz(p) & 127) >> 1);
        p = 1 * 16384 + 0 * 8192 + t * 16; o10 = (size_t)(p >> 7) * K + ((swz(p) & 127) >> 1);
        p = 1 * 16384 + 1 * 8192 + t * 16; o11 = (size_t)(p >> 7) * K + ((swz(p) & 127) >> 1);
    }
    const int wb = w * 1024;

    gload16(Asrc + o00, ldsA + wb);
    gload16(Asrc + o01, ldsA + 8192 + wb);
    gload16(Asrc + o10, ldsA + 16384 + wb);
    gload16(Asrc + o11, ldsA + 16384 + 8192 + wb);
    gload16(Bsrc + o00, ldsB + wb);
    gload16(Bsrc + o01, ldsB + 8192 + wb);
    gload16(Bsrc + o10, ldsB + 16384 + wb);
    gload16(Bsrc + o11, ldsB + 16384 + 8192 + wb);
    gload16(Bsrc + o00 + 64, ldsB + 32768 + wb);
    gload16(Bsrc + o01 + 64, ldsB + 32768 + 8192 + wb);
    gload16(Bsrc + o10 + 64, ldsB + 32768 + 16384 + wb);
    gload16(Bsrc + o11 + 64, ldsB + 32768 + 16384 + 8192 + wb);
    asm volatile("s_waitcnt vmcnt(4)" ::: "memory");
    __builtin_amdgcn_s_barrier();
    __builtin_amdgcn_sched_barrier(0);

    f32x4 acc[8][4] = {};

    for (int T = 0; T < nt; ++T) {
        const char* Ab = ldsA + (T & 1) * 32768;
        const char* Bb = ldsB + (T & 1) * 32768;
        char* Anx = ldsA + ((T + 1) & 1) * 32768;
        char* Bnx = ldsB + (T & 1) * 32768;
        const bool stA = (T + 1 < nt), stB = (T + 2 < nt);
        const size_t kA = (size_t)(T + 1) * 64, kB = (size_t)(T + 2) * 64;

        bf16x8 bfr[4][2], af[2][2];

        #pragma unroll
        for (int nj = 0; nj < 4; ++nj)
            #pragma unroll
            for (int kk = 0; kk < 2; ++kk) {
                int lin = (wn * 64 + nj * 16 + fr) * 128 + kk * 64 + fq * 16;
                bfr[nj][kk] = *(const bf16x8*)(Bb + swz(lin));
            }
        read_afrags<0>(Ab, arow, fr, fq, af);
        if (stA) {
            gload16(Asrc + o00 + kA, Anx + wb);
            gload16(Asrc + o01 + kA, Anx + 8192 + wb);
        }
        phase_mma<0>(af, bfr, acc);
        __builtin_amdgcn_s_barrier();

        read_afrags<1>(Ab, arow, fr, fq, af);
        if (stA) {
            gload16(Asrc + o10 + kA, Anx + 16384 + wb);
            gload16(Asrc + o11 + kA, Anx + 16384 + 8192 + wb);
        }
        phase_mma<1>(af, bfr, acc);
        __builtin_amdgcn_s_barrier();

        read_afrags<2>(Ab, arow, fr, fq, af);
        if (stB) {
            gload16(Bsrc + o00 + kB, Bnx + wb);
            gload16(Bsrc + o01 + kB, Bnx + 8192 + wb);
        }
        phase_mma<2>(af, bfr, acc);
        __builtin_amdgcn_s_barrier();

        read_afrags<3>(Ab, arow, fr, fq, af);
        if (stB) {
            gload16(Bsrc + o10 + kB, Bnx + 16384 + wb);
            gload16(Bsrc + o11 + kB, Bnx + 16384 + 8192 + wb);
        }
        phase_mma<3>(af, bfr, acc);
        if (stB)      asm volatile("s_waitcnt vmcnt(4)" ::: "memory");
        else if (stA) asm volatile("s_waitcnt vmcnt(0)" ::: "memory");
        __builtin_amdgcn_s_barrier();
        __builtin_amdgcn_sched_barrier(0);
    }

    #pragma unroll
    for (int mi = 0; mi < 8; ++mi) {
        #pragma unroll
        for (int nj = 0; nj < 4; ++nj) {
            #pragma unroll
            for (int r = 0; r < 4; ++r) {
                int row = m0 + wm * 128 + mi * 16 + fq * 4 + r;
                int col = n0 + wn * 64 + nj * 16 + fr;
                float v = acc[mi][nj][r];
                if (BIAS) v += bias[col];
                if (OUTBF) outb[(size_t)row * N + col] = f2bf(v);
                else       outf[(size_t)row * N + col] = v;
            }
        }
    }
}

// ---------------- tiled GEMM (2-barrier), occupancy via small tiles ----------------
template<int BM, int BN, int BIAS, int GELU_, int RES, int OUTBF>
__global__ void gemm_bt(const u16* __restrict__ A, const u16* __restrict__ Bw,
                        const float* __restrict__ bias, const float* __restrict__ res,
                        float* __restrict__ outf, u16* __restrict__ outb,
                        int M, int N, int K) {
    constexpr int MR = BM / 32;
    constexpr int NR = BN / 32;
    constexpr int AL = BM / 64;
    constexpr int BL = BN / 64;
    __shared__ u16 lA[BM * 32];
    __shared__ u16 lB[BN * 32];
    const int t = threadIdx.x;
    const int w = t >> 6, l = t & 63;

    int bid = blockIdx.y * gridDim.x + blockIdx.x;
    int swzb = xcd_swz(bid, gridDim.x * gridDim.y);
    const int m0 = (swzb % gridDim.x) * BM;
    const int n0 = (swzb / gridDim.x) * BN;

    const int wr = (w >> 1) * (BM / 2), wc = (w & 1) * (BN / 2);
    const int fr = l & 15, fq = l >> 4;

    f32x4 acc[MR][NR] = {};
    const int g0 = w * 64 + l;

    for (int k0 = 0; k0 < K; k0 += 32) {
        #pragma unroll
        for (int i = 0; i < AL; ++i) {
            int g = g0 + i * 256;
            int row = g >> 2, c = (g & 3) * 8;
            gload16(A + (size_t)(m0 + row) * K + k0 + c, lA + w * 512 + i * 2048);
        }
        #pragma unroll
        for (int i = 0; i < BL; ++i) {
            int g = g0 + i * 256;
            int row = g >> 2, c = (g & 3) * 8;
            gload16(Bw + (size_t)(n0 + row) * K + k0 + c, lB + w * 512 + i * 2048);
        }
        __syncthreads();
        bf16x8 af[MR], bfv[NR];
        #pragma unroll
        for (int mi = 0; mi < MR; ++mi)
            af[mi] = *(const bf16x8*)(lA + (wr + mi * 16 + fr) * 32 + fq * 8);
        #pragma unroll
        for (int ni = 0; ni < NR; ++ni)
            bfv[ni] = *(const bf16x8*)(lB + (wc + ni * 16 + fr) * 32 + fq * 8);
        #pragma unroll
        for (int mi = 0; mi < MR; ++mi)
            #pragma unroll
            for (int ni = 0; ni < NR; ++ni)
                acc[mi][ni] = __builtin_amdgcn_mfma_f32_16x16x32_bf16(af[mi], bfv[ni], acc[mi][ni], 0, 0, 0);
        __syncthreads();
    }

    #pragma unroll
    for (int mi = 0; mi < MR; ++mi) {
        #pragma unroll
        for (int ni = 0; ni < NR; ++ni) {
            #pragma unroll
            for (int r = 0; r < 4; ++r) {
                int row = m0 + wr + mi * 16 + fq * 4 + r;
                int col = n0 + wc + ni * 16 + fr;
                float v = acc[mi][ni][r];
                if (BIAS) v += bias[col];
                if (GELU_) v = 0.5f * v * (1.0f + erff(v * 0.70710678118f));
                if (RES) v += res[(size_t)row * N + col];
                if (OUTBF) outb[(size_t)row * N + col] = f2bf(v);
                else       outf[(size_t)row * N + col] = v;
            }
        }
    }
}

// ---------------- split-K GEMM (fc2): z = k-half, writes f32 partials ----------------
template<int BM, int BN>
__global__ void gemm_sk(const u16* __restrict__ A, const u16* __restrict__ Bw,
                        float* __restrict__ pbuf, int M, int N, int Kfull) {
    constexpr int MR = BM / 32;
    constexpr int NR = BN / 32;
    constexpr int AL = BM / 64;
    constexpr int BL = BN / 64;
    __shared__ u16 lA[BM * 32];
    __shared__ u16 lB[BN * 32];
    const int t = threadIdx.x;
    const int w = t >> 6, l = t & 63;
    const int z = blockIdx.z;
    const int Kh = Kfull >> 1;
    const int kbase = z * Kh;

    int bid = blockIdx.y * gridDim.x + blockIdx.x;
    int swzb = xcd_swz(bid, gridDim.x * gridDim.y);
    const int m0 = (swzb % gridDim.x) * BM;
    const int n0 = (swzb / gridDim.x) * BN;

    const int wr = (w >> 1) * (BM / 2), wc = (w & 1) * (BN / 2);
    const int fr = l & 15, fq = l >> 4;

    f32x4 acc[MR][NR] = {};
    const int g0 = w * 64 + l;

    for (int k0 = 0; k0 < Kh; k0 += 32) {
        #pragma unroll
        for (int i = 0; i < AL; ++i) {
            int g = g0 + i * 256;
            int row = g >> 2, c = (g & 3) * 8;
            gload16(A + (size_t)(m0 + row) * Kfull + kbase + k0 + c, lA + w * 512 + i * 2048);
        }
        #pragma unroll
        for (int i = 0; i < BL; ++i) {
            int g = g0 + i * 256;
            int row = g >> 2, c = (g & 3) * 8;
            gload16(Bw + (size_t)(n0 + row) * Kfull + kbase + k0 + c, lB + w * 512 + i * 2048);
        }
        __syncthreads();
        bf16x8 af[MR], bfv[NR];
        #pragma unroll
        for (int mi = 0; mi < MR; ++mi)
            af[mi] = *(const bf16x8*)(lA + (wr + mi * 16 + fr) * 32 + fq * 8);
        #pragma unroll
        for (int ni = 0; ni < NR; ++ni)
            bfv[ni] = *(const bf16x8*)(lB + (wc + ni * 16 + fr) * 32 + fq * 8);
        #pragma unroll
        for (int mi = 0; mi < MR; ++mi)
            #pragma unroll
            for (int ni = 0; ni < NR; ++ni)
                acc[mi][ni] = __builtin_amdgcn_mfma_f32_16x16x32_bf16(af[mi], bfv[ni], acc[mi][ni], 0, 0, 0);
        __syncthreads();
    }

    float* outp = pbuf + (size_t)z * M * N;
    #pragma unroll
    for (int mi = 0; mi < MR; ++mi) {
        #pragma unroll
        for (int ni = 0; ni < NR; ++ni) {
            #pragma unroll
            for (int r = 0; r < 4; ++r) {
                int row = m0 + wr + mi * 16 + fq * 4 + r;
                int col = n0 + wc + ni * 16 + fr;
                outp[(size_t)row * N + col] = acc[mi][ni][r];
            }
        }
    }
}

// ---------------- Flash attention (swizzled LDS, XCD-chunked grid) ----------------
__global__ void attn_k(const u16* __restrict__ qkv, u16* __restrict__ o) {
    __shared__ u16 lK[64 * 64];
    __shared__ u16 lV[64 * 64];
    __shared__ u16 lP[4 * 16 * 64];
    const int t = threadIdx.x;
    const int w = t >> 6, l = t & 63;
    const int fr = l & 15, fq = l >> 4;

    int swzb = xcd_swz(blockIdx.x, gridDim.x);
    const int qb = 15 - (swzb & 15);
    const int hh = (swzb >> 4) & 15;
    const int b  = swzb >> 8;
    const int q0 = qb * 64;

    const u16* srcK[2];
    #pragma unroll
    for (int i = 0; i < 2; ++i) {
        int p = (t + i * 256) * 16;
        int L = swz(p);
        srcK[i] = qkv + ((size_t)(b * 1024) + (L >> 7)) * 3072 + 1024 + hh * 64 + ((L & 127) >> 1);
    }

    bf16x8 qf[2];
    {
        size_t base = ((size_t)(b * 1024) + q0 + w * 16 + fr) * 3072 + hh * 64;
        qf[0] = *(const bf16x8*)(qkv + base + fq * 8);
        qf[1] = *(const bf16x8*)(qkv + base + 32 + fq * 8);
    }

    float m_run[4], l_run[4];
    f32x4 acc_o[4] = {};
    #pragma unroll
    for (int r = 0; r < 4; ++r) { m_run[r] = -__builtin_inff(); l_run[r] = 0.0f; }

    for (int kv0 = 0; kv0 <= q0; kv0 += 64) {
        #pragma unroll
        for (int i = 0; i < 2; ++i)
            gload16(srcK[i] + (size_t)kv0 * 3072, (char*)lK + w * 1024 + i * 4096);
        #pragma unroll
        for (int i = 0; i < 2; ++i) {
            int g = t + i * 256;
            int kv = g >> 3, d0 = (g & 7) * 8;
            const u32* gv = (const u32*)(qkv + ((size_t)(b * 1024) + kv0 + kv) * 3072 + 2048 + hh * 64 + d0);
            u32 v0 = gv[0], v1 = gv[1], v2 = gv[2], v3 = gv[3];
            u16 e[8] = { (u16)v0, (u16)(v0 >> 16), (u16)v1, (u16)(v1 >> 16),
                         (u16)v2, (u16)(v2 >> 16), (u16)v3, (u16)(v3 >> 16) };
            #pragma unroll
            for (int j = 0; j < 8; ++j) {
                int pv = ((d0 + j) * 64 + kv) * 2;
                *(u16*)((char*)lV + swz(pv)) = e[j];
            }
        }
        __syncthreads();

        f32x4 accs[4] = {};
        #pragma unroll
        for (int nt = 0; nt < 4; ++nt) {
            #pragma unroll
            for (int ks = 0; ks < 2; ++ks) {
                int pk = ((nt * 16 + fr) * 64 + ks * 32 + fq * 8) * 2;
                bf16x8 kf = *(const bf16x8*)((const char*)lK + swz(pk));
                accs[nt] = __builtin_amdgcn_mfma_f32_16x16x32_bf16(qf[ks], kf, accs[nt], 0, 0, 0);
            }
        }

        float p[4][4], mx[4], rs[4];
        #pragma unroll
        for (int r = 0; r < 4; ++r) {
            int qg = q0 + w * 16 + fq * 4 + r;
            float m = -__builtin_inff();
            #pragma unroll
            for (int nt = 0; nt < 4; ++nt) {
                int kvg = kv0 + nt * 16 + fr;
                float s = (kvg <= qg) ? accs[nt][r] * 0.125f : -__builtin_inff();
                p[nt][r] = s;
                m = fmaxf(m, s);
            }
            mx[r] = m;
        }
        #pragma unroll
        for (int msk = 1; msk < 16; msk <<= 1) {
            #pragma unroll
            for (int r = 0; r < 4; ++r) mx[r] = fmaxf(mx[r], __shfl_xor(mx[r], msk));
        }
        float mnew[4], alpha[4];
        #pragma unroll
        for (int r = 0; r < 4; ++r) {
            mnew[r] = fmaxf(m_run[r], mx[r]);
            alpha[r] = __expf(m_run[r] - mnew[r]);
            float s = 0.0f;
            #pragma unroll
            for (int nt = 0; nt < 4; ++nt) {
                float pv = __expf(p[nt][r] - mnew[r]);
                p[nt][r] = pv;
                s += pv;
            }
            rs[r] = s;
        }
        #pragma unroll
        for (int msk = 1; msk < 16; msk <<= 1) {
            #pragma unroll
            for (int r = 0; r < 4; ++r) rs[r] += __shfl_xor(rs[r], msk);
        }
        #pragma unroll
        for (int r = 0; r < 4; ++r) {
            l_run[r] = l_run[r] * alpha[r] + rs[r];
            m_run[r] = mnew[r];
        }
        #pragma unroll
        for (int nt = 0; nt < 4; ++nt)
            #pragma unroll
            for (int r = 0; r < 4; ++r) acc_o[nt][r] *= alpha[r];

        #pragma unroll
        for (int nt = 0; nt < 4; ++nt)
            #pragma unroll
            for (int r = 0; r < 4; ++r) {
                int pp = (w * 1024 + (fq * 4 + r) * 64 + nt * 16 + fr) * 2;
                *(u16*)((char*)lP + swz(pp)) = f2bf(p[nt][r]);
            }
        __syncthreads();

        bf16x8 pa[2];
        #pragma unroll
        for (int ks = 0; ks < 2; ++ks) {
            int ppr = (w * 1024 + fr * 64 + ks * 32 + fq * 8) * 2;
            pa[ks] = *(const bf16x8*)((const char*)lP + swz(ppr));
        }
        #pragma unroll
        for (int nt = 0; nt < 4; ++nt) {
            #pragma unroll
            for (int ks = 0; ks < 2; ++ks) {
                int pvr = ((nt * 16 + fr) * 64 + ks * 32 + fq * 8) * 2;
                bf16x8 vf = *(const bf16x8*)((const char*)lV + swz(pvr));
                acc_o[nt] = __builtin_amdgcn_mfma_f32_16x16x32_bf16(pa[ks], vf, acc_o[nt], 0, 0, 0);
            }
        }
        __syncthreads();
    }

    #pragma unroll
    for (int nt = 0; nt < 4; ++nt) {
        #pragma unroll
        for (int r = 0; r < 4; ++r) {
            int qg = q0 + w * 16 + fq * 4 + r;
            int d = nt * 16 + fr;
            float ov = acc_o[nt][r] / l_run[r];
            o[((size_t)(b * 1024) + qg) * 1024 + hh * 64 + d] = f2bf(ov);
        }
    }
}

// ---------------- launch ----------------
extern "C" void kernel_launch(void* const* d_in, const int* in_sizes, int n_in,
                              void* d_out, int out_size, void* d_ws, size_t ws_size,
                              hipStream_t stream) {
    const int*   x       = (const int*)  d_in[0];
    const float* tok_emb = (const float*)d_in[1];
    const float* pos_emb = (const float*)d_in[2];
    const float* ln1_g   = (const float*)d_in[3];
    const float* ln1_b   = (const float*)d_in[4];
    const float* qkv_w   = (const float*)d_in[5];
    const float* qkv_b   = (const float*)d_in[6];
    const float* proj_w  = (const float*)d_in[7];
    const float* proj_b  = (const float*)d_in[8];
    const float* ln2_g   = (const float*)d_in[9];
    const float* ln2_b   = (const float*)d_in[10];
    const float* fc1_w   = (const float*)d_in[11];
    const float* fc1_b   = (const float*)d_in[12];
    const float* fc2_w   = (const float*)d_in[13];
    const float* fc2_b   = (const float*)d_in[14];
    const float* lnf_g   = (const float*)d_in[15];
    const float* lnf_b   = (const float*)d_in[16];
    const float* head_w  = (const float*)d_in[17];
    float* out = (float*)d_out;

    char* ws = (char*)d_ws;
    float* h   = (float*)(ws + 0);            //  8 MB f32 (2048x1024)
    u16*   xn  = (u16*)(ws + 8388608);        //  4 MB bf16
    u16*   qkv = (u16*)(ws + 12582912);       // 12.6 MB bf16 (2048x3072)
    u16*   ob  = (u16*)(ws + 25165824);       //  4 MB bf16
    u16*   ff  = (u16*)(ws + 29360128);       // 16.8 MB bf16 (2048x4096)
    u16*   wq  = (u16*)(ws + 46137344);       // 65.5 MB bf16 weight slab
    // fc2 split-K partials (16 MB f32) overlap the qkv+ob region (dead at fc2 time)
    float* pbuf = (float*)(ws + 12582912);

    u16* wqkv = wq;
    u16* wproj = wqkv + 3072 * 1024;
    u16* wfc1  = wproj + 1024 * 1024;
    u16* wfc2  = wfc1 + 4096 * 1024;

    const int M = 2048;

    embed_k<<<dim3(2048), 256, 0, stream>>>(x, tok_emb, pos_emb, h);

    for (int lyr = 0; lyr < 6; ++lyr) {
        cvt4_k<<<dim3(2048), 256, 0, stream>>>(
            qkv_w + (size_t)lyr * 3072 * 1024, proj_w + (size_t)lyr * 1024 * 1024,
            fc1_w + (size_t)lyr * 4096 * 1024, fc2_w + (size_t)lyr * 1024 * 4096,
            wq, 3072 * 256, 1024 * 256, 4096 * 256, 4096 * 256);
        ln_k<<<dim3(2048), 256, 0, stream>>>(h, ln1_g + lyr * 1024, ln1_b + lyr * 1024, xn);
        gemm_bt<128, 64, 1, 0, 0, 1><<<dim3(16, 48), 256, 0, stream>>>(
            xn, wqkv, qkv_b + lyr * 3072, nullptr, nullptr, qkv, M, 3072, 1024);
        attn_k<<<dim3(512), 256, 0, stream>>>(qkv, ob);
        gemm_bt<64, 64, 1, 0, 1, 0><<<dim3(32, 16), 256, 0, stream>>>(
            ob, wproj, proj_b + lyr * 1024, h, h, nullptr, M, 1024, 1024);
        ln_k<<<dim3(2048), 256, 0, stream>>>(h, ln2_g + lyr * 1024, ln2_b + lyr * 1024, xn);
        gemm_bt<128, 64, 1, 1, 0, 1><<<dim3(16, 64), 256, 0, stream>>>(
            xn, wfc1, fc1_b + lyr * 4096, nullptr, nullptr, ff, M, 4096, 1024);
        gemm_sk<128, 64><<<dim3(16, 16, 2), 256, 0, stream>>>(
            ff, wfc2, pbuf, M, 1024, 4096);
        fuse2_k<<<dim3(2048), 256, 0, stream>>>(
            pbuf, pbuf + (size_t)M * 1024, fc2_b + lyr * 1024, h);
    }

    ln_k<<<dim3(2048), 256, 0, stream>>>(h, lnf_g, lnf_b, xn);
    cvt_k<<<dim3(2048), 256, 0, stream>>>(head_w, wq, 32000 * 1024 / 4);
    gemm8p<0, 0><<<dim3(8, 125), 512, 0, stream>>>(
        xn, wq, nullptr, out, nullptr, M, 32000, 1024);
}

// Round 7
// 1335.605 us; speedup vs baseline: 1.3326x; 1.0111x over previous
//
#include <hip/hip_runtime.h>

typedef unsigned short u16;
typedef unsigned int   u32;
typedef __bf16 bf16x8 __attribute__((ext_vector_type(8)));
typedef float  f32x4  __attribute__((ext_vector_type(4)));

#define DEV __device__ __forceinline__

DEV u16 f2bf(float f) {
    u32 u = __builtin_bit_cast(u32, f);
    u32 r = u + 0x7FFFu + ((u >> 16) & 1u);
    return (u16)(r >> 16);
}

DEV void gload16(const void* g, void* l) {
    __builtin_amdgcn_global_load_lds((const __attribute__((address_space(1))) void*)g,
                                     (__attribute__((address_space(3))) void*)l, 16, 0, 0);
}

// bijective XCD-aware swizzle (m204)
DEV int xcd_swz(int bid, int nwg) {
    int q = nwg >> 3, r = nwg & 7;
    int xcd = bid & 7, idx = bid >> 3;
    return (xcd < r ? xcd * (q + 1) : r * (q + 1) + (xcd - r) * q) + idx;
}

// involutive LDS byte swizzle for 128B rows: XOR byte bits[6:4] with row bits [0,2,1]
DEV int swz(int p) {
    int m = (((p >> 7) & 1) << 6) | (((p >> 9) & 1) << 5) | (((p >> 8) & 1) << 4);
    return p ^ m;
}

// ---------------- convert f32 -> bf16 (single tensor) ----------------
__global__ void cvt_k(const float* __restrict__ src, u16* __restrict__ dst, int n4) {
    int i = blockIdx.x * blockDim.x + threadIdx.x;
    int stride = gridDim.x * blockDim.x;
    for (; i < n4; i += stride) {
        float4 v = ((const float4*)src)[i];
        ushort4 u;
        u.x = f2bf(v.x); u.y = f2bf(v.y); u.z = f2bf(v.z); u.w = f2bf(v.w);
        ((ushort4*)dst)[i] = u;
    }
}

// ---------------- convert 4 tensors in one launch (per-layer weights) ----------------
__global__ void cvt4_k(const float* __restrict__ s0, const float* __restrict__ s1,
                       const float* __restrict__ s2, const float* __restrict__ s3,
                       u16* __restrict__ dst, int n0, int n1, int n2, int n3) {
    int i = blockIdx.x * blockDim.x + threadIdx.x;
    int stride = gridDim.x * blockDim.x;
    int t0 = n0, t1 = t0 + n1, t2 = t1 + n2, t3 = t2 + n3;
    for (; i < t3; i += stride) {
        const float* s; int j;
        if (i < t0)      { s = s0; j = i; }
        else if (i < t1) { s = s1; j = i - t0; }
        else if (i < t2) { s = s2; j = i - t1; }
        else             { s = s3; j = i - t2; }
        float4 v = ((const float4*)s)[j];
        ushort4 u;
        u.x = f2bf(v.x); u.y = f2bf(v.y); u.z = f2bf(v.z); u.w = f2bf(v.w);
        ((ushort4*)dst)[i] = u;
    }
}

// ---------------- embedding ----------------
__global__ void embed_k(const int* __restrict__ x, const float* __restrict__ te,
                        const float* __restrict__ pe, float* __restrict__ h) {
    int row = blockIdx.x;
    int t = threadIdx.x;
    int tok = x[row];
    int s = row & 1023;
    float4 a = ((const float4*)(te + (size_t)tok * 1024))[t];
    float4 p = ((const float4*)(pe + (size_t)s * 1024))[t];
    a.x += p.x; a.y += p.y; a.z += p.z; a.w += p.w;
    ((float4*)(h + (size_t)row * 1024))[t] = a;
}

// ---------------- LayerNorm: f32 in -> bf16 out ----------------
__global__ void ln_k(const float* __restrict__ in, const float* __restrict__ g,
                     const float* __restrict__ b, u16* __restrict__ out) {
    int row = blockIdx.x;
    int t = threadIdx.x;
    float4 v = ((const float4*)(in + (size_t)row * 1024))[t];
    float s = v.x + v.y + v.z + v.w;
    float s2 = v.x * v.x + v.y * v.y + v.z * v.z + v.w * v.w;
    #pragma unroll
    for (int msk = 1; msk < 64; msk <<= 1) {
        s  += __shfl_xor(s, msk);
        s2 += __shfl_xor(s2, msk);
    }
    __shared__ float ps[4], ps2[4];
    if ((t & 63) == 0) { ps[t >> 6] = s; ps2[t >> 6] = s2; }
    __syncthreads();
    s = ps[0] + ps[1] + ps[2] + ps[3];
    s2 = ps2[0] + ps2[1] + ps2[2] + ps2[3];
    float mu = s * (1.0f / 1024.0f);
    float var = s2 * (1.0f / 1024.0f) - mu * mu;
    float rstd = rsqrtf(var + 1e-5f);
    float4 gg = ((const float4*)g)[t];
    float4 bb = ((const float4*)b)[t];
    ushort4 o;
    o.x = f2bf((v.x - mu) * rstd * gg.x + bb.x);
    o.y = f2bf((v.y - mu) * rstd * gg.y + bb.y);
    o.z = f2bf((v.z - mu) * rstd * gg.z + bb.z);
    o.w = f2bf((v.w - mu) * rstd * gg.w + bb.w);
    ((ushort4*)out)[(size_t)row * 256 + t] = o;
}

// ---------------- fc2 fuse: h += p0 + p1 + bias ----------------
__global__ void fuse2_k(const float* __restrict__ p0, const float* __restrict__ p1,
                        const float* __restrict__ bias, float* __restrict__ h) {
    int row = blockIdx.x;
    int t = threadIdx.x;
    size_t idx = (size_t)row * 256 + t;
    float4 a = ((const float4*)p0)[idx];
    float4 b = ((const float4*)p1)[idx];
    float4 c = ((const float4*)bias)[t];
    float4 v = ((const float4*)h)[idx];
    v.x += a.x + b.x + c.x;
    v.y += a.y + b.y + c.y;
    v.z += a.z + b.z + c.z;
    v.w += a.w + b.w + c.w;
    ((float4*)h)[idx] = v;
}

// ============ 256x256 8-wave 4-phase-per-K-tile GEMM (BK=64, counted vmcnt) ============
template<int PH>
DEV void phase_mma(const bf16x8 (&af)[2][2], const bf16x8 (&bfr)[4][2], f32x4 (&acc)[8][4]) {
    __builtin_amdgcn_s_barrier();
    asm volatile("s_waitcnt lgkmcnt(0)" ::: "memory");
    __builtin_amdgcn_sched_barrier(0);
    __builtin_amdgcn_s_setprio(1);
    #pragma unroll
    for (int ms = 0; ms < 2; ++ms)
        #pragma unroll
        for (int nj = 0; nj < 4; ++nj)
            #pragma unroll
            for (int kk = 0; kk < 2; ++kk)
                acc[PH * 2 + ms][nj] = __builtin_amdgcn_mfma_f32_16x16x32_bf16(
                    af[ms][kk], bfr[nj][kk], acc[PH * 2 + ms][nj], 0, 0, 0);
    __builtin_amdgcn_s_setprio(0);
}

template<int PH>
DEV void read_afrags(const char* Ab, int arow, int fr, int fq, bf16x8 (&af)[2][2]) {
    #pragma unroll
    for (int ms = 0; ms < 2; ++ms)
        #pragma unroll
        for (int kk = 0; kk < 2; ++kk) {
            int lin = (arow + (PH * 2 + ms) * 16 + fr) * 128 + kk * 64 + fq * 16;
            af[ms][kk] = *(const bf16x8*)(Ab + swz(lin));
        }
}

template<int BIAS, int OUTBF>
__global__ __launch_bounds__(512, 2)
void gemm8p(const u16* __restrict__ A, const u16* __restrict__ Bw,
            const float* __restrict__ bias,
            float* __restrict__ outf, u16* __restrict__ outb,
            int M, int N, int K) {
    __shared__ char lds[131072];
    char* ldsA = lds;
    char* ldsB = lds + 65536;
    const int t = threadIdx.x;
    const int w = t >> 6, l = t & 63;
    const int fr = l & 15, fq = l >> 4;
    const int wm = w >> 2, wn = w & 3;

    int bid = blockIdx.y * gridDim.x + blockIdx.x;
    int swzb = xcd_swz(bid, gridDim.x * gridDim.y);
    const int m0 = (swzb % gridDim.x) * 256;
    const int n0 = (swzb / gridDim.x) * 256;
    const int nt = K >> 6;
    const int arow = wm * 128;

    const u16* Asrc = A + (size_t)m0 * K;
    const u16* Bsrc = Bw + (size_t)n0 * K;

    size_t o00, o01, o10, o11;
    {
        int p;
        p = 0 * 16384 + 0 * 8192 + t * 16; o00 = (size_t)(p >> 7) * K + ((swz(p) & 127) >> 1);
        p = 0 * 16384 + 1 * 8192 + t * 16; o01 = (size_t)(p >> 7) * K + ((swz(p) & 127) >> 1);
        p = 1 * 16384 + 0 * 8192 + t * 16; o10 = (size_t)(p >> 7) * K + ((swz(p) & 127) >> 1);
        p = 1 * 16384 + 1 * 8192 + t * 16; o11 = (size_t)(p >> 7) * K + ((swz(p) & 127) >> 1);
    }
    const int wb = w * 1024;

    gload16(Asrc + o00, ldsA + wb);
    gload16(Asrc + o01, ldsA + 8192 + wb);
    gload16(Asrc + o10, ldsA + 16384 + wb);
    gload16(Asrc + o11, ldsA + 16384 + 8192 + wb);
    gload16(Bsrc + o00, ldsB + wb);
    gload16(Bsrc + o01, ldsB + 8192 + wb);
    gload16(Bsrc + o10, ldsB + 16384 + wb);
    gload16(Bsrc + o11, ldsB + 16384 + 8192 + wb);
    gload16(Bsrc + o00 + 64, ldsB + 32768 + wb);
    gload16(Bsrc + o01 + 64, ldsB + 32768 + 8192 + wb);
    gload16(Bsrc + o10 + 64, ldsB + 32768 + 16384 + wb);
    gload16(Bsrc + o11 + 64, ldsB + 32768 + 16384 + 8192 + wb);
    asm volatile("s_waitcnt vmcnt(4)" ::: "memory");
    __builtin_amdgcn_s_barrier();
    __builtin_amdgcn_sched_barrier(0);

    f32x4 acc[8][4] = {};

    for (int T = 0; T < nt; ++T) {
        const char* Ab = ldsA + (T & 1) * 32768;
        const char* Bb = ldsB + (T & 1) * 32768;
        char* Anx = ldsA + ((T + 1) & 1) * 32768;
        char* Bnx = ldsB + (T & 1) * 32768;
        const bool stA = (T + 1 < nt), stB = (T + 2 < nt);
        const size_t kA = (size_t)(T + 1) * 64, kB = (size_t)(T + 2) * 64;

        bf16x8 bfr[4][2], af[2][2];

        #pragma unroll
        for (int nj = 0; nj < 4; ++nj)
            #pragma unroll
            for (int kk = 0; kk < 2; ++kk) {
                int lin = (wn * 64 + nj * 16 + fr) * 128 + kk * 64 + fq * 16;
                bfr[nj][kk] = *(const bf16x8*)(Bb + swz(lin));
            }
        read_afrags<0>(Ab, arow, fr, fq, af);
        if (stA) {
            gload16(Asrc + o00 + kA, Anx + wb);
            gload16(Asrc + o01 + kA, Anx + 8192 + wb);
        }
        phase_mma<0>(af, bfr, acc);
        __builtin_amdgcn_s_barrier();

        read_afrags<1>(Ab, arow, fr, fq, af);
        if (stA) {
            gload16(Asrc + o10 + kA, Anx + 16384 + wb);
            gload16(Asrc + o11 + kA, Anx + 16384 + 8192 + wb);
        }
        phase_mma<1>(af, bfr, acc);
        __builtin_amdgcn_s_barrier();

        read_afrags<2>(Ab, arow, fr, fq, af);
        if (stB) {
            gload16(Bsrc + o00 + kB, Bnx + wb);
            gload16(Bsrc + o01 + kB, Bnx + 8192 + wb);
        }
        phase_mma<2>(af, bfr, acc);
        __builtin_amdgcn_s_barrier();

        read_afrags<3>(Ab, arow, fr, fq, af);
        if (stB) {
            gload16(Bsrc + o10 + kB, Bnx + 16384 + wb);
            gload16(Bsrc + o11 + kB, Bnx + 16384 + 8192 + wb);
        }
        phase_mma<3>(af, bfr, acc);
        if (stB)      asm volatile("s_waitcnt vmcnt(4)" ::: "memory");
        else if (stA) asm volatile("s_waitcnt vmcnt(0)" ::: "memory");
        __builtin_amdgcn_s_barrier();
        __builtin_amdgcn_sched_barrier(0);
    }

    #pragma unroll
    for (int mi = 0; mi < 8; ++mi) {
        #pragma unroll
        for (int nj = 0; nj < 4; ++nj) {
            #pragma unroll
            for (int r = 0; r < 4; ++r) {
                int row = m0 + wm * 128 + mi * 16 + fq * 4 + r;
                int col = n0 + wn * 64 + nj * 16 + fr;
                float v = acc[mi][nj][r];
                if (BIAS) v += bias[col];
                if (OUTBF) outb[(size_t)row * N + col] = f2bf(v);
                else       outf[(size_t)row * N + col] = v;
            }
        }
    }
}

// ---------------- 2-phase double-buffered GEMM (issue-early staging, 1 barrier/tile) ----------------
// SPLITK: grid.z halves K; writes f32 partials to outf + z*M*N (no bias/gelu/res).
template<int BM, int BN, int BIAS, int GELU_, int RES, int OUTBF, int SPLITK>
__global__ void gemm_db(const u16* __restrict__ A, const u16* __restrict__ Bw,
                        const float* __restrict__ bias, const float* __restrict__ res,
                        float* __restrict__ outf, u16* __restrict__ outb,
                        int M, int N, int K) {
    constexpr int MR = BM / 32;
    constexpr int NR = BN / 32;
    constexpr int AL = BM / 64;
    constexpr int BL = BN / 64;
    __shared__ u16 lA[2][BM * 32];
    __shared__ u16 lB[2][BN * 32];
    const int t = threadIdx.x;
    const int w = t >> 6, l = t & 63;

    int bid = blockIdx.y * gridDim.x + blockIdx.x;
    int swzb = xcd_swz(bid, gridDim.x * gridDim.y);
    const int m0 = (swzb % gridDim.x) * BM;
    const int n0 = (swzb / gridDim.x) * BN;

    int kbase = 0, Keff = K;
    if (SPLITK) { Keff = K >> 1; kbase = blockIdx.z * Keff; }
    const int nt = Keff >> 5;

    const int wr = (w >> 1) * (BM / 2), wc = (w & 1) * (BN / 2);
    const int fr = l & 15, fq = l >> 4;
    const int g0 = w * 64 + l;

    // per-thread staging source offsets (constant across tiles)
    const int srow = g0 >> 2, scol = (g0 & 3) * 8;

    f32x4 acc[MR][NR] = {};

    // prologue: stage tile 0 -> buf 0
    #pragma unroll
    for (int i = 0; i < AL; ++i)
        gload16(A + (size_t)(m0 + srow + i * 64) * K + kbase + scol, lA[0] + (srow + i * 64) * 32 + scol);
    #pragma unroll
    for (int i = 0; i < BL; ++i)
        gload16(Bw + (size_t)(n0 + srow + i * 64) * K + kbase + scol, lB[0] + (srow + i * 64) * 32 + scol);
    __syncthreads();

    for (int T = 0; T < nt; ++T) {
        const int cur = T & 1, nxt = cur ^ 1;
        if (T + 1 < nt) {
            const int kk = kbase + (T + 1) * 32;
            #pragma unroll
            for (int i = 0; i < AL; ++i)
                gload16(A + (size_t)(m0 + srow + i * 64) * K + kk + scol, lA[nxt] + (srow + i * 64) * 32 + scol);
            #pragma unroll
            for (int i = 0; i < BL; ++i)
                gload16(Bw + (size_t)(n0 + srow + i * 64) * K + kk + scol, lB[nxt] + (srow + i * 64) * 32 + scol);
        }
        bf16x8 af[MR], bfv[NR];
        #pragma unroll
        for (int mi = 0; mi < MR; ++mi)
            af[mi] = *(const bf16x8*)(lA[cur] + (wr + mi * 16 + fr) * 32 + fq * 8);
        #pragma unroll
        for (int ni = 0; ni < NR; ++ni)
            bfv[ni] = *(const bf16x8*)(lB[cur] + (wc + ni * 16 + fr) * 32 + fq * 8);
        #pragma unroll
        for (int mi = 0; mi < MR; ++mi)
            #pragma unroll
            for (int ni = 0; ni < NR; ++ni)
                acc[mi][ni] = __builtin_amdgcn_mfma_f32_16x16x32_bf16(af[mi], bfv[ni], acc[mi][ni], 0, 0, 0);
        __syncthreads();   // drains vmcnt(0)+lgkmcnt(0): next tile staged, reads done
    }

    float* op = outf;
    if (SPLITK) op = outf + (size_t)blockIdx.z * M * N;

    #pragma unroll
    for (int mi = 0; mi < MR; ++mi) {
        #pragma unroll
        for (int ni = 0; ni < NR; ++ni) {
            #pragma unroll
            for (int r = 0; r < 4; ++r) {
                int row = m0 + wr + mi * 16 + fq * 4 + r;
                int col = n0 + wc + ni * 16 + fr;
                float v = acc[mi][ni][r];
                if (BIAS) v += bias[col];
                if (GELU_) v = 0.5f * v * (1.0f + erff(v * 0.70710678118f));
                if (RES) v += res[(size_t)row * N + col];
                if (OUTBF) outb[(size_t)row * N + col] = f2bf(v);
                else       op[(size_t)row * N + col] = v;
            }
        }
    }
}

// ---------------- Flash attention (swizzled LDS, XCD-chunked grid) ----------------
__global__ void attn_k(const u16* __restrict__ qkv, u16* __restrict__ o) {
    __shared__ u16 lK[64 * 64];
    __shared__ u16 lV[64 * 64];
    __shared__ u16 lP[4 * 16 * 64];
    const int t = threadIdx.x;
    const int w = t >> 6, l = t & 63;
    const int fr = l & 15, fq = l >> 4;

    int swzb = xcd_swz(blockIdx.x, gridDim.x);
    const int qb = 15 - (swzb & 15);
    const int hh = (swzb >> 4) & 15;
    const int b  = swzb >> 8;
    const int q0 = qb * 64;

    const u16* srcK[2];
    #pragma unroll
    for (int i = 0; i < 2; ++i) {
        int p = (t + i * 256) * 16;
        int L = swz(p);
        srcK[i] = qkv + ((size_t)(b * 1024) + (L >> 7)) * 3072 + 1024 + hh * 64 + ((L & 127) >> 1);
    }

    bf16x8 qf[2];
    {
        size_t base = ((size_t)(b * 1024) + q0 + w * 16 + fr) * 3072 + hh * 64;
        qf[0] = *(const bf16x8*)(qkv + base + fq * 8);
        qf[1] = *(const bf16x8*)(qkv + base + 32 + fq * 8);
    }

    float m_run[4], l_run[4];
    f32x4 acc_o[4] = {};
    #pragma unroll
    for (int r = 0; r < 4; ++r) { m_run[r] = -__builtin_inff(); l_run[r] = 0.0f; }

    for (int kv0 = 0; kv0 <= q0; kv0 += 64) {
        #pragma unroll
        for (int i = 0; i < 2; ++i)
            gload16(srcK[i] + (size_t)kv0 * 3072, (char*)lK + w * 1024 + i * 4096);
        #pragma unroll
        for (int i = 0; i < 2; ++i) {
            int g = t + i * 256;
            int kv = g >> 3, d0 = (g & 7) * 8;
            const u32* gv = (const u32*)(qkv + ((size_t)(b * 1024) + kv0 + kv) * 3072 + 2048 + hh * 64 + d0);
            u32 v0 = gv[0], v1 = gv[1], v2 = gv[2], v3 = gv[3];
            u16 e[8] = { (u16)v0, (u16)(v0 >> 16), (u16)v1, (u16)(v1 >> 16),
                         (u16)v2, (u16)(v2 >> 16), (u16)v3, (u16)(v3 >> 16) };
            #pragma unroll
            for (int j = 0; j < 8; ++j) {
                int pv = ((d0 + j) * 64 + kv) * 2;
                *(u16*)((char*)lV + swz(pv)) = e[j];
            }
        }
        __syncthreads();

        f32x4 accs[4] = {};
        #pragma unroll
        for (int nt = 0; nt < 4; ++nt) {
            #pragma unroll
            for (int ks = 0; ks < 2; ++ks) {
                int pk = ((nt * 16 + fr) * 64 + ks * 32 + fq * 8) * 2;
                bf16x8 kf = *(const bf16x8*)((const char*)lK + swz(pk));
                accs[nt] = __builtin_amdgcn_mfma_f32_16x16x32_bf16(qf[ks], kf, accs[nt], 0, 0, 0);
            }
        }

        float p[4][4], mx[4], rs[4];
        #pragma unroll
        for (int r = 0; r < 4; ++r) {
            int qg = q0 + w * 16 + fq * 4 + r;
            float m = -__builtin_inff();
            #pragma unroll
            for (int nt = 0; nt < 4; ++nt) {
                int kvg = kv0 + nt * 16 + fr;
                float s = (kvg <= qg) ? accs[nt][r] * 0.125f : -__builtin_inff();
                p[nt][r] = s;
                m = fmaxf(m, s);
            }
            mx[r] = m;
        }
        #pragma unroll
        for (int msk = 1; msk < 16; msk <<= 1) {
            #pragma unroll
            for (int r = 0; r < 4; ++r) mx[r] = fmaxf(mx[r], __shfl_xor(mx[r], msk));
        }
        float mnew[4], alpha[4];
        #pragma unroll
        for (int r = 0; r < 4; ++r) {
            mnew[r] = fmaxf(m_run[r], mx[r]);
            alpha[r] = __expf(m_run[r] - mnew[r]);
            float s = 0.0f;
            #pragma unroll
            for (int nt = 0; nt < 4; ++nt) {
                float pv = __expf(p[nt][r] - mnew[r]);
                p[nt][r] = pv;
                s += pv;
            }
            rs[r] = s;
        }
        #pragma unroll
        for (int msk = 1; msk < 16; msk <<= 1) {
            #pragma unroll
            for (int r = 0; r < 4; ++r) rs[r] += __shfl_xor(rs[r], msk);
        }
        #pragma unroll
        for (int r = 0; r < 4; ++r) {
            l_run[r] = l_run[r] * alpha[r] + rs[r];
            m_run[r] = mnew[r];
        }
        #pragma unroll
        for (int nt = 0; nt < 4; ++nt)
            #pragma unroll
            for (int r = 0; r < 4; ++r) acc_o[nt][r] *= alpha[r];

        #pragma unroll
        for (int nt = 0; nt < 4; ++nt)
            #pragma unroll
            for (int r = 0; r < 4; ++r) {
                int pp = (w * 1024 + (fq * 4 + r) * 64 + nt * 16 + fr) * 2;
                *(u16*)((char*)lP + swz(pp)) = f2bf(p[nt][r]);
            }
        __syncthreads();

        bf16x8 pa[2];
        #pragma unroll
        for (int ks = 0; ks < 2; ++ks) {
            int ppr = (w * 1024 + fr * 64 + ks * 32 + fq * 8) * 2;
            pa[ks] = *(const bf16x8*)((const char*)lP + swz(ppr));
        }
        #pragma unroll
        for (int nt = 0; nt < 4; ++nt) {
            #pragma unroll
            for (int ks = 0; ks < 2; ++ks) {
                int pvr = ((nt * 16 + fr) * 64 + ks * 32 + fq * 8) * 2;
                bf16x8 vf = *(const bf16x8*)((const char*)lV + swz(pvr));
                acc_o[nt] = __builtin_amdgcn_mfma_f32_16x16x32_bf16(pa[ks], vf, acc_o[nt], 0, 0, 0);
            }
        }
        __syncthreads();
    }

    #pragma unroll
    for (int nt = 0; nt < 4; ++nt) {
        #pragma unroll
        for (int r = 0; r < 4; ++r) {
            int qg = q0 + w * 16 + fq * 4 + r;
            int d = nt * 16 + fr;
            float ov = acc_o[nt][r] / l_run[r];
            o[((size_t)(b * 1024) + qg) * 1024 + hh * 64 + d] = f2bf(ov);
        }
    }
}

// ---------------- launch ----------------
extern "C" void kernel_launch(void* const* d_in, const int* in_sizes, int n_in,
                              void* d_out, int out_size, void* d_ws, size_t ws_size,
                              hipStream_t stream) {
    const int*   x       = (const int*)  d_in[0];
    const float* tok_emb = (const float*)d_in[1];
    const float* pos_emb = (const float*)d_in[2];
    const float* ln1_g   = (const float*)d_in[3];
    const float* ln1_b   = (const float*)d_in[4];
    const float* qkv_w   = (const float*)d_in[5];
    const float* qkv_b   = (const float*)d_in[6];
    const float* proj_w  = (const float*)d_in[7];
    const float* proj_b  = (const float*)d_in[8];
    const float* ln2_g   = (const float*)d_in[9];
    const float* ln2_b   = (const float*)d_in[10];
    const float* fc1_w   = (const float*)d_in[11];
    const float* fc1_b   = (const float*)d_in[12];
    const float* fc2_w   = (const float*)d_in[13];
    const float* fc2_b   = (const float*)d_in[14];
    const float* lnf_g   = (const float*)d_in[15];
    const float* lnf_b   = (const float*)d_in[16];
    const float* head_w  = (const float*)d_in[17];
    float* out = (float*)d_out;

    char* ws = (char*)d_ws;
    float* h   = (float*)(ws + 0);            //  8 MB f32 (2048x1024)
    u16*   xn  = (u16*)(ws + 8388608);        //  4 MB bf16
    u16*   qkv = (u16*)(ws + 12582912);       // 12.6 MB bf16 (2048x3072)
    u16*   ob  = (u16*)(ws + 25165824);       //  4 MB bf16
    u16*   ff  = (u16*)(ws + 29360128);       // 16.8 MB bf16 (2048x4096)
    u16*   wq  = (u16*)(ws + 46137344);       // 65.5 MB bf16 weight slab
    float* pbuf = (float*)(ws + 12582912);    // fc2 split-K partials (16 MB f32, dead region)

    u16* wqkv = wq;
    u16* wproj = wqkv + 3072 * 1024;
    u16* wfc1  = wproj + 1024 * 1024;
    u16* wfc2  = wfc1 + 4096 * 1024;

    const int M = 2048;

    embed_k<<<dim3(2048), 256, 0, stream>>>(x, tok_emb, pos_emb, h);

    for (int lyr = 0; lyr < 6; ++lyr) {
        cvt4_k<<<dim3(2048), 256, 0, stream>>>(
            qkv_w + (size_t)lyr * 3072 * 1024, proj_w + (size_t)lyr * 1024 * 1024,
            fc1_w + (size_t)lyr * 4096 * 1024, fc2_w + (size_t)lyr * 1024 * 4096,
            wq, 3072 * 256, 1024 * 256, 4096 * 256, 4096 * 256);
        ln_k<<<dim3(2048), 256, 0, stream>>>(h, ln1_g + lyr * 1024, ln1_b + lyr * 1024, xn);
        gemm_db<128, 64, 1, 0, 0, 1, 0><<<dim3(16, 48), 256, 0, stream>>>(
            xn, wqkv, qkv_b + lyr * 3072, nullptr, nullptr, qkv, M, 3072, 1024);
        attn_k<<<dim3(512), 256, 0, stream>>>(qkv, ob);
        gemm_db<64, 64, 1, 0, 1, 0, 0><<<dim3(32, 16), 256, 0, stream>>>(
            ob, wproj, proj_b + lyr * 1024, h, h, nullptr, M, 1024, 1024);
        ln_k<<<dim3(2048), 256, 0, stream>>>(h, ln2_g + lyr * 1024, ln2_b + lyr * 1024, xn);
        gemm_db<128, 64, 1, 1, 0, 1, 0><<<dim3(16, 64), 256, 0, stream>>>(
            xn, wfc1, fc1_b + lyr * 4096, nullptr, nullptr, ff, M, 4096, 1024);
        gemm_db<128, 64, 0, 0, 0, 0, 1><<<dim3(16, 16, 2), 256, 0, stream>>>(
            ff, wfc2, nullptr, nullptr, pbuf, nullptr, M, 1024, 4096);
        fuse2_k<<<dim3(2048), 256, 0, stream>>>(
            pbuf, pbuf + (size_t)M * 1024, fc2_b + lyr * 1024, h);
    }

    ln_k<<<dim3(2048), 256, 0, stream>>>(h, lnf_g, lnf_b, xn);
    cvt_k<<<dim3(2048), 256, 0, stream>>>(head_w, wq, 32000 * 1024 / 4);
    gemm8p<0, 0><<<dim3(8, 125), 512, 0, stream>>>(
        xn, wq, nullptr, out, nullptr, M, 32000, 1024);
}

// Round 8
// 1256.096 us; speedup vs baseline: 1.4170x; 1.0633x over previous
//
#include <hip/hip_runtime.h>

typedef unsigned short u16;
typedef unsigned int   u32;
typedef __bf16 bf16x8 __attribute__((ext_vector_type(8)));
typedef float  f32x4  __attribute__((ext_vector_type(4)));

#define DEV __device__ __forceinline__

DEV u16 f2bf(float f) {
    u32 u = __builtin_bit_cast(u32, f);
    u32 r = u + 0x7FFFu + ((u >> 16) & 1u);
    return (u16)(r >> 16);
}

DEV void gload16(const void* g, void* l) {
    __builtin_amdgcn_global_load_lds((const __attribute__((address_space(1))) void*)g,
                                     (__attribute__((address_space(3))) void*)l, 16, 0, 0);
}

// bijective XCD-aware swizzle (m204)
DEV int xcd_swz(int bid, int nwg) {
    int q = nwg >> 3, r = nwg & 7;
    int xcd = bid & 7, idx = bid >> 3;
    return (xcd < r ? xcd * (q + 1) : r * (q + 1) + (xcd - r) * q) + idx;
}

// involutive LDS byte swizzle for 128B rows: XOR byte bits[6:4] with row bits [0,2,1]
DEV int swz(int p) {
    int m = (((p >> 7) & 1) << 6) | (((p >> 9) & 1) << 5) | (((p >> 8) & 1) << 4);
    return p ^ m;
}

// ---------------- convert f32 -> bf16 (single tensor) ----------------
__global__ void cvt_k(const float* __restrict__ src, u16* __restrict__ dst, int n4) {
    int i = blockIdx.x * blockDim.x + threadIdx.x;
    int stride = gridDim.x * blockDim.x;
    for (; i < n4; i += stride) {
        float4 v = ((const float4*)src)[i];
        ushort4 u;
        u.x = f2bf(v.x); u.y = f2bf(v.y); u.z = f2bf(v.z); u.w = f2bf(v.w);
        ((ushort4*)dst)[i] = u;
    }
}

// ---------------- convert 4 tensors in one launch (per-layer weights) ----------------
__global__ void cvt4_k(const float* __restrict__ s0, const float* __restrict__ s1,
                       const float* __restrict__ s2, const float* __restrict__ s3,
                       u16* __restrict__ dst, int n0, int n1, int n2, int n3) {
    int i = blockIdx.x * blockDim.x + threadIdx.x;
    int stride = gridDim.x * blockDim.x;
    int t0 = n0, t1 = t0 + n1, t2 = t1 + n2, t3 = t2 + n3;
    for (; i < t3; i += stride) {
        const float* s; int j;
        if (i < t0)      { s = s0; j = i; }
        else if (i < t1) { s = s1; j = i - t0; }
        else if (i < t2) { s = s2; j = i - t1; }
        else             { s = s3; j = i - t2; }
        float4 v = ((const float4*)s)[j];
        ushort4 u;
        u.x = f2bf(v.x); u.y = f2bf(v.y); u.z = f2bf(v.z); u.w = f2bf(v.w);
        ((ushort4*)dst)[i] = u;
    }
}

// ---------------- embedding ----------------
__global__ void embed_k(const int* __restrict__ x, const float* __restrict__ te,
                        const float* __restrict__ pe, float* __restrict__ h) {
    int row = blockIdx.x;
    int t = threadIdx.x;
    int tok = x[row];
    int s = row & 1023;
    float4 a = ((const float4*)(te + (size_t)tok * 1024))[t];
    float4 p = ((const float4*)(pe + (size_t)s * 1024))[t];
    a.x += p.x; a.y += p.y; a.z += p.z; a.w += p.w;
    ((float4*)(h + (size_t)row * 1024))[t] = a;
}

// ---------------- LayerNorm: f32 in -> bf16 out ----------------
__global__ void ln_k(const float* __restrict__ in, const float* __restrict__ g,
                     const float* __restrict__ b, u16* __restrict__ out) {
    int row = blockIdx.x;
    int t = threadIdx.x;
    float4 v = ((const float4*)(in + (size_t)row * 1024))[t];
    float s = v.x + v.y + v.z + v.w;
    float s2 = v.x * v.x + v.y * v.y + v.z * v.z + v.w * v.w;
    #pragma unroll
    for (int msk = 1; msk < 64; msk <<= 1) {
        s  += __shfl_xor(s, msk);
        s2 += __shfl_xor(s2, msk);
    }
    __shared__ float ps[4], ps2[4];
    if ((t & 63) == 0) { ps[t >> 6] = s; ps2[t >> 6] = s2; }
    __syncthreads();
    s = ps[0] + ps[1] + ps[2] + ps[3];
    s2 = ps2[0] + ps2[1] + ps2[2] + ps2[3];
    float mu = s * (1.0f / 1024.0f);
    float var = s2 * (1.0f / 1024.0f) - mu * mu;
    float rstd = rsqrtf(var + 1e-5f);
    float4 gg = ((const float4*)g)[t];
    float4 bb = ((const float4*)b)[t];
    ushort4 o;
    o.x = f2bf((v.x - mu) * rstd * gg.x + bb.x);
    o.y = f2bf((v.y - mu) * rstd * gg.y + bb.y);
    o.z = f2bf((v.z - mu) * rstd * gg.z + bb.z);
    o.w = f2bf((v.w - mu) * rstd * gg.w + bb.w);
    ((ushort4*)out)[(size_t)row * 256 + t] = o;
}

// ---------------- fc2 fuse: h += p0 + p1 + bias ----------------
__global__ void fuse2_k(const float* __restrict__ p0, const float* __restrict__ p1,
                        const float* __restrict__ bias, float* __restrict__ h) {
    int row = blockIdx.x;
    int t = threadIdx.x;
    size_t idx = (size_t)row * 256 + t;
    float4 a = ((const float4*)p0)[idx];
    float4 b = ((const float4*)p1)[idx];
    float4 c = ((const float4*)bias)[t];
    float4 v = ((const float4*)h)[idx];
    v.x += a.x + b.x + c.x;
    v.y += a.y + b.y + c.y;
    v.z += a.z + b.z + c.z;
    v.w += a.w + b.w + c.w;
    ((float4*)h)[idx] = v;
}

// ============ 256x256 8-wave 4-phase-per-K-tile GEMM (BK=64, counted vmcnt) ============
template<int PH>
DEV void phase_mma(const bf16x8 (&af)[2][2], const bf16x8 (&bfr)[4][2], f32x4 (&acc)[8][4]) {
    __builtin_amdgcn_s_barrier();
    asm volatile("s_waitcnt lgkmcnt(0)" ::: "memory");
    __builtin_amdgcn_sched_barrier(0);
    __builtin_amdgcn_s_setprio(1);
    #pragma unroll
    for (int ms = 0; ms < 2; ++ms)
        #pragma unroll
        for (int nj = 0; nj < 4; ++nj)
            #pragma unroll
            for (int kk = 0; kk < 2; ++kk)
                acc[PH * 2 + ms][nj] = __builtin_amdgcn_mfma_f32_16x16x32_bf16(
                    af[ms][kk], bfr[nj][kk], acc[PH * 2 + ms][nj], 0, 0, 0);
    __builtin_amdgcn_s_setprio(0);
}

template<int PH>
DEV void read_afrags(const char* Ab, int arow, int fr, int fq, bf16x8 (&af)[2][2]) {
    #pragma unroll
    for (int ms = 0; ms < 2; ++ms)
        #pragma unroll
        for (int kk = 0; kk < 2; ++kk) {
            int lin = (arow + (PH * 2 + ms) * 16 + fr) * 128 + kk * 64 + fq * 16;
            af[ms][kk] = *(const bf16x8*)(Ab + swz(lin));
        }
}

template<int BIAS, int OUTBF>
__global__ __launch_bounds__(512, 2)
void gemm8p(const u16* __restrict__ A, const u16* __restrict__ Bw,
            const float* __restrict__ bias,
            float* __restrict__ outf, u16* __restrict__ outb,
            int M, int N, int K) {
    __shared__ char lds[131072];
    char* ldsA = lds;
    char* ldsB = lds + 65536;
    const int t = threadIdx.x;
    const int w = t >> 6, l = t & 63;
    const int fr = l & 15, fq = l >> 4;
    const int wm = w >> 2, wn = w & 3;

    int bid = blockIdx.y * gridDim.x + blockIdx.x;
    int swzb = xcd_swz(bid, gridDim.x * gridDim.y);
    const int m0 = (swzb % gridDim.x) * 256;
    const int n0 = (swzb / gridDim.x) * 256;
    const int nt = K >> 6;
    const int arow = wm * 128;

    const u16* Asrc = A + (size_t)m0 * K;
    const u16* Bsrc = Bw + (size_t)n0 * K;

    size_t o00, o01, o10, o11;
    {
        int p;
        p = 0 * 16384 + 0 * 8192 + t * 16; o00 = (size_t)(p >> 7) * K + ((swz(p) & 127) >> 1);
        p = 0 * 16384 + 1 * 8192 + t * 16; o01 = (size_t)(p >> 7) * K + ((swz(p) & 127) >> 1);
        p = 1 * 16384 + 0 * 8192 + t * 16; o10 = (size_t)(p >> 7) * K + ((swz(p) & 127) >> 1);
        p = 1 * 16384 + 1 * 8192 + t * 16; o11 = (size_t)(p >> 7) * K + ((swz(p) & 127) >> 1);
    }
    const int wb = w * 1024;

    gload16(Asrc + o00, ldsA + wb);
    gload16(Asrc + o01, ldsA + 8192 + wb);
    gload16(Asrc + o10, ldsA + 16384 + wb);
    gload16(Asrc + o11, ldsA + 16384 + 8192 + wb);
    gload16(Bsrc + o00, ldsB + wb);
    gload16(Bsrc + o01, ldsB + 8192 + wb);
    gload16(Bsrc + o10, ldsB + 16384 + wb);
    gload16(Bsrc + o11, ldsB + 16384 + 8192 + wb);
    gload16(Bsrc + o00 + 64, ldsB + 32768 + wb);
    gload16(Bsrc + o01 + 64, ldsB + 32768 + 8192 + wb);
    gload16(Bsrc + o10 + 64, ldsB + 32768 + 16384 + wb);
    gload16(Bsrc + o11 + 64, ldsB + 32768 + 16384 + 8192 + wb);
    asm volatile("s_waitcnt vmcnt(4)" ::: "memory");
    __builtin_amdgcn_s_barrier();
    __builtin_amdgcn_sched_barrier(0);

    f32x4 acc[8][4] = {};

    for (int T = 0; T < nt; ++T) {
        const char* Ab = ldsA + (T & 1) * 32768;
        const char* Bb = ldsB + (T & 1) * 32768;
        char* Anx = ldsA + ((T + 1) & 1) * 32768;
        char* Bnx = ldsB + (T & 1) * 32768;
        const bool stA = (T + 1 < nt), stB = (T + 2 < nt);
        const size_t kA = (size_t)(T + 1) * 64, kB = (size_t)(T + 2) * 64;

        bf16x8 bfr[4][2], af[2][2];

        #pragma unroll
        for (int nj = 0; nj < 4; ++nj)
            #pragma unroll
            for (int kk = 0; kk < 2; ++kk) {
                int lin = (wn * 64 + nj * 16 + fr) * 128 + kk * 64 + fq * 16;
                bfr[nj][kk] = *(const bf16x8*)(Bb + swz(lin));
            }
        read_afrags<0>(Ab, arow, fr, fq, af);
        if (stA) {
            gload16(Asrc + o00 + kA, Anx + wb);
            gload16(Asrc + o01 + kA, Anx + 8192 + wb);
        }
        phase_mma<0>(af, bfr, acc);
        __builtin_amdgcn_s_barrier();

        read_afrags<1>(Ab, arow, fr, fq, af);
        if (stA) {
            gload16(Asrc + o10 + kA, Anx + 16384 + wb);
            gload16(Asrc + o11 + kA, Anx + 16384 + 8192 + wb);
        }
        phase_mma<1>(af, bfr, acc);
        __builtin_amdgcn_s_barrier();

        read_afrags<2>(Ab, arow, fr, fq, af);
        if (stB) {
            gload16(Bsrc + o00 + kB, Bnx + wb);
            gload16(Bsrc + o01 + kB, Bnx + 8192 + wb);
        }
        phase_mma<2>(af, bfr, acc);
        __builtin_amdgcn_s_barrier();

        read_afrags<3>(Ab, arow, fr, fq, af);
        if (stB) {
            gload16(Bsrc + o10 + kB, Bnx + 16384 + wb);
            gload16(Bsrc + o11 + kB, Bnx + 16384 + 8192 + wb);
        }
        phase_mma<3>(af, bfr, acc);
        if (stB)      asm volatile("s_waitcnt vmcnt(4)" ::: "memory");
        else if (stA) asm volatile("s_waitcnt vmcnt(0)" ::: "memory");
        __builtin_amdgcn_s_barrier();
        __builtin_amdgcn_sched_barrier(0);
    }

    #pragma unroll
    for (int mi = 0; mi < 8; ++mi) {
        #pragma unroll
        for (int nj = 0; nj < 4; ++nj) {
            #pragma unroll
            for (int r = 0; r < 4; ++r) {
                int row = m0 + wm * 128 + mi * 16 + fq * 4 + r;
                int col = n0 + wn * 64 + nj * 16 + fr;
                float v = acc[mi][nj][r];
                if (BIAS) v += bias[col];
                if (OUTBF) outb[(size_t)row * N + col] = f2bf(v);
                else       outf[(size_t)row * N + col] = v;
            }
        }
    }
}

// ============ 128x128 8-wave 2-phase-per-K-tile GEMM (gemm8p halved; BK=64, vmcnt(2)) ============
template<int BIAS, int GELU_, int OUTBF, int SPLITK>
__global__ __launch_bounds__(512, 2)
void gemm4p(const u16* __restrict__ A, const u16* __restrict__ Bw,
            const float* __restrict__ bias,
            float* __restrict__ outf, u16* __restrict__ outb,
            int M, int N, int K) {
    __shared__ char lds[65536];
    char* ldsA = lds;            // 2 x 16384
    char* ldsB = lds + 32768;    // 2 x 16384
    const int t = threadIdx.x;
    const int w = t >> 6, l = t & 63;
    const int fr = l & 15, fq = l >> 4;
    const int wm = w >> 2, wn = w & 3;     // 2 x 4 waves -> 64x32 out each

    int bid = blockIdx.y * gridDim.x + blockIdx.x;
    int swzb = xcd_swz(bid, gridDim.x * gridDim.y);
    const int m0 = (swzb % gridDim.x) * 128;
    const int n0 = (swzb / gridDim.x) * 128;

    int kbase = 0, Keff = K;
    if (SPLITK) { Keff = K >> 1; kbase = blockIdx.z * Keff; }
    const int nt = Keff >> 6;

    const u16* Asrc = A + (size_t)m0 * K + kbase;
    const u16* Bsrc = Bw + (size_t)n0 * K + kbase;

    size_t o0, o1;
    {
        int p = t * 16;        o0 = (size_t)(p >> 7) * K + ((swz(p) & 127) >> 1);
        p = 8192 + t * 16;     o1 = (size_t)(p >> 7) * K + ((swz(p) & 127) >> 1);
    }
    const int wb = w * 1024;

    // prologue: A(0), B(0), B(1)  (6 loads; oldest 4 = A0+B0 -> vmcnt(2))
    gload16(Asrc + o0, ldsA + wb);
    gload16(Asrc + o1, ldsA + 8192 + wb);
    gload16(Bsrc + o0, ldsB + wb);
    gload16(Bsrc + o1, ldsB + 8192 + wb);
    gload16(Bsrc + o0 + 64, ldsB + 16384 + wb);
    gload16(Bsrc + o1 + 64, ldsB + 16384 + 8192 + wb);
    asm volatile("s_waitcnt vmcnt(2)" ::: "memory");
    __builtin_amdgcn_s_barrier();
    __builtin_amdgcn_sched_barrier(0);

    f32x4 acc[4][2] = {};

    for (int T = 0; T < nt; ++T) {
        const char* Ab = ldsA + (T & 1) * 16384;
        const char* Bb = ldsB + (T & 1) * 16384;
        char* Anx = ldsA + ((T + 1) & 1) * 16384;
        char* Bnx = ldsB + (T & 1) * 16384;            // B(T+2) parity == T parity
        const bool stA = (T + 1 < nt), stB = (T + 2 < nt);
        const size_t kA = (size_t)(T + 1) * 64, kB = (size_t)(T + 2) * 64;

        bf16x8 bfr[2][2], af[2][2];

        // ---- phase 0: B frags + A mi0,1; stage A(T+1) ----
        #pragma unroll
        for (int nj = 0; nj < 2; ++nj)
            #pragma unroll
            for (int kk = 0; kk < 2; ++kk) {
                int lin = (wn * 32 + nj * 16 + fr) * 128 + kk * 64 + fq * 16;
                bfr[nj][kk] = *(const bf16x8*)(Bb + swz(lin));
            }
        #pragma unroll
        for (int ms = 0; ms < 2; ++ms)
            #pragma unroll
            for (int kk = 0; kk < 2; ++kk) {
                int lin = (wm * 64 + ms * 16 + fr) * 128 + kk * 64 + fq * 16;
                af[ms][kk] = *(const bf16x8*)(Ab + swz(lin));
            }
        if (stA) {
            gload16(Asrc + o0 + kA, Anx + wb);
            gload16(Asrc + o1 + kA, Anx + 8192 + wb);
        }
        __builtin_amdgcn_s_barrier();
        asm volatile("s_waitcnt lgkmcnt(0)" ::: "memory");
        __builtin_amdgcn_sched_barrier(0);
        __builtin_amdgcn_s_setprio(1);
        #pragma unroll
        for (int ms = 0; ms < 2; ++ms)
            #pragma unroll
            for (int nj = 0; nj < 2; ++nj)
                #pragma unroll
                for (int kk = 0; kk < 2; ++kk)
                    acc[ms][nj] = __builtin_amdgcn_mfma_f32_16x16x32_bf16(
                        af[ms][kk], bfr[nj][kk], acc[ms][nj], 0, 0, 0);
        __builtin_amdgcn_s_setprio(0);
        __builtin_amdgcn_s_barrier();

        // ---- phase 1: A mi2,3; stage B(T+2); boundary vmcnt ----
        #pragma unroll
        for (int ms = 0; ms < 2; ++ms)
            #pragma unroll
            for (int kk = 0; kk < 2; ++kk) {
                int lin = (wm * 64 + (2 + ms) * 16 + fr) * 128 + kk * 64 + fq * 16;
                af[ms][kk] = *(const bf16x8*)(Ab + swz(lin));
            }
        if (stB) {
            gload16(Bsrc + o0 + kB, Bnx + wb);
            gload16(Bsrc + o1 + kB, Bnx + 8192 + wb);
        }
        __builtin_amdgcn_s_barrier();
        asm volatile("s_waitcnt lgkmcnt(0)" ::: "memory");
        __builtin_amdgcn_sched_barrier(0);
        __builtin_amdgcn_s_setprio(1);
        #pragma unroll
        for (int ms = 0; ms < 2; ++ms)
            #pragma unroll
            for (int nj = 0; nj < 2; ++nj)
                #pragma unroll
                for (int kk = 0; kk < 2; ++kk)
                    acc[2 + ms][nj] = __builtin_amdgcn_mfma_f32_16x16x32_bf16(
                        af[ms][kk], bfr[nj][kk], acc[2 + ms][nj], 0, 0, 0);
        __builtin_amdgcn_s_setprio(0);
        if (stB)      asm volatile("s_waitcnt vmcnt(2)" ::: "memory");
        else if (stA) asm volatile("s_waitcnt vmcnt(0)" ::: "memory");
        __builtin_amdgcn_s_barrier();
        __builtin_amdgcn_sched_barrier(0);
    }

    float* op = outf;
    if (SPLITK) op = outf + (size_t)blockIdx.z * M * N;

    #pragma unroll
    for (int mi = 0; mi < 4; ++mi) {
        #pragma unroll
        for (int nj = 0; nj < 2; ++nj) {
            #pragma unroll
            for (int r = 0; r < 4; ++r) {
                int row = m0 + wm * 64 + mi * 16 + fq * 4 + r;
                int col = n0 + wn * 32 + nj * 16 + fr;
                float v = acc[mi][nj][r];
                if (BIAS) v += bias[col];
                if (GELU_) v = 0.5f * v * (1.0f + erff(v * 0.70710678118f));
                if (OUTBF) outb[(size_t)row * N + col] = f2bf(v);
                else       op[(size_t)row * N + col] = v;
            }
        }
    }
}

// ---------------- 2-phase double-buffered GEMM (kept for proj: RES epilogue, small N) ----------------
template<int BM, int BN, int BIAS, int GELU_, int RES, int OUTBF, int SPLITK>
__global__ void gemm_db(const u16* __restrict__ A, const u16* __restrict__ Bw,
                        const float* __restrict__ bias, const float* __restrict__ res,
                        float* __restrict__ outf, u16* __restrict__ outb,
                        int M, int N, int K) {
    constexpr int MR = BM / 32;
    constexpr int NR = BN / 32;
    constexpr int AL = BM / 64;
    constexpr int BL = BN / 64;
    __shared__ u16 lA[2][BM * 32];
    __shared__ u16 lB[2][BN * 32];
    const int t = threadIdx.x;
    const int w = t >> 6, l = t & 63;

    int bid = blockIdx.y * gridDim.x + blockIdx.x;
    int swzb = xcd_swz(bid, gridDim.x * gridDim.y);
    const int m0 = (swzb % gridDim.x) * BM;
    const int n0 = (swzb / gridDim.x) * BN;

    int kbase = 0, Keff = K;
    if (SPLITK) { Keff = K >> 1; kbase = blockIdx.z * Keff; }
    const int nt = Keff >> 5;

    const int wr = (w >> 1) * (BM / 2), wc = (w & 1) * (BN / 2);
    const int fr = l & 15, fq = l >> 4;
    const int g0 = w * 64 + l;

    const int srow = g0 >> 2, scol = (g0 & 3) * 8;

    f32x4 acc[MR][NR] = {};

    #pragma unroll
    for (int i = 0; i < AL; ++i)
        gload16(A + (size_t)(m0 + srow + i * 64) * K + kbase + scol, lA[0] + (srow + i * 64) * 32 + scol);
    #pragma unroll
    for (int i = 0; i < BL; ++i)
        gload16(Bw + (size_t)(n0 + srow + i * 64) * K + kbase + scol, lB[0] + (srow + i * 64) * 32 + scol);
    __syncthreads();

    for (int T = 0; T < nt; ++T) {
        const int cur = T & 1, nxt = cur ^ 1;
        if (T + 1 < nt) {
            const int kk = kbase + (T + 1) * 32;
            #pragma unroll
            for (int i = 0; i < AL; ++i)
                gload16(A + (size_t)(m0 + srow + i * 64) * K + kk + scol, lA[nxt] + (srow + i * 64) * 32 + scol);
            #pragma unroll
            for (int i = 0; i < BL; ++i)
                gload16(Bw + (size_t)(n0 + srow + i * 64) * K + kk + scol, lB[nxt] + (srow + i * 64) * 32 + scol);
        }
        bf16x8 af[MR], bfv[NR];
        #pragma unroll
        for (int mi = 0; mi < MR; ++mi)
            af[mi] = *(const bf16x8*)(lA[cur] + (wr + mi * 16 + fr) * 32 + fq * 8);
        #pragma unroll
        for (int ni = 0; ni < NR; ++ni)
            bfv[ni] = *(const bf16x8*)(lB[cur] + (wc + ni * 16 + fr) * 32 + fq * 8);
        #pragma unroll
        for (int mi = 0; mi < MR; ++mi)
            #pragma unroll
            for (int ni = 0; ni < NR; ++ni)
                acc[mi][ni] = __builtin_amdgcn_mfma_f32_16x16x32_bf16(af[mi], bfv[ni], acc[mi][ni], 0, 0, 0);
        __syncthreads();
    }

    float* op = outf;
    if (SPLITK) op = outf + (size_t)blockIdx.z * M * N;

    #pragma unroll
    for (int mi = 0; mi < MR; ++mi) {
        #pragma unroll
        for (int ni = 0; ni < NR; ++ni) {
            #pragma unroll
            for (int r = 0; r < 4; ++r) {
                int row = m0 + wr + mi * 16 + fq * 4 + r;
                int col = n0 + wc + ni * 16 + fr;
                float v = acc[mi][ni][r];
                if (BIAS) v += bias[col];
                if (GELU_) v = 0.5f * v * (1.0f + erff(v * 0.70710678118f));
                if (RES) v += res[(size_t)row * N + col];
                if (OUTBF) outb[(size_t)row * N + col] = f2bf(v);
                else       op[(size_t)row * N + col] = v;
            }
        }
    }
}

// ---------------- Flash attention: QBLK=128, 8 waves, swizzled LDS, XCD-chunked ----------------
__global__ __launch_bounds__(512, 2)
void attn_k(const u16* __restrict__ qkv, u16* __restrict__ o) {
    __shared__ u16 lK[64 * 64];        // 8 KB
    __shared__ u16 lV[64 * 64];        // 8 KB, transposed [d][kv], swizzled
    __shared__ u16 lP[8 * 16 * 64];    // 16 KB, per-wave
    const int t = threadIdx.x;
    const int w = t >> 6, l = t & 63;
    const int fr = l & 15, fq = l >> 4;

    // grid 256 = 8 qb x 16 h x 2 b, XCD-chunked; qb descending (long first)
    int swzb = xcd_swz(blockIdx.x, gridDim.x);
    const int qb = 7 - (swzb & 7);
    const int hh = (swzb >> 3) & 15;
    const int b  = swzb >> 7;
    const int q0 = qb * 128;
    const int qw = q0 + w * 16;        // this wave's first q-row

    // K staging: pre-swizzled per-lane global source, linear LDS dest (1 load/thread)
    const u16* srcK;
    {
        int p = t * 16;
        int L = swz(p);
        srcK = qkv + ((size_t)(b * 1024) + (L >> 7)) * 3072 + 1024 + hh * 64 + ((L & 127) >> 1);
    }

    bf16x8 qf[2];
    {
        size_t base = ((size_t)(b * 1024) + qw + fr) * 3072 + hh * 64;
        qf[0] = *(const bf16x8*)(qkv + base + fq * 8);
        qf[1] = *(const bf16x8*)(qkv + base + 32 + fq * 8);
    }

    float m_run[4], l_run[4];
    f32x4 acc_o[4] = {};
    #pragma unroll
    for (int r = 0; r < 4; ++r) { m_run[r] = -__builtin_inff(); l_run[r] = 0.0f; }

    for (int kv0 = 0; kv0 < q0 + 128; kv0 += 64) {
        // stage K (all threads)
        gload16(srcK + (size_t)kv0 * 3072, (char*)lK + w * 1024);
        // stage V transposed (all threads, 1 row-slice each)
        {
            int kv = t >> 3, d0 = (t & 7) * 8;
            const u32* gv = (const u32*)(qkv + ((size_t)(b * 1024) + kv0 + kv) * 3072 + 2048 + hh * 64 + d0);
            u32 v0 = gv[0], v1 = gv[1], v2 = gv[2], v3 = gv[3];
            u16 e[8] = { (u16)v0, (u16)(v0 >> 16), (u16)v1, (u16)(v1 >> 16),
                         (u16)v2, (u16)(v2 >> 16), (u16)v3, (u16)(v3 >> 16) };
            #pragma unroll
            for (int j = 0; j < 8; ++j) {
                int pv = ((d0 + j) * 64 + kv) * 2;
                *(u16*)((char*)lV + swz(pv)) = e[j];
            }
        }
        __syncthreads();

        const bool active = (kv0 <= qw + 15);   // wave-uniform
        if (active) {
            f32x4 accs[4] = {};
            #pragma unroll
            for (int nt = 0; nt < 4; ++nt) {
                #pragma unroll
                for (int ks = 0; ks < 2; ++ks) {
                    int pk = ((nt * 16 + fr) * 64 + ks * 32 + fq * 8) * 2;
                    bf16x8 kf = *(const bf16x8*)((const char*)lK + swz(pk));
                    accs[nt] = __builtin_amdgcn_mfma_f32_16x16x32_bf16(qf[ks], kf, accs[nt], 0, 0, 0);
                }
            }

            float p[4][4], mx[4], rs[4];
            #pragma unroll
            for (int r = 0; r < 4; ++r) {
                int qg = qw + fq * 4 + r;
                float m = -__builtin_inff();
                #pragma unroll
                for (int nt = 0; nt < 4; ++nt) {
                    int kvg = kv0 + nt * 16 + fr;
                    float s = (kvg <= qg) ? accs[nt][r] * 0.125f : -__builtin_inff();
                    p[nt][r] = s;
                    m = fmaxf(m, s);
                }
                mx[r] = m;
            }
            #pragma unroll
            for (int msk = 1; msk < 16; msk <<= 1) {
                #pragma unroll
                for (int r = 0; r < 4; ++r) mx[r] = fmaxf(mx[r], __shfl_xor(mx[r], msk));
            }
            float mnew[4], alpha[4];
            #pragma unroll
            for (int r = 0; r < 4; ++r) {
                mnew[r] = fmaxf(m_run[r], mx[r]);
                alpha[r] = __expf(m_run[r] - mnew[r]);
                float s = 0.0f;
                #pragma unroll
                for (int nt = 0; nt < 4; ++nt) {
                    float pv = __expf(p[nt][r] - mnew[r]);
                    p[nt][r] = pv;
                    s += pv;
                }
                rs[r] = s;
            }
            #pragma unroll
            for (int msk = 1; msk < 16; msk <<= 1) {
                #pragma unroll
                for (int r = 0; r < 4; ++r) rs[r] += __shfl_xor(rs[r], msk);
            }
            #pragma unroll
            for (int r = 0; r < 4; ++r) {
                l_run[r] = l_run[r] * alpha[r] + rs[r];
                m_run[r] = mnew[r];
            }
            #pragma unroll
            for (int nt = 0; nt < 4; ++nt)
                #pragma unroll
                for (int r = 0; r < 4; ++r) acc_o[nt][r] *= alpha[r];

            #pragma unroll
            for (int nt = 0; nt < 4; ++nt)
                #pragma unroll
                for (int r = 0; r < 4; ++r) {
                    int pp = (w * 1024 + (fq * 4 + r) * 64 + nt * 16 + fr) * 2;
                    *(u16*)((char*)lP + swz(pp)) = f2bf(p[nt][r]);
                }

            bf16x8 pa[2];
            #pragma unroll
            for (int ks = 0; ks < 2; ++ks) {
                int ppr = (w * 1024 + fr * 64 + ks * 32 + fq * 8) * 2;
                pa[ks] = *(const bf16x8*)((const char*)lP + swz(ppr));
            }
            #pragma unroll
            for (int nt = 0; nt < 4; ++nt) {
                #pragma unroll
                for (int ks = 0; ks < 2; ++ks) {
                    int pvr = ((nt * 16 + fr) * 64 + ks * 32 + fq * 8) * 2;
                    bf16x8 vf = *(const bf16x8*)((const char*)lV + swz(pvr));
                    acc_o[nt] = __builtin_amdgcn_mfma_f32_16x16x32_bf16(pa[ks], vf, acc_o[nt], 0, 0, 0);
                }
            }
        }
        __syncthreads();
    }

    #pragma unroll
    for (int nt = 0; nt < 4; ++nt) {
        #pragma unroll
        for (int r = 0; r < 4; ++r) {
            int qg = qw + fq * 4 + r;
            int d = nt * 16 + fr;
            float ov = acc_o[nt][r] / l_run[r];
            o[((size_t)(b * 1024) + qg) * 1024 + hh * 64 + d] = f2bf(ov);
        }
    }
}

// ---------------- launch ----------------
extern "C" void kernel_launch(void* const* d_in, const int* in_sizes, int n_in,
                              void* d_out, int out_size, void* d_ws, size_t ws_size,
                              hipStream_t stream) {
    const int*   x       = (const int*)  d_in[0];
    const float* tok_emb = (const float*)d_in[1];
    const float* pos_emb = (const float*)d_in[2];
    const float* ln1_g   = (const float*)d_in[3];
    const float* ln1_b   = (const float*)d_in[4];
    const float* qkv_w   = (const float*)d_in[5];
    const float* qkv_b   = (const float*)d_in[6];
    const float* proj_w  = (const float*)d_in[7];
    const float* proj_b  = (const float*)d_in[8];
    const float* ln2_g   = (const float*)d_in[9];
    const float* ln2_b   = (const float*)d_in[10];
    const float* fc1_w   = (const float*)d_in[11];
    const float* fc1_b   = (const float*)d_in[12];
    const float* fc2_w   = (const float*)d_in[13];
    const float* fc2_b   = (const float*)d_in[14];
    const float* lnf_g   = (const float*)d_in[15];
    const float* lnf_b   = (const float*)d_in[16];
    const float* head_w  = (const float*)d_in[17];
    float* out = (float*)d_out;

    char* ws = (char*)d_ws;
    float* h   = (float*)(ws + 0);            //  8 MB f32 (2048x1024)
    u16*   xn  = (u16*)(ws + 8388608);        //  4 MB bf16
    u16*   qkv = (u16*)(ws + 12582912);       // 12.6 MB bf16 (2048x3072)
    u16*   ob  = (u16*)(ws + 25165824);       //  4 MB bf16
    u16*   ff  = (u16*)(ws + 29360128);       // 16.8 MB bf16 (2048x4096)
    u16*   wq  = (u16*)(ws + 46137344);       // 65.5 MB bf16 weight slab
    float* pbuf = (float*)(ws + 12582912);    // fc2 split-K partials (16 MB f32, dead region)

    u16* wqkv = wq;
    u16* wproj = wqkv + 3072 * 1024;
    u16* wfc1  = wproj + 1024 * 1024;
    u16* wfc2  = wfc1 + 4096 * 1024;

    const int M = 2048;

    embed_k<<<dim3(2048), 256, 0, stream>>>(x, tok_emb, pos_emb, h);

    for (int lyr = 0; lyr < 6; ++lyr) {
        cvt4_k<<<dim3(2048), 256, 0, stream>>>(
            qkv_w + (size_t)lyr * 3072 * 1024, proj_w + (size_t)lyr * 1024 * 1024,
            fc1_w + (size_t)lyr * 4096 * 1024, fc2_w + (size_t)lyr * 1024 * 4096,
            wq, 3072 * 256, 1024 * 256, 4096 * 256, 4096 * 256);
        ln_k<<<dim3(2048), 256, 0, stream>>>(h, ln1_g + lyr * 1024, ln1_b + lyr * 1024, xn);
        gemm4p<1, 0, 1, 0><<<dim3(16, 24), 512, 0, stream>>>(
            xn, wqkv, qkv_b + lyr * 3072, nullptr, qkv, M, 3072, 1024);
        attn_k<<<dim3(256), 512, 0, stream>>>(qkv, ob);
        gemm_db<64, 64, 1, 0, 1, 0, 0><<<dim3(32, 16), 256, 0, stream>>>(
            ob, wproj, proj_b + lyr * 1024, h, h, nullptr, M, 1024, 1024);
        ln_k<<<dim3(2048), 256, 0, stream>>>(h, ln2_g + lyr * 1024, ln2_b + lyr * 1024, xn);
        gemm4p<1, 1, 1, 0><<<dim3(16, 32), 512, 0, stream>>>(
            xn, wfc1, fc1_b + lyr * 4096, nullptr, ff, M, 4096, 1024);
        gemm4p<0, 0, 0, 1><<<dim3(16, 8, 2), 512, 0, stream>>>(
            ff, wfc2, nullptr, pbuf, nullptr, M, 1024, 4096);
        fuse2_k<<<dim3(2048), 256, 0, stream>>>(
            pbuf, pbuf + (size_t)M * 1024, fc2_b + lyr * 1024, h);
    }

    ln_k<<<dim3(2048), 256, 0, stream>>>(h, lnf_g, lnf_b, xn);
    cvt_k<<<dim3(2048), 256, 0, stream>>>(head_w, wq, 32000 * 1024 / 4);
    gemm8p<0, 0><<<dim3(8, 125), 512, 0, stream>>>(
        xn, wq, nullptr, out, nullptr, M, 32000, 1024);
}

// Round 9
// 1247.858 us; speedup vs baseline: 1.4263x; 1.0066x over previous
//
#include <hip/hip_runtime.h>

typedef unsigned short u16;
typedef unsigned int   u32;
typedef __bf16 bf16x8 __attribute__((ext_vector_type(8)));
typedef float  f32x4  __attribute__((ext_vector_type(4)));

#define DEV __device__ __forceinline__

DEV u16 f2bf(float f) {
    u32 u = __builtin_bit_cast(u32, f);
    u32 r = u + 0x7FFFu + ((u >> 16) & 1u);
    return (u16)(r >> 16);
}

DEV void gload16(const void* g, void* l) {
    __builtin_amdgcn_global_load_lds((const __attribute__((address_space(1))) void*)g,
                                     (__attribute__((address_space(3))) void*)l, 16, 0, 0);
}

// bijective XCD-aware swizzle (m204)
DEV int xcd_swz(int bid, int nwg) {
    int q = nwg >> 3, r = nwg & 7;
    int xcd = bid & 7, idx = bid >> 3;
    return (xcd < r ? xcd * (q + 1) : r * (q + 1) + (xcd - r) * q) + idx;
}

// involutive LDS byte swizzle for 128B rows: XOR byte bits[6:4] with row bits [0,2,1]
DEV int swz(int p) {
    int m = (((p >> 7) & 1) << 6) | (((p >> 9) & 1) << 5) | (((p >> 8) & 1) << 4);
    return p ^ m;
}

// ---------------- convert f32 -> bf16 (single tensor) ----------------
__global__ void cvt_k(const float* __restrict__ src, u16* __restrict__ dst, int n4) {
    int i = blockIdx.x * blockDim.x + threadIdx.x;
    int stride = gridDim.x * blockDim.x;
    for (; i < n4; i += stride) {
        float4 v = ((const float4*)src)[i];
        ushort4 u;
        u.x = f2bf(v.x); u.y = f2bf(v.y); u.z = f2bf(v.z); u.w = f2bf(v.w);
        ((ushort4*)dst)[i] = u;
    }
}

// ---------------- convert 4 tensors in one launch (per-layer weights) ----------------
__global__ void cvt4_k(const float* __restrict__ s0, const float* __restrict__ s1,
                       const float* __restrict__ s2, const float* __restrict__ s3,
                       u16* __restrict__ dst, int n0, int n1, int n2, int n3) {
    int i = blockIdx.x * blockDim.x + threadIdx.x;
    int stride = gridDim.x * blockDim.x;
    int t0 = n0, t1 = t0 + n1, t2 = t1 + n2, t3 = t2 + n3;
    for (; i < t3; i += stride) {
        const float* s; int j;
        if (i < t0)      { s = s0; j = i; }
        else if (i < t1) { s = s1; j = i - t0; }
        else if (i < t2) { s = s2; j = i - t1; }
        else             { s = s3; j = i - t2; }
        float4 v = ((const float4*)s)[j];
        ushort4 u;
        u.x = f2bf(v.x); u.y = f2bf(v.y); u.z = f2bf(v.z); u.w = f2bf(v.w);
        ((ushort4*)dst)[i] = u;
    }
}

// ---------------- LN core (one block per row, 256 threads x float4) ----------------
DEV void ln_store(float4 v, const float* __restrict__ g, const float* __restrict__ b,
                  u16* __restrict__ out, int row, int t) {
    float s = v.x + v.y + v.z + v.w;
    float s2 = v.x * v.x + v.y * v.y + v.z * v.z + v.w * v.w;
    #pragma unroll
    for (int msk = 1; msk < 64; msk <<= 1) {
        s  += __shfl_xor(s, msk);
        s2 += __shfl_xor(s2, msk);
    }
    __shared__ float ps[4], ps2[4];
    if ((t & 63) == 0) { ps[t >> 6] = s; ps2[t >> 6] = s2; }
    __syncthreads();
    s = ps[0] + ps[1] + ps[2] + ps[3];
    s2 = ps2[0] + ps2[1] + ps2[2] + ps2[3];
    float mu = s * (1.0f / 1024.0f);
    float var = s2 * (1.0f / 1024.0f) - mu * mu;
    float rstd = rsqrtf(var + 1e-5f);
    float4 gg = ((const float4*)g)[t];
    float4 bb = ((const float4*)b)[t];
    ushort4 o;
    o.x = f2bf((v.x - mu) * rstd * gg.x + bb.x);
    o.y = f2bf((v.y - mu) * rstd * gg.y + bb.y);
    o.z = f2bf((v.z - mu) * rstd * gg.z + bb.z);
    o.w = f2bf((v.w - mu) * rstd * gg.w + bb.w);
    ((ushort4*)out)[(size_t)row * 256 + t] = o;
}

// ---------------- LayerNorm: f32 in -> bf16 out ----------------
__global__ void ln_k(const float* __restrict__ in, const float* __restrict__ g,
                     const float* __restrict__ b, u16* __restrict__ out) {
    int row = blockIdx.x;
    int t = threadIdx.x;
    float4 v = ((const float4*)(in + (size_t)row * 1024))[t];
    ln_store(v, g, b, out, row, t);
}

// ---------------- embedding + first LN ----------------
__global__ void embed_ln_k(const int* __restrict__ x, const float* __restrict__ te,
                           const float* __restrict__ pe, float* __restrict__ h,
                           const float* __restrict__ g, const float* __restrict__ b,
                           u16* __restrict__ xn) {
    int row = blockIdx.x;
    int t = threadIdx.x;
    int tok = x[row];
    int s = row & 1023;
    float4 a = ((const float4*)(te + (size_t)tok * 1024))[t];
    float4 p = ((const float4*)(pe + (size_t)s * 1024))[t];
    a.x += p.x; a.y += p.y; a.z += p.z; a.w += p.w;
    ((float4*)(h + (size_t)row * 1024))[t] = a;
    ln_store(a, g, b, xn, row, t);
}

// ---------------- fc2 fuse + next LN: h += p0+p1+bias; xn = LN(h) ----------------
__global__ void fuse2ln_k(const float* __restrict__ p0, const float* __restrict__ p1,
                          const float* __restrict__ bias, float* __restrict__ h,
                          const float* __restrict__ g, const float* __restrict__ b,
                          u16* __restrict__ xn) {
    int row = blockIdx.x;
    int t = threadIdx.x;
    size_t idx = (size_t)row * 256 + t;
    float4 a = ((const float4*)p0)[idx];
    float4 bb = ((const float4*)p1)[idx];
    float4 c = ((const float4*)bias)[t];
    float4 v = ((const float4*)h)[idx];
    v.x += a.x + bb.x + c.x;
    v.y += a.y + bb.y + c.y;
    v.z += a.z + bb.z + c.z;
    v.w += a.w + bb.w + c.w;
    ((float4*)h)[idx] = v;
    ln_store(v, g, b, xn, row, t);
}

// ============ 128x128 8-wave 2-phase-per-K-tile GEMM (BK=64, counted vmcnt(2)) ============
template<int BIAS, int GELU_, int OUTBF, int SPLITK>
__global__ __launch_bounds__(512, 2)
void gemm4p(const u16* __restrict__ A, const u16* __restrict__ Bw,
            const float* __restrict__ bias,
            float* __restrict__ outf, u16* __restrict__ outb,
            int M, int N, int K) {
    __shared__ char lds[65536];
    char* ldsA = lds;            // 2 x 16384
    char* ldsB = lds + 32768;    // 2 x 16384
    const int t = threadIdx.x;
    const int w = t >> 6, l = t & 63;
    const int fr = l & 15, fq = l >> 4;
    const int wm = w >> 2, wn = w & 3;     // 2 x 4 waves -> 64x32 out each

    int bid = blockIdx.y * gridDim.x + blockIdx.x;
    int swzb = xcd_swz(bid, gridDim.x * gridDim.y);
    const int m0 = (swzb % gridDim.x) * 128;
    const int n0 = (swzb / gridDim.x) * 128;

    int kbase = 0, Keff = K;
    if (SPLITK) { Keff = K >> 1; kbase = blockIdx.z * Keff; }
    const int nt = Keff >> 6;

    const u16* Asrc = A + (size_t)m0 * K + kbase;
    const u16* Bsrc = Bw + (size_t)n0 * K + kbase;

    size_t o0, o1;
    {
        int p = t * 16;        o0 = (size_t)(p >> 7) * K + ((swz(p) & 127) >> 1);
        p = 8192 + t * 16;     o1 = (size_t)(p >> 7) * K + ((swz(p) & 127) >> 1);
    }
    const int wb = w * 1024;

    // prologue: A(0), B(0), B(1)  (6 loads; oldest 4 = A0+B0 -> vmcnt(2))
    gload16(Asrc + o0, ldsA + wb);
    gload16(Asrc + o1, ldsA + 8192 + wb);
    gload16(Bsrc + o0, ldsB + wb);
    gload16(Bsrc + o1, ldsB + 8192 + wb);
    gload16(Bsrc + o0 + 64, ldsB + 16384 + wb);
    gload16(Bsrc + o1 + 64, ldsB + 16384 + 8192 + wb);
    asm volatile("s_waitcnt vmcnt(2)" ::: "memory");
    __builtin_amdgcn_s_barrier();
    __builtin_amdgcn_sched_barrier(0);

    f32x4 acc[4][2] = {};

    for (int T = 0; T < nt; ++T) {
        const char* Ab = ldsA + (T & 1) * 16384;
        const char* Bb = ldsB + (T & 1) * 16384;
        char* Anx = ldsA + ((T + 1) & 1) * 16384;
        char* Bnx = ldsB + (T & 1) * 16384;            // B(T+2) parity == T parity
        const bool stA = (T + 1 < nt), stB = (T + 2 < nt);
        const size_t kA = (size_t)(T + 1) * 64, kB = (size_t)(T + 2) * 64;

        bf16x8 bfr[2][2], af[2][2];

        // ---- phase 0: B frags + A mi0,1; stage A(T+1) ----
        #pragma unroll
        for (int nj = 0; nj < 2; ++nj)
            #pragma unroll
            for (int kk = 0; kk < 2; ++kk) {
                int lin = (wn * 32 + nj * 16 + fr) * 128 + kk * 64 + fq * 16;
                bfr[nj][kk] = *(const bf16x8*)(Bb + swz(lin));
            }
        #pragma unroll
        for (int ms = 0; ms < 2; ++ms)
            #pragma unroll
            for (int kk = 0; kk < 2; ++kk) {
                int lin = (wm * 64 + ms * 16 + fr) * 128 + kk * 64 + fq * 16;
                af[ms][kk] = *(const bf16x8*)(Ab + swz(lin));
            }
        if (stA) {
            gload16(Asrc + o0 + kA, Anx + wb);
            gload16(Asrc + o1 + kA, Anx + 8192 + wb);
        }
        __builtin_amdgcn_s_barrier();
        asm volatile("s_waitcnt lgkmcnt(0)" ::: "memory");
        __builtin_amdgcn_sched_barrier(0);
        __builtin_amdgcn_s_setprio(1);
        #pragma unroll
        for (int ms = 0; ms < 2; ++ms)
            #pragma unroll
            for (int nj = 0; nj < 2; ++nj)
                #pragma unroll
                for (int kk = 0; kk < 2; ++kk)
                    acc[ms][nj] = __builtin_amdgcn_mfma_f32_16x16x32_bf16(
                        af[ms][kk], bfr[nj][kk], acc[ms][nj], 0, 0, 0);
        __builtin_amdgcn_s_setprio(0);
        __builtin_amdgcn_s_barrier();

        // ---- phase 1: A mi2,3; stage B(T+2); boundary vmcnt ----
        #pragma unroll
        for (int ms = 0; ms < 2; ++ms)
            #pragma unroll
            for (int kk = 0; kk < 2; ++kk) {
                int lin = (wm * 64 + (2 + ms) * 16 + fr) * 128 + kk * 64 + fq * 16;
                af[ms][kk] = *(const bf16x8*)(Ab + swz(lin));
            }
        if (stB) {
            gload16(Bsrc + o0 + kB, Bnx + wb);
            gload16(Bsrc + o1 + kB, Bnx + 8192 + wb);
        }
        __builtin_amdgcn_s_barrier();
        asm volatile("s_waitcnt lgkmcnt(0)" ::: "memory");
        __builtin_amdgcn_sched_barrier(0);
        __builtin_amdgcn_s_setprio(1);
        #pragma unroll
        for (int ms = 0; ms < 2; ++ms)
            #pragma unroll
            for (int nj = 0; nj < 2; ++nj)
                #pragma unroll
                for (int kk = 0; kk < 2; ++kk)
                    acc[2 + ms][nj] = __builtin_amdgcn_mfma_f32_16x16x32_bf16(
                        af[ms][kk], bfr[nj][kk], acc[2 + ms][nj], 0, 0, 0);
        __builtin_amdgcn_s_setprio(0);
        if (stB)      asm volatile("s_waitcnt vmcnt(2)" ::: "memory");
        else if (stA) asm volatile("s_waitcnt vmcnt(0)" ::: "memory");
        __builtin_amdgcn_s_barrier();
        __builtin_amdgcn_sched_barrier(0);
    }

    float* op = outf;
    if (SPLITK) op = outf + (size_t)blockIdx.z * M * N;

    #pragma unroll
    for (int mi = 0; mi < 4; ++mi) {
        #pragma unroll
        for (int nj = 0; nj < 2; ++nj) {
            #pragma unroll
            for (int r = 0; r < 4; ++r) {
                int row = m0 + wm * 64 + mi * 16 + fq * 4 + r;
                int col = n0 + wn * 32 + nj * 16 + fr;
                float v = acc[mi][nj][r];
                if (BIAS) v += bias[col];
                if (GELU_) v = 0.5f * v * (1.0f + erff(v * 0.70710678118f));
                if (OUTBF) outb[(size_t)row * N + col] = f2bf(v);
                else       op[(size_t)row * N + col] = v;
            }
        }
    }
}

// ---------------- 2-phase double-buffered GEMM (proj: RES epilogue, small N) ----------------
template<int BM, int BN, int BIAS, int GELU_, int RES, int OUTBF, int SPLITK>
__global__ void gemm_db(const u16* __restrict__ A, const u16* __restrict__ Bw,
                        const float* __restrict__ bias, const float* __restrict__ res,
                        float* __restrict__ outf, u16* __restrict__ outb,
                        int M, int N, int K) {
    constexpr int MR = BM / 32;
    constexpr int NR = BN / 32;
    constexpr int AL = BM / 64;
    constexpr int BL = BN / 64;
    __shared__ u16 lA[2][BM * 32];
    __shared__ u16 lB[2][BN * 32];
    const int t = threadIdx.x;
    const int w = t >> 6, l = t & 63;

    int bid = blockIdx.y * gridDim.x + blockIdx.x;
    int swzb = xcd_swz(bid, gridDim.x * gridDim.y);
    const int m0 = (swzb % gridDim.x) * BM;
    const int n0 = (swzb / gridDim.x) * BN;

    int kbase = 0, Keff = K;
    if (SPLITK) { Keff = K >> 1; kbase = blockIdx.z * Keff; }
    const int nt = Keff >> 5;

    const int wr = (w >> 1) * (BM / 2), wc = (w & 1) * (BN / 2);
    const int fr = l & 15, fq = l >> 4;
    const int g0 = w * 64 + l;

    const int srow = g0 >> 2, scol = (g0 & 3) * 8;

    f32x4 acc[MR][NR] = {};

    #pragma unroll
    for (int i = 0; i < AL; ++i)
        gload16(A + (size_t)(m0 + srow + i * 64) * K + kbase + scol, lA[0] + (srow + i * 64) * 32 + scol);
    #pragma unroll
    for (int i = 0; i < BL; ++i)
        gload16(Bw + (size_t)(n0 + srow + i * 64) * K + kbase + scol, lB[0] + (srow + i * 64) * 32 + scol);
    __syncthreads();

    for (int T = 0; T < nt; ++T) {
        const int cur = T & 1, nxt = cur ^ 1;
        if (T + 1 < nt) {
            const int kk = kbase + (T + 1) * 32;
            #pragma unroll
            for (int i = 0; i < AL; ++i)
                gload16(A + (size_t)(m0 + srow + i * 64) * K + kk + scol, lA[nxt] + (srow + i * 64) * 32 + scol);
            #pragma unroll
            for (int i = 0; i < BL; ++i)
                gload16(Bw + (size_t)(n0 + srow + i * 64) * K + kk + scol, lB[nxt] + (srow + i * 64) * 32 + scol);
        }
        bf16x8 af[MR], bfv[NR];
        #pragma unroll
        for (int mi = 0; mi < MR; ++mi)
            af[mi] = *(const bf16x8*)(lA[cur] + (wr + mi * 16 + fr) * 32 + fq * 8);
        #pragma unroll
        for (int ni = 0; ni < NR; ++ni)
            bfv[ni] = *(const bf16x8*)(lB[cur] + (wc + ni * 16 + fr) * 32 + fq * 8);
        #pragma unroll
        for (int mi = 0; mi < MR; ++mi)
            #pragma unroll
            for (int ni = 0; ni < NR; ++ni)
                acc[mi][ni] = __builtin_amdgcn_mfma_f32_16x16x32_bf16(af[mi], bfv[ni], acc[mi][ni], 0, 0, 0);
        __syncthreads();
    }

    float* op = outf;
    if (SPLITK) op = outf + (size_t)blockIdx.z * M * N;

    #pragma unroll
    for (int mi = 0; mi < MR; ++mi) {
        #pragma unroll
        for (int ni = 0; ni < NR; ++ni) {
            #pragma unroll
            for (int r = 0; r < 4; ++r) {
                int row = m0 + wr + mi * 16 + fq * 4 + r;
                int col = n0 + wc + ni * 16 + fr;
                float v = acc[mi][ni][r];
                if (BIAS) v += bias[col];
                if (GELU_) v = 0.5f * v * (1.0f + erff(v * 0.70710678118f));
                if (RES) v += res[(size_t)row * N + col];
                if (OUTBF) outb[(size_t)row * N + col] = f2bf(v);
                else       op[(size_t)row * N + col] = v;
            }
        }
    }
}

// ---------------- Flash attention: QBLK=128, 8 waves, swizzled LDS, XCD-chunked ----------------
__global__ __launch_bounds__(512, 2)
void attn_k(const u16* __restrict__ qkv, u16* __restrict__ o) {
    __shared__ u16 lK[64 * 64];        // 8 KB
    __shared__ u16 lV[64 * 64];        // 8 KB, transposed [d][kv], swizzled
    __shared__ u16 lP[8 * 16 * 64];    // 16 KB, per-wave
    const int t = threadIdx.x;
    const int w = t >> 6, l = t & 63;
    const int fr = l & 15, fq = l >> 4;

    // grid 256 = 8 qb x 16 h x 2 b, XCD-chunked; qb descending (long first)
    int swzb = xcd_swz(blockIdx.x, gridDim.x);
    const int qb = 7 - (swzb & 7);
    const int hh = (swzb >> 3) & 15;
    const int b  = swzb >> 7;
    const int q0 = qb * 128;
    const int qw = q0 + w * 16;        // this wave's first q-row

    const u16* srcK;
    {
        int p = t * 16;
        int L = swz(p);
        srcK = qkv + ((size_t)(b * 1024) + (L >> 7)) * 3072 + 1024 + hh * 64 + ((L & 127) >> 1);
    }

    bf16x8 qf[2];
    {
        size_t base = ((size_t)(b * 1024) + qw + fr) * 3072 + hh * 64;
        qf[0] = *(const bf16x8*)(qkv + base + fq * 8);
        qf[1] = *(const bf16x8*)(qkv + base + 32 + fq * 8);
    }

    float m_run[4], l_run[4];
    f32x4 acc_o[4] = {};
    #pragma unroll
    for (int r = 0; r < 4; ++r) { m_run[r] = -__builtin_inff(); l_run[r] = 0.0f; }

    for (int kv0 = 0; kv0 < q0 + 128; kv0 += 64) {
        gload16(srcK + (size_t)kv0 * 3072, (char*)lK + w * 1024);
        {
            int kv = t >> 3, d0 = (t & 7) * 8;
            const u32* gv = (const u32*)(qkv + ((size_t)(b * 1024) + kv0 + kv) * 3072 + 2048 + hh * 64 + d0);
            u32 v0 = gv[0], v1 = gv[1], v2 = gv[2], v3 = gv[3];
            u16 e[8] = { (u16)v0, (u16)(v0 >> 16), (u16)v1, (u16)(v1 >> 16),
                         (u16)v2, (u16)(v2 >> 16), (u16)v3, (u16)(v3 >> 16) };
            #pragma unroll
            for (int j = 0; j < 8; ++j) {
                int pv = ((d0 + j) * 64 + kv) * 2;
                *(u16*)((char*)lV + swz(pv)) = e[j];
            }
        }
        __syncthreads();

        const bool active = (kv0 <= qw + 15);   // wave-uniform
        if (active) {
            f32x4 accs[4] = {};
            #pragma unroll
            for (int nt = 0; nt < 4; ++nt) {
                #pragma unroll
                for (int ks = 0; ks < 2; ++ks) {
                    int pk = ((nt * 16 + fr) * 64 + ks * 32 + fq * 8) * 2;
                    bf16x8 kf = *(const bf16x8*)((const char*)lK + swz(pk));
                    accs[nt] = __builtin_amdgcn_mfma_f32_16x16x32_bf16(qf[ks], kf, accs[nt], 0, 0, 0);
                }
            }

            float p[4][4], mx[4], rs[4];
            #pragma unroll
            for (int r = 0; r < 4; ++r) {
                int qg = qw + fq * 4 + r;
                float m = -__builtin_inff();
                #pragma unroll
                for (int nt = 0; nt < 4; ++nt) {
                    int kvg = kv0 + nt * 16 + fr;
                    float s = (kvg <= qg) ? accs[nt][r] * 0.125f : -__builtin_inff();
                    p[nt][r] = s;
                    m = fmaxf(m, s);
                }
                mx[r] = m;
            }
            #pragma unroll
            for (int msk = 1; msk < 16; msk <<= 1) {
                #pragma unroll
                for (int r = 0; r < 4; ++r) mx[r] = fmaxf(mx[r], __shfl_xor(mx[r], msk));
            }
            float mnew[4], alpha[4];
            #pragma unroll
            for (int r = 0; r < 4; ++r) {
                mnew[r] = fmaxf(m_run[r], mx[r]);
                alpha[r] = __expf(m_run[r] - mnew[r]);
                float s = 0.0f;
                #pragma unroll
                for (int nt = 0; nt < 4; ++nt) {
                    float pv = __expf(p[nt][r] - mnew[r]);
                    p[nt][r] = pv;
                    s += pv;
                }
                rs[r] = s;
            }
            #pragma unroll
            for (int msk = 1; msk < 16; msk <<= 1) {
                #pragma unroll
                for (int r = 0; r < 4; ++r) rs[r] += __shfl_xor(rs[r], msk);
            }
            #pragma unroll
            for (int r = 0; r < 4; ++r) {
                l_run[r] = l_run[r] * alpha[r] + rs[r];
                m_run[r] = mnew[r];
            }
            #pragma unroll
            for (int nt = 0; nt < 4; ++nt)
                #pragma unroll
                for (int r = 0; r < 4; ++r) acc_o[nt][r] *= alpha[r];

            #pragma unroll
            for (int nt = 0; nt < 4; ++nt)
                #pragma unroll
                for (int r = 0; r < 4; ++r) {
                    int pp = (w * 1024 + (fq * 4 + r) * 64 + nt * 16 + fr) * 2;
                    *(u16*)((char*)lP + swz(pp)) = f2bf(p[nt][r]);
                }

            bf16x8 pa[2];
            #pragma unroll
            for (int ks = 0; ks < 2; ++ks) {
                int ppr = (w * 1024 + fr * 64 + ks * 32 + fq * 8) * 2;
                pa[ks] = *(const bf16x8*)((const char*)lP + swz(ppr));
            }
            #pragma unroll
            for (int nt = 0; nt < 4; ++nt) {
                #pragma unroll
                for (int ks = 0; ks < 2; ++ks) {
                    int pvr = ((nt * 16 + fr) * 64 + ks * 32 + fq * 8) * 2;
                    bf16x8 vf = *(const bf16x8*)((const char*)lV + swz(pvr));
                    acc_o[nt] = __builtin_amdgcn_mfma_f32_16x16x32_bf16(pa[ks], vf, acc_o[nt], 0, 0, 0);
                }
            }
        }
        __syncthreads();
    }

    #pragma unroll
    for (int nt = 0; nt < 4; ++nt) {
        #pragma unroll
        for (int r = 0; r < 4; ++r) {
            int qg = qw + fq * 4 + r;
            int d = nt * 16 + fr;
            float ov = acc_o[nt][r] / l_run[r];
            o[((size_t)(b * 1024) + qg) * 1024 + hh * 64 + d] = f2bf(ov);
        }
    }
}

// ---------------- launch ----------------
extern "C" void kernel_launch(void* const* d_in, const int* in_sizes, int n_in,
                              void* d_out, int out_size, void* d_ws, size_t ws_size,
                              hipStream_t stream) {
    const int*   x       = (const int*)  d_in[0];
    const float* tok_emb = (const float*)d_in[1];
    const float* pos_emb = (const float*)d_in[2];
    const float* ln1_g   = (const float*)d_in[3];
    const float* ln1_b   = (const float*)d_in[4];
    const float* qkv_w   = (const float*)d_in[5];
    const float* qkv_b   = (const float*)d_in[6];
    const float* proj_w  = (const float*)d_in[7];
    const float* proj_b  = (const float*)d_in[8];
    const float* ln2_g   = (const float*)d_in[9];
    const float* ln2_b   = (const float*)d_in[10];
    const float* fc1_w   = (const float*)d_in[11];
    const float* fc1_b   = (const float*)d_in[12];
    const float* fc2_w   = (const float*)d_in[13];
    const float* fc2_b   = (const float*)d_in[14];
    const float* lnf_g   = (const float*)d_in[15];
    const float* lnf_b   = (const float*)d_in[16];
    const float* head_w  = (const float*)d_in[17];
    float* out = (float*)d_out;

    char* ws = (char*)d_ws;
    float* h   = (float*)(ws + 0);            //  8 MB f32 (2048x1024)
    u16*   xn  = (u16*)(ws + 8388608);        //  4 MB bf16
    u16*   qkv = (u16*)(ws + 12582912);       // 12.6 MB bf16 (2048x3072)
    u16*   ob  = (u16*)(ws + 25165824);       //  4 MB bf16
    u16*   ff  = (u16*)(ws + 29360128);       // 16.8 MB bf16 (2048x4096)
    u16*   wq  = (u16*)(ws + 46137344);       // 65.5 MB bf16 weight slab
    float* pbuf = (float*)(ws + 12582912);    // fc2 split-K partials (16 MB f32, dead region)

    u16* wqkv = wq;
    u16* wproj = wqkv + 3072 * 1024;
    u16* wfc1  = wproj + 1024 * 1024;
    u16* wfc2  = wfc1 + 4096 * 1024;

    const int M = 2048;

    embed_ln_k<<<dim3(2048), 256, 0, stream>>>(x, tok_emb, pos_emb, h, ln1_g, ln1_b, xn);

    for (int lyr = 0; lyr < 6; ++lyr) {
        cvt4_k<<<dim3(2048), 256, 0, stream>>>(
            qkv_w + (size_t)lyr * 3072 * 1024, proj_w + (size_t)lyr * 1024 * 1024,
            fc1_w + (size_t)lyr * 4096 * 1024, fc2_w + (size_t)lyr * 1024 * 4096,
            wq, 3072 * 256, 1024 * 256, 4096 * 256, 4096 * 256);
        gemm4p<1, 0, 1, 0><<<dim3(16, 24), 512, 0, stream>>>(
            xn, wqkv, qkv_b + lyr * 3072, nullptr, qkv, M, 3072, 1024);
        attn_k<<<dim3(256), 512, 0, stream>>>(qkv, ob);
        gemm_db<64, 64, 1, 0, 1, 0, 0><<<dim3(32, 16), 256, 0, stream>>>(
            ob, wproj, proj_b + lyr * 1024, h, h, nullptr, M, 1024, 1024);
        ln_k<<<dim3(2048), 256, 0, stream>>>(h, ln2_g + lyr * 1024, ln2_b + lyr * 1024, xn);
        gemm4p<1, 1, 1, 0><<<dim3(16, 32), 512, 0, stream>>>(
            xn, wfc1, fc1_b + lyr * 4096, nullptr, ff, M, 4096, 1024);
        gemm4p<0, 0, 0, 1><<<dim3(16, 8, 2), 512, 0, stream>>>(
            ff, wfc2, nullptr, pbuf, nullptr, M, 1024, 4096);
        // fused: h += p0+p1+fc2_b, then LN with next layer's ln1 (or lnf on last layer)
        const float* g = (lyr < 5) ? (ln1_g + (lyr + 1) * 1024) : lnf_g;
        const float* b = (lyr < 5) ? (ln1_b + (lyr + 1) * 1024) : lnf_b;
        fuse2ln_k<<<dim3(2048), 256, 0, stream>>>(
            pbuf, pbuf + (size_t)M * 1024, fc2_b + lyr * 1024, h, g, b, xn);
    }

    cvt_k<<<dim3(2048), 256, 0, stream>>>(head_w, wq, 32000 * 1024 / 4);
    gemm4p<0, 0, 0, 0><<<dim3(16, 250), 512, 0, stream>>>(
        xn, wq, nullptr, out, nullptr, M, 32000, 1024);
}

// Round 10
// 1205.320 us; speedup vs baseline: 1.4767x; 1.0353x over previous
//
#include <hip/hip_runtime.h>

typedef unsigned short u16;
typedef unsigned int   u32;
typedef __bf16 bf16x8 __attribute__((ext_vector_type(8)));
typedef float  f32x4  __attribute__((ext_vector_type(4)));

#define DEV __device__ __forceinline__

DEV u16 f2bf(float f) {
    u32 u = __builtin_bit_cast(u32, f);
    u32 r = u + 0x7FFFu + ((u >> 16) & 1u);
    return (u16)(r >> 16);
}

DEV void gload16(const void* g, void* l) {
    __builtin_amdgcn_global_load_lds((const __attribute__((address_space(1))) void*)g,
                                     (__attribute__((address_space(3))) void*)l, 16, 0, 0);
}

// bijective XCD-aware swizzle (m204)
DEV int xcd_swz(int bid, int nwg) {
    int q = nwg >> 3, r = nwg & 7;
    int xcd = bid & 7, idx = bid >> 3;
    return (xcd < r ? xcd * (q + 1) : r * (q + 1) + (xcd - r) * q) + idx;
}

// involutive LDS byte swizzle for 128B rows: XOR byte bits[6:4] with row bits [0,2,1]
DEV int swz(int p) {
    int m = (((p >> 7) & 1) << 6) | (((p >> 9) & 1) << 5) | (((p >> 8) & 1) << 4);
    return p ^ m;
}

// ---------------- convert f32 -> bf16 (single tensor) ----------------
__global__ void cvt_k(const float* __restrict__ src, u16* __restrict__ dst, int n4) {
    int i = blockIdx.x * blockDim.x + threadIdx.x;
    int stride = gridDim.x * blockDim.x;
    for (; i < n4; i += stride) {
        float4 v = ((const float4*)src)[i];
        ushort4 u;
        u.x = f2bf(v.x); u.y = f2bf(v.y); u.z = f2bf(v.z); u.w = f2bf(v.w);
        ((ushort4*)dst)[i] = u;
    }
}

// ---------------- convert 4 tensors in one launch (per-layer weights) ----------------
__global__ void cvt4_k(const float* __restrict__ s0, const float* __restrict__ s1,
                       const float* __restrict__ s2, const float* __restrict__ s3,
                       u16* __restrict__ dst, int n0, int n1, int n2, int n3) {
    int i = blockIdx.x * blockDim.x + threadIdx.x;
    int stride = gridDim.x * blockDim.x;
    int t0 = n0, t1 = t0 + n1, t2 = t1 + n2, t3 = t2 + n3;
    for (; i < t3; i += stride) {
        const float* s; int j;
        if (i < t0)      { s = s0; j = i; }
        else if (i < t1) { s = s1; j = i - t0; }
        else if (i < t2) { s = s2; j = i - t1; }
        else             { s = s3; j = i - t2; }
        float4 v = ((const float4*)s)[j];
        ushort4 u;
        u.x = f2bf(v.x); u.y = f2bf(v.y); u.z = f2bf(v.z); u.w = f2bf(v.w);
        ((ushort4*)dst)[i] = u;
    }
}

// ---------------- LN core ----------------
DEV void ln_store(float4 v, const float* __restrict__ g, const float* __restrict__ b,
                  u16* __restrict__ out, int row, int t) {
    float s = v.x + v.y + v.z + v.w;
    float s2 = v.x * v.x + v.y * v.y + v.z * v.z + v.w * v.w;
    #pragma unroll
    for (int msk = 1; msk < 64; msk <<= 1) {
        s  += __shfl_xor(s, msk);
        s2 += __shfl_xor(s2, msk);
    }
    __shared__ float ps[4], ps2[4];
    if ((t & 63) == 0) { ps[t >> 6] = s; ps2[t >> 6] = s2; }
    __syncthreads();
    s = ps[0] + ps[1] + ps[2] + ps[3];
    s2 = ps2[0] + ps2[1] + ps2[2] + ps2[3];
    float mu = s * (1.0f / 1024.0f);
    float var = s2 * (1.0f / 1024.0f) - mu * mu;
    float rstd = rsqrtf(var + 1e-5f);
    float4 gg = ((const float4*)g)[t];
    float4 bb = ((const float4*)b)[t];
    ushort4 o;
    o.x = f2bf((v.x - mu) * rstd * gg.x + bb.x);
    o.y = f2bf((v.y - mu) * rstd * gg.y + bb.y);
    o.z = f2bf((v.z - mu) * rstd * gg.z + bb.z);
    o.w = f2bf((v.w - mu) * rstd * gg.w + bb.w);
    ((ushort4*)out)[(size_t)row * 256 + t] = o;
}

__global__ void ln_k(const float* __restrict__ in, const float* __restrict__ g,
                     const float* __restrict__ b, u16* __restrict__ out) {
    int row = blockIdx.x;
    int t = threadIdx.x;
    float4 v = ((const float4*)(in + (size_t)row * 1024))[t];
    ln_store(v, g, b, out, row, t);
}

__global__ void embed_ln_k(const int* __restrict__ x, const float* __restrict__ te,
                           const float* __restrict__ pe, float* __restrict__ h,
                           const float* __restrict__ g, const float* __restrict__ b,
                           u16* __restrict__ xn) {
    int row = blockIdx.x;
    int t = threadIdx.x;
    int tok = x[row];
    int s = row & 1023;
    float4 a = ((const float4*)(te + (size_t)tok * 1024))[t];
    float4 p = ((const float4*)(pe + (size_t)s * 1024))[t];
    a.x += p.x; a.y += p.y; a.z += p.z; a.w += p.w;
    ((float4*)(h + (size_t)row * 1024))[t] = a;
    ln_store(a, g, b, xn, row, t);
}

__global__ void fuse2ln_k(const float* __restrict__ p0, const float* __restrict__ p1,
                          const float* __restrict__ bias, float* __restrict__ h,
                          const float* __restrict__ g, const float* __restrict__ b,
                          u16* __restrict__ xn) {
    int row = blockIdx.x;
    int t = threadIdx.x;
    size_t idx = (size_t)row * 256 + t;
    float4 a = ((const float4*)p0)[idx];
    float4 bb = ((const float4*)p1)[idx];
    float4 c = ((const float4*)bias)[t];
    float4 v = ((const float4*)h)[idx];
    v.x += a.x + bb.x + c.x;
    v.y += a.y + bb.y + c.y;
    v.z += a.z + bb.z + c.z;
    v.w += a.w + bb.w + c.w;
    ((float4*)h)[idx] = v;
    ln_store(v, g, b, xn, row, t);
}

// ============ 256x256 8-wave 4-phase-per-K-tile GEMM (BK=64, counted vmcnt) ============
template<int PH>
DEV void phase_mma(const bf16x8 (&af)[2][2], const bf16x8 (&bfr)[4][2], f32x4 (&acc)[8][4]) {
    __builtin_amdgcn_s_barrier();
    asm volatile("s_waitcnt lgkmcnt(0)" ::: "memory");
    __builtin_amdgcn_sched_barrier(0);
    __builtin_amdgcn_s_setprio(1);
    #pragma unroll
    for (int ms = 0; ms < 2; ++ms)
        #pragma unroll
        for (int nj = 0; nj < 4; ++nj)
            #pragma unroll
            for (int kk = 0; kk < 2; ++kk)
                acc[PH * 2 + ms][nj] = __builtin_amdgcn_mfma_f32_16x16x32_bf16(
                    af[ms][kk], bfr[nj][kk], acc[PH * 2 + ms][nj], 0, 0, 0);
    __builtin_amdgcn_s_setprio(0);
}

template<int PH>
DEV void read_afrags(const char* Ab, int arow, int fr, int fq, bf16x8 (&af)[2][2]) {
    #pragma unroll
    for (int ms = 0; ms < 2; ++ms)
        #pragma unroll
        for (int kk = 0; kk < 2; ++kk) {
            int lin = (arow + (PH * 2 + ms) * 16 + fr) * 128 + kk * 64 + fq * 16;
            af[ms][kk] = *(const bf16x8*)(Ab + swz(lin));
        }
}

template<int BIAS, int OUTBF>
__global__ __launch_bounds__(512, 2)
void gemm8p(const u16* __restrict__ A, const u16* __restrict__ Bw,
            const float* __restrict__ bias,
            float* __restrict__ outf, u16* __restrict__ outb,
            int M, int N, int K) {
    __shared__ char lds[131072];
    char* ldsA = lds;
    char* ldsB = lds + 65536;
    const int t = threadIdx.x;
    const int w = t >> 6, l = t & 63;
    const int fr = l & 15, fq = l >> 4;
    const int wm = w >> 2, wn = w & 3;

    int bid = blockIdx.y * gridDim.x + blockIdx.x;
    int swzb = xcd_swz(bid, gridDim.x * gridDim.y);
    const int m0 = (swzb % gridDim.x) * 256;
    const int n0 = (swzb / gridDim.x) * 256;
    const int nt = K >> 6;
    const int arow = wm * 128;

    const u16* Asrc = A + (size_t)m0 * K;
    const u16* Bsrc = Bw + (size_t)n0 * K;

    size_t o00, o01, o10, o11;
    {
        int p;
        p = 0 * 16384 + 0 * 8192 + t * 16; o00 = (size_t)(p >> 7) * K + ((swz(p) & 127) >> 1);
        p = 0 * 16384 + 1 * 8192 + t * 16; o01 = (size_t)(p >> 7) * K + ((swz(p) & 127) >> 1);
        p = 1 * 16384 + 0 * 8192 + t * 16; o10 = (size_t)(p >> 7) * K + ((swz(p) & 127) >> 1);
        p = 1 * 16384 + 1 * 8192 + t * 16; o11 = (size_t)(p >> 7) * K + ((swz(p) & 127) >> 1);
    }
    const int wb = w * 1024;

    gload16(Asrc + o00, ldsA + wb);
    gload16(Asrc + o01, ldsA + 8192 + wb);
    gload16(Asrc + o10, ldsA + 16384 + wb);
    gload16(Asrc + o11, ldsA + 16384 + 8192 + wb);
    gload16(Bsrc + o00, ldsB + wb);
    gload16(Bsrc + o01, ldsB + 8192 + wb);
    gload16(Bsrc + o10, ldsB + 16384 + wb);
    gload16(Bsrc + o11, ldsB + 16384 + 8192 + wb);
    gload16(Bsrc + o00 + 64, ldsB + 32768 + wb);
    gload16(Bsrc + o01 + 64, ldsB + 32768 + 8192 + wb);
    gload16(Bsrc + o10 + 64, ldsB + 32768 + 16384 + wb);
    gload16(Bsrc + o11 + 64, ldsB + 32768 + 16384 + 8192 + wb);
    asm volatile("s_waitcnt vmcnt(4)" ::: "memory");
    __builtin_amdgcn_s_barrier();
    __builtin_amdgcn_sched_barrier(0);

    f32x4 acc[8][4] = {};

    for (int T = 0; T < nt; ++T) {
        const char* Ab = ldsA + (T & 1) * 32768;
        const char* Bb = ldsB + (T & 1) * 32768;
        char* Anx = ldsA + ((T + 1) & 1) * 32768;
        char* Bnx = ldsB + (T & 1) * 32768;
        const bool stA = (T + 1 < nt), stB = (T + 2 < nt);
        const size_t kA = (size_t)(T + 1) * 64, kB = (size_t)(T + 2) * 64;

        bf16x8 bfr[4][2], af[2][2];

        #pragma unroll
        for (int nj = 0; nj < 4; ++nj)
            #pragma unroll
            for (int kk = 0; kk < 2; ++kk) {
                int lin = (wn * 64 + nj * 16 + fr) * 128 + kk * 64 + fq * 16;
                bfr[nj][kk] = *(const bf16x8*)(Bb + swz(lin));
            }
        read_afrags<0>(Ab, arow, fr, fq, af);
        if (stA) {
            gload16(Asrc + o00 + kA, Anx + wb);
            gload16(Asrc + o01 + kA, Anx + 8192 + wb);
        }
        phase_mma<0>(af, bfr, acc);
        __builtin_amdgcn_s_barrier();

        read_afrags<1>(Ab, arow, fr, fq, af);
        if (stA) {
            gload16(Asrc + o10 + kA, Anx + 16384 + wb);
            gload16(Asrc + o11 + kA, Anx + 16384 + 8192 + wb);
        }
        phase_mma<1>(af, bfr, acc);
        __builtin_amdgcn_s_barrier();

        read_afrags<2>(Ab, arow, fr, fq, af);
        if (stB) {
            gload16(Bsrc + o00 + kB, Bnx + wb);
            gload16(Bsrc + o01 + kB, Bnx + 8192 + wb);
        }
        phase_mma<2>(af, bfr, acc);
        __builtin_amdgcn_s_barrier();

        read_afrags<3>(Ab, arow, fr, fq, af);
        if (stB) {
            gload16(Bsrc + o10 + kB, Bnx + 16384 + wb);
            gload16(Bsrc + o11 + kB, Bnx + 16384 + 8192 + wb);
        }
        phase_mma<3>(af, bfr, acc);
        if (stB)      asm volatile("s_waitcnt vmcnt(4)" ::: "memory");
        else if (stA) asm volatile("s_waitcnt vmcnt(0)" ::: "memory");
        __builtin_amdgcn_s_barrier();
        __builtin_amdgcn_sched_barrier(0);
    }

    #pragma unroll
    for (int mi = 0; mi < 8; ++mi) {
        #pragma unroll
        for (int nj = 0; nj < 4; ++nj) {
            #pragma unroll
            for (int r = 0; r < 4; ++r) {
                int row = m0 + wm * 128 + mi * 16 + fq * 4 + r;
                int col = n0 + wn * 64 + nj * 16 + fr;
                float v = acc[mi][nj][r];
                if (BIAS) v += bias[col];
                if (OUTBF) outb[(size_t)row * N + col] = f2bf(v);
                else       outf[(size_t)row * N + col] = v;
            }
        }
    }
}

// ============ 128x128 8-wave 2-phase-per-K-tile GEMM (BK=64, counted vmcnt(2)) ============
template<int BIAS, int GELU_, int OUTBF, int SPLITK>
__global__ __launch_bounds__(512, 2)
void gemm4p(const u16* __restrict__ A, const u16* __restrict__ Bw,
            const float* __restrict__ bias,
            float* __restrict__ outf, u16* __restrict__ outb,
            int M, int N, int K) {
    __shared__ char lds[65536];
    char* ldsA = lds;
    char* ldsB = lds + 32768;
    const int t = threadIdx.x;
    const int w = t >> 6, l = t & 63;
    const int fr = l & 15, fq = l >> 4;
    const int wm = w >> 2, wn = w & 3;

    int bid = blockIdx.y * gridDim.x + blockIdx.x;
    int swzb = xcd_swz(bid, gridDim.x * gridDim.y);
    const int m0 = (swzb % gridDim.x) * 128;
    const int n0 = (swzb / gridDim.x) * 128;

    int kbase = 0, Keff = K;
    if (SPLITK) { Keff = K >> 1; kbase = blockIdx.z * Keff; }
    const int nt = Keff >> 6;

    const u16* Asrc = A + (size_t)m0 * K + kbase;
    const u16* Bsrc = Bw + (size_t)n0 * K + kbase;

    size_t o0, o1;
    {
        int p = t * 16;        o0 = (size_t)(p >> 7) * K + ((swz(p) & 127) >> 1);
        p = 8192 + t * 16;     o1 = (size_t)(p >> 7) * K + ((swz(p) & 127) >> 1);
    }
    const int wb = w * 1024;

    gload16(Asrc + o0, ldsA + wb);
    gload16(Asrc + o1, ldsA + 8192 + wb);
    gload16(Bsrc + o0, ldsB + wb);
    gload16(Bsrc + o1, ldsB + 8192 + wb);
    gload16(Bsrc + o0 + 64, ldsB + 16384 + wb);
    gload16(Bsrc + o1 + 64, ldsB + 16384 + 8192 + wb);
    asm volatile("s_waitcnt vmcnt(2)" ::: "memory");
    __builtin_amdgcn_s_barrier();
    __builtin_amdgcn_sched_barrier(0);

    f32x4 acc[4][2] = {};

    for (int T = 0; T < nt; ++T) {
        const char* Ab = ldsA + (T & 1) * 16384;
        const char* Bb = ldsB + (T & 1) * 16384;
        char* Anx = ldsA + ((T + 1) & 1) * 16384;
        char* Bnx = ldsB + (T & 1) * 16384;
        const bool stA = (T + 1 < nt), stB = (T + 2 < nt);
        const size_t kA = (size_t)(T + 1) * 64, kB = (size_t)(T + 2) * 64;

        bf16x8 bfr[2][2], af[2][2];

        #pragma unroll
        for (int nj = 0; nj < 2; ++nj)
            #pragma unroll
            for (int kk = 0; kk < 2; ++kk) {
                int lin = (wn * 32 + nj * 16 + fr) * 128 + kk * 64 + fq * 16;
                bfr[nj][kk] = *(const bf16x8*)(Bb + swz(lin));
            }
        #pragma unroll
        for (int ms = 0; ms < 2; ++ms)
            #pragma unroll
            for (int kk = 0; kk < 2; ++kk) {
                int lin = (wm * 64 + ms * 16 + fr) * 128 + kk * 64 + fq * 16;
                af[ms][kk] = *(const bf16x8*)(Ab + swz(lin));
            }
        if (stA) {
            gload16(Asrc + o0 + kA, Anx + wb);
            gload16(Asrc + o1 + kA, Anx + 8192 + wb);
        }
        __builtin_amdgcn_s_barrier();
        asm volatile("s_waitcnt lgkmcnt(0)" ::: "memory");
        __builtin_amdgcn_sched_barrier(0);
        __builtin_amdgcn_s_setprio(1);
        #pragma unroll
        for (int ms = 0; ms < 2; ++ms)
            #pragma unroll
            for (int nj = 0; nj < 2; ++nj)
                #pragma unroll
                for (int kk = 0; kk < 2; ++kk)
                    acc[ms][nj] = __builtin_amdgcn_mfma_f32_16x16x32_bf16(
                        af[ms][kk], bfr[nj][kk], acc[ms][nj], 0, 0, 0);
        __builtin_amdgcn_s_setprio(0);
        __builtin_amdgcn_s_barrier();

        #pragma unroll
        for (int ms = 0; ms < 2; ++ms)
            #pragma unroll
            for (int kk = 0; kk < 2; ++kk) {
                int lin = (wm * 64 + (2 + ms) * 16 + fr) * 128 + kk * 64 + fq * 16;
                af[ms][kk] = *(const bf16x8*)(Ab + swz(lin));
            }
        if (stB) {
            gload16(Bsrc + o0 + kB, Bnx + wb);
            gload16(Bsrc + o1 + kB, Bnx + 8192 + wb);
        }
        __builtin_amdgcn_s_barrier();
        asm volatile("s_waitcnt lgkmcnt(0)" ::: "memory");
        __builtin_amdgcn_sched_barrier(0);
        __builtin_amdgcn_s_setprio(1);
        #pragma unroll
        for (int ms = 0; ms < 2; ++ms)
            #pragma unroll
            for (int nj = 0; nj < 2; ++nj)
                #pragma unroll
                for (int kk = 0; kk < 2; ++kk)
                    acc[2 + ms][nj] = __builtin_amdgcn_mfma_f32_16x16x32_bf16(
                        af[ms][kk], bfr[nj][kk], acc[2 + ms][nj], 0, 0, 0);
        __builtin_amdgcn_s_setprio(0);
        if (stB)      asm volatile("s_waitcnt vmcnt(2)" ::: "memory");
        else if (stA) asm volatile("s_waitcnt vmcnt(0)" ::: "memory");
        __builtin_amdgcn_s_barrier();
        __builtin_amdgcn_sched_barrier(0);
    }

    float* op = outf;
    if (SPLITK) op = outf + (size_t)blockIdx.z * M * N;

    #pragma unroll
    for (int mi = 0; mi < 4; ++mi) {
        #pragma unroll
        for (int nj = 0; nj < 2; ++nj) {
            #pragma unroll
            for (int r = 0; r < 4; ++r) {
                int row = m0 + wm * 64 + mi * 16 + fq * 4 + r;
                int col = n0 + wn * 32 + nj * 16 + fr;
                float v = acc[mi][nj][r];
                if (BIAS) v += bias[col];
                if (GELU_) v = 0.5f * v * (1.0f + erff(v * 0.70710678118f));
                if (OUTBF) outb[(size_t)row * N + col] = f2bf(v);
                else       op[(size_t)row * N + col] = v;
            }
        }
    }
}

// ---------------- 2-phase double-buffered GEMM (proj: RES epilogue) ----------------
template<int BM, int BN, int BIAS, int GELU_, int RES, int OUTBF, int SPLITK>
__global__ void gemm_db(const u16* __restrict__ A, const u16* __restrict__ Bw,
                        const float* __restrict__ bias, const float* __restrict__ res,
                        float* __restrict__ outf, u16* __restrict__ outb,
                        int M, int N, int K) {
    constexpr int MR = BM / 32;
    constexpr int NR = BN / 32;
    constexpr int AL = BM / 64;
    constexpr int BL = BN / 64;
    __shared__ u16 lA[2][BM * 32];
    __shared__ u16 lB[2][BN * 32];
    const int t = threadIdx.x;
    const int w = t >> 6, l = t & 63;

    int bid = blockIdx.y * gridDim.x + blockIdx.x;
    int swzb = xcd_swz(bid, gridDim.x * gridDim.y);
    const int m0 = (swzb % gridDim.x) * BM;
    const int n0 = (swzb / gridDim.x) * BN;

    int kbase = 0, Keff = K;
    if (SPLITK) { Keff = K >> 1; kbase = blockIdx.z * Keff; }
    const int nt = Keff >> 5;

    const int wr = (w >> 1) * (BM / 2), wc = (w & 1) * (BN / 2);
    const int fr = l & 15, fq = l >> 4;
    const int g0 = w * 64 + l;

    const int srow = g0 >> 2, scol = (g0 & 3) * 8;

    f32x4 acc[MR][NR] = {};

    #pragma unroll
    for (int i = 0; i < AL; ++i)
        gload16(A + (size_t)(m0 + srow + i * 64) * K + kbase + scol, lA[0] + (srow + i * 64) * 32 + scol);
    #pragma unroll
    for (int i = 0; i < BL; ++i)
        gload16(Bw + (size_t)(n0 + srow + i * 64) * K + kbase + scol, lB[0] + (srow + i * 64) * 32 + scol);
    __syncthreads();

    for (int T = 0; T < nt; ++T) {
        const int cur = T & 1, nxt = cur ^ 1;
        if (T + 1 < nt) {
            const int kk = kbase + (T + 1) * 32;
            #pragma unroll
            for (int i = 0; i < AL; ++i)
                gload16(A + (size_t)(m0 + srow + i * 64) * K + kk + scol, lA[nxt] + (srow + i * 64) * 32 + scol);
            #pragma unroll
            for (int i = 0; i < BL; ++i)
                gload16(Bw + (size_t)(n0 + srow + i * 64) * K + kk + scol, lB[nxt] + (srow + i * 64) * 32 + scol);
        }
        bf16x8 af[MR], bfv[NR];
        #pragma unroll
        for (int mi = 0; mi < MR; ++mi)
            af[mi] = *(const bf16x8*)(lA[cur] + (wr + mi * 16 + fr) * 32 + fq * 8);
        #pragma unroll
        for (int ni = 0; ni < NR; ++ni)
            bfv[ni] = *(const bf16x8*)(lB[cur] + (wc + ni * 16 + fr) * 32 + fq * 8);
        #pragma unroll
        for (int mi = 0; mi < MR; ++mi)
            #pragma unroll
            for (int ni = 0; ni < NR; ++ni)
                acc[mi][ni] = __builtin_amdgcn_mfma_f32_16x16x32_bf16(af[mi], bfv[ni], acc[mi][ni], 0, 0, 0);
        __syncthreads();
    }

    float* op = outf;
    if (SPLITK) op = outf + (size_t)blockIdx.z * M * N;

    #pragma unroll
    for (int mi = 0; mi < MR; ++mi) {
        #pragma unroll
        for (int ni = 0; ni < NR; ++ni) {
            #pragma unroll
            for (int r = 0; r < 4; ++r) {
                int row = m0 + wr + mi * 16 + fq * 4 + r;
                int col = n0 + wc + ni * 16 + fr;
                float v = acc[mi][ni][r];
                if (BIAS) v += bias[col];
                if (GELU_) v = 0.5f * v * (1.0f + erff(v * 0.70710678118f));
                if (RES) v += res[(size_t)row * N + col];
                if (OUTBF) outb[(size_t)row * N + col] = f2bf(v);
                else       op[(size_t)row * N + col] = v;
            }
        }
    }
}

// ---------------- Flash attention: QBLK=128, 8 waves, async V prefetch ----------------
__global__ __launch_bounds__(512, 2)
void attn_k(const u16* __restrict__ qkv, u16* __restrict__ o) {
    __shared__ u16 lK[64 * 64];        // 8 KB
    __shared__ u16 lV[64 * 64];        // 8 KB, transposed [d][kv], swizzled
    __shared__ u16 lP[8 * 16 * 64];    // 16 KB, per-wave
    const int t = threadIdx.x;
    const int w = t >> 6, l = t & 63;
    const int fr = l & 15, fq = l >> 4;

    // grid 256 = 8 qb x 16 h x 2 b, XCD-chunked; qb descending (long first)
    int swzb = xcd_swz(blockIdx.x, gridDim.x);
    const int qb = 7 - (swzb & 7);
    const int hh = (swzb >> 3) & 15;
    const int b  = swzb >> 7;
    const int q0 = qb * 128;
    const int qw = q0 + w * 16;

    // K staging: pre-swizzled per-lane global source, linear LDS dest
    const u16* srcK;
    {
        int p = t * 16;
        int L = swz(p);
        srcK = qkv + ((size_t)(b * 1024) + (L >> 7)) * 3072 + 1024 + hh * 64 + ((L & 127) >> 1);
    }

    // V staging assignment: thread owns kv pair (2*kvp, 2*kvp+1) x 4 d's
    const int kvp = (t & 31) * 2;          // kv base 0..62
    const int vd0 = (t >> 5) * 4;          // d base 0..60
    const u16* srcV = qkv + (size_t)(b * 1024) * 3072 + 2048 + hh * 64 + vd0;

    bf16x8 qf[2];
    {
        size_t base = ((size_t)(b * 1024) + qw + fr) * 3072 + hh * 64;
        qf[0] = *(const bf16x8*)(qkv + base + fq * 8);
        qf[1] = *(const bf16x8*)(qkv + base + 32 + fq * 8);
    }

    float m_run[4], l_run[4];
    f32x4 acc_o[4] = {};
    #pragma unroll
    for (int r = 0; r < 4; ++r) { m_run[r] = -__builtin_inff(); l_run[r] = 0.0f; }

    // prefetch V(tile 0) into registers
    uint2 gv0 = *(const uint2*)(srcV + (size_t)kvp * 3072);
    uint2 gv1 = *(const uint2*)(srcV + (size_t)(kvp + 1) * 3072);

    const int kv_end = q0 + 128;
    for (int kv0 = 0; kv0 < kv_end; kv0 += 64) {
        // write V(t) regs -> LDS (4 x u32, swizzled [d][kv] pairs)
        #pragma unroll
        for (int j = 0; j < 4; ++j) {
            u32 lo = (j < 2) ? gv0.x : gv0.y;
            u32 hi = (j < 2) ? gv1.x : gv1.y;
            lo = (j & 1) ? (lo >> 16) : (lo & 0xffffu);
            hi = (j & 1) ? (hi >> 16) : (hi & 0xffffu);
            u32 word = lo | (hi << 16);
            int pv = (vd0 + j) * 128 + kvp * 2;
            *(u32*)((char*)lV + swz(pv)) = word;
        }
        // stage K(t) via global_load_lds
        gload16(srcK + (size_t)kv0 * 3072, (char*)lK + w * 1024);
        __syncthreads();   // drains vmcnt (K landed) + lgkm (V writes visible)

        // prefetch V(t+1) regs: latency hides under compute below
        if (kv0 + 64 < kv_end) {
            gv0 = *(const uint2*)(srcV + (size_t)(kv0 + 64 + kvp) * 3072);
            gv1 = *(const uint2*)(srcV + (size_t)(kv0 + 64 + kvp + 1) * 3072);
        }

        const bool active = (kv0 <= qw + 15);   // wave-uniform
        if (active) {
            f32x4 accs[4] = {};
            #pragma unroll
            for (int nt = 0; nt < 4; ++nt) {
                #pragma unroll
                for (int ks = 0; ks < 2; ++ks) {
                    int pk = ((nt * 16 + fr) * 64 + ks * 32 + fq * 8) * 2;
                    bf16x8 kf = *(const bf16x8*)((const char*)lK + swz(pk));
                    accs[nt] = __builtin_amdgcn_mfma_f32_16x16x32_bf16(qf[ks], kf, accs[nt], 0, 0, 0);
                }
            }

            float p[4][4], mx[4], rs[4];
            #pragma unroll
            for (int r = 0; r < 4; ++r) {
                int qg = qw + fq * 4 + r;
                float m = -__builtin_inff();
                #pragma unroll
                for (int nt = 0; nt < 4; ++nt) {
                    int kvg = kv0 + nt * 16 + fr;
                    float s = (kvg <= qg) ? accs[nt][r] * 0.125f : -__builtin_inff();
                    p[nt][r] = s;
                    m = fmaxf(m, s);
                }
                mx[r] = m;
            }
            #pragma unroll
            for (int msk = 1; msk < 16; msk <<= 1) {
                #pragma unroll
                for (int r = 0; r < 4; ++r) mx[r] = fmaxf(mx[r], __shfl_xor(mx[r], msk));
            }
            float mnew[4], alpha[4];
            #pragma unroll
            for (int r = 0; r < 4; ++r) {
                mnew[r] = fmaxf(m_run[r], mx[r]);
                alpha[r] = __expf(m_run[r] - mnew[r]);
                float s = 0.0f;
                #pragma unroll
                for (int nt = 0; nt < 4; ++nt) {
                    float pv = __expf(p[nt][r] - mnew[r]);
                    p[nt][r] = pv;
                    s += pv;
                }
                rs[r] = s;
            }
            #pragma unroll
            for (int msk = 1; msk < 16; msk <<= 1) {
                #pragma unroll
                for (int r = 0; r < 4; ++r) rs[r] += __shfl_xor(rs[r], msk);
            }
            #pragma unroll
            for (int r = 0; r < 4; ++r) {
                l_run[r] = l_run[r] * alpha[r] + rs[r];
                m_run[r] = mnew[r];
            }
            #pragma unroll
            for (int nt = 0; nt < 4; ++nt)
                #pragma unroll
                for (int r = 0; r < 4; ++r) acc_o[nt][r] *= alpha[r];

            #pragma unroll
            for (int nt = 0; nt < 4; ++nt)
                #pragma unroll
                for (int r = 0; r < 4; ++r) {
                    int pp = (w * 1024 + (fq * 4 + r) * 64 + nt * 16 + fr) * 2;
                    *(u16*)((char*)lP + swz(pp)) = f2bf(p[nt][r]);
                }

            bf16x8 pa[2];
            #pragma unroll
            for (int ks = 0; ks < 2; ++ks) {
                int ppr = (w * 1024 + fr * 64 + ks * 32 + fq * 8) * 2;
                pa[ks] = *(const bf16x8*)((const char*)lP + swz(ppr));
            }
            #pragma unroll
            for (int nt = 0; nt < 4; ++nt) {
                #pragma unroll
                for (int ks = 0; ks < 2; ++ks) {
                    int pvr = ((nt * 16 + fr) * 64 + ks * 32 + fq * 8) * 2;
                    bf16x8 vf = *(const bf16x8*)((const char*)lV + swz(pvr));
                    acc_o[nt] = __builtin_amdgcn_mfma_f32_16x16x32_bf16(pa[ks], vf, acc_o[nt], 0, 0, 0);
                }
            }
        }
        __syncthreads();
    }

    #pragma unroll
    for (int nt = 0; nt < 4; ++nt) {
        #pragma unroll
        for (int r = 0; r < 4; ++r) {
            int qg = qw + fq * 4 + r;
            int d = nt * 16 + fr;
            float ov = acc_o[nt][r] / l_run[r];
            o[((size_t)(b * 1024) + qg) * 1024 + hh * 64 + d] = f2bf(ov);
        }
    }
}

// ---------------- launch ----------------
extern "C" void kernel_launch(void* const* d_in, const int* in_sizes, int n_in,
                              void* d_out, int out_size, void* d_ws, size_t ws_size,
                              hipStream_t stream) {
    const int*   x       = (const int*)  d_in[0];
    const float* tok_emb = (const float*)d_in[1];
    const float* pos_emb = (const float*)d_in[2];
    const float* ln1_g   = (const float*)d_in[3];
    const float* ln1_b   = (const float*)d_in[4];
    const float* qkv_w   = (const float*)d_in[5];
    const float* qkv_b   = (const float*)d_in[6];
    const float* proj_w  = (const float*)d_in[7];
    const float* proj_b  = (const float*)d_in[8];
    const float* ln2_g   = (const float*)d_in[9];
    const float* ln2_b   = (const float*)d_in[10];
    const float* fc1_w   = (const float*)d_in[11];
    const float* fc1_b   = (const float*)d_in[12];
    const float* fc2_w   = (const float*)d_in[13];
    const float* fc2_b   = (const float*)d_in[14];
    const float* lnf_g   = (const float*)d_in[15];
    const float* lnf_b   = (const float*)d_in[16];
    const float* head_w  = (const float*)d_in[17];
    float* out = (float*)d_out;

    char* ws = (char*)d_ws;
    float* h   = (float*)(ws + 0);            //  8 MB f32 (2048x1024)
    u16*   xn  = (u16*)(ws + 8388608);        //  4 MB bf16
    u16*   qkv = (u16*)(ws + 12582912);       // 12.6 MB bf16 (2048x3072)
    u16*   ob  = (u16*)(ws + 25165824);       //  4 MB bf16
    u16*   ff  = (u16*)(ws + 29360128);       // 16.8 MB bf16 (2048x4096)
    u16*   wq  = (u16*)(ws + 46137344);       // 65.5 MB bf16 weight slab
    float* pbuf = (float*)(ws + 12582912);    // fc2 split-K partials (dead region)

    u16* wqkv = wq;
    u16* wproj = wqkv + 3072 * 1024;
    u16* wfc1  = wproj + 1024 * 1024;
    u16* wfc2  = wfc1 + 4096 * 1024;

    const int M = 2048;

    embed_ln_k<<<dim3(2048), 256, 0, stream>>>(x, tok_emb, pos_emb, h, ln1_g, ln1_b, xn);

    for (int lyr = 0; lyr < 6; ++lyr) {
        cvt4_k<<<dim3(2048), 256, 0, stream>>>(
            qkv_w + (size_t)lyr * 3072 * 1024, proj_w + (size_t)lyr * 1024 * 1024,
            fc1_w + (size_t)lyr * 4096 * 1024, fc2_w + (size_t)lyr * 1024 * 4096,
            wq, 3072 * 256, 1024 * 256, 4096 * 256, 4096 * 256);
        gemm4p<1, 0, 1, 0><<<dim3(16, 24), 512, 0, stream>>>(
            xn, wqkv, qkv_b + lyr * 3072, nullptr, qkv, M, 3072, 1024);
        attn_k<<<dim3(256), 512, 0, stream>>>(qkv, ob);
        gemm_db<64, 64, 1, 0, 1, 0, 0><<<dim3(32, 16), 256, 0, stream>>>(
            ob, wproj, proj_b + lyr * 1024, h, h, nullptr, M, 1024, 1024);
        ln_k<<<dim3(2048), 256, 0, stream>>>(h, ln2_g + lyr * 1024, ln2_b + lyr * 1024, xn);
        gemm4p<1, 1, 1, 0><<<dim3(16, 32), 512, 0, stream>>>(
            xn, wfc1, fc1_b + lyr * 4096, nullptr, ff, M, 4096, 1024);
        gemm4p<0, 0, 0, 1><<<dim3(16, 8, 2), 512, 0, stream>>>(
            ff, wfc2, nullptr, pbuf, nullptr, M, 1024, 4096);
        const float* g = (lyr < 5) ? (ln1_g + (lyr + 1) * 1024) : lnf_g;
        const float* b = (lyr < 5) ? (ln1_b + (lyr + 1) * 1024) : lnf_b;
        fuse2ln_k<<<dim3(2048), 256, 0, stream>>>(
            pbuf, pbuf + (size_t)M * 1024, fc2_b + lyr * 1024, h, g, b, xn);
    }

    cvt_k<<<dim3(2048), 256, 0, stream>>>(head_w, wq, 32000 * 1024 / 4);
    gemm8p<0, 0><<<dim3(8, 125), 512, 0, stream>>>(
        xn, wq, nullptr, out, nullptr, M, 32000, 1024);
}